// Round 14
// baseline (694.607 us; speedup 1.0000x reference)
//
#include <hip/hip_runtime.h>

#define NTOT 21904
#define MPAD 22016
#define NPATCH 1369
#define BIMG 16
#define DIM 768
#define NCLS 200
#define CDIM 201
#define KP 5
#define NCK 1005
#define PCH 16   // pnew patch chunks per image
#define QCH 32   // pool patch chunks per image (fallback)
#define UCH 1024 // pca pass partial chunks

typedef short bf16x8 __attribute__((ext_vector_type(8)));
typedef float f32x4v __attribute__((ext_vector_type(4)));

__device__ __forceinline__ unsigned encf(float x){
  unsigned b = __float_as_uint(x);
  return (b & 0x80000000u) ? ~b : (b | 0x80000000u);
}
__device__ __forceinline__ float decf(unsigned e){
  return (e & 0x80000000u) ? __uint_as_float(e ^ 0x80000000u) : __uint_as_float(~e);
}
__device__ __forceinline__ unsigned short f2bf(float f){
  unsigned u = __float_as_uint(f);
  u += 0x7FFFu + ((u >> 16) & 1u);
  return (unsigned short)(u >> 16);
}
__device__ __forceinline__ float bf2f(unsigned short h){
  return __uint_as_float(((unsigned)h) << 16);
}
__device__ __forceinline__ void gload16(const unsigned short* g, unsigned short* l){
  __builtin_amdgcn_global_load_lds(
      (const __attribute__((address_space(1))) unsigned int*)g,
      (__attribute__((address_space(3))) unsigned int*)l, 16, 0, 0);
}

__device__ __forceinline__ float red256(float v, float* sh){
  int t = threadIdx.x;
  sh[t] = v; __syncthreads();
  for(int s = 128; s > 0; s >>= 1){ if(t < s) sh[t] += sh[t+s]; __syncthreads(); }
  float r = sh[0]; __syncthreads();
  return r;
}

// ---------------- column sums, 512 chunks x 43 rows (FROZEN ORDER; unroll = load batching only) ----------------
__global__ __launch_bounds__(256) void k_colmean1(const float* __restrict__ X, float* __restrict__ pbuf){
  int b = blockIdx.x, t = threadIdx.x;
  int n0 = b * 43, n1 = n0 + 43; if(n1 > NTOT) n1 = NTOT;
  float s0 = 0.f, s1 = 0.f, s2 = 0.f;
  #pragma unroll 8
  for(int n = n0; n < n1; ++n){
    const float* row = X + (size_t)n * DIM;
    s0 += row[t]; s1 += row[t + 256]; s2 += row[t + 512];
  }
  float* pb = pbuf + (size_t)b * DIM;
  pb[t] = s0; pb[t + 256] = s1; pb[t + 512] = s2;
}

// ---------------- mean + wv init + 12-way parts; also init counts/enc (FROZEN ORDER; ILP unroll) ----------------
__global__ __launch_bounds__(256) void k_meanred(const float* __restrict__ pbuf,
    float* __restrict__ meanv, float* __restrict__ wvb, float* __restrict__ parts,
    int* __restrict__ counts, unsigned* __restrict__ enc){
  __shared__ float sh[256];
  int cg = blockIdx.x, t = threadIdx.x;
  if(cg == 0){
    if(t < CDIM) counts[t] = 0;
    if(t == 0){ enc[0] = 0xFFFFFFFFu; enc[1] = 0u; }
  }
  int tc = t & 63, th = t >> 6;
  int col = cg * 64 + tc;
  const float v0 = 0.036084391824351615f;   // 1/sqrt(768)
  float s = 0.f;
  #pragma unroll 32
  for(int ch = th; ch < 512; ch += 4) s += pbuf[ch * DIM + col];
  sh[t] = s; __syncthreads();
  float mcontrib = 0.f;
  if(th == 0){
    float m = (sh[tc] + sh[64 + tc] + sh[128 + tc] + sh[192 + tc]) / 21904.0f;
    meanv[col] = m;
    wvb[col] = v0;
    mcontrib = m * v0;
  }
  __syncthreads();
  float md = red256(mcontrib, sh);
  if(t == 0){ parts[cg] = 64.0f * v0 * v0; parts[16 + cg] = md; }
}

// ---------------- power-iteration pass (FROZEN ORDER; 5-row batch for MLP, bit-identical accumulation) ----------------
__global__ __launch_bounds__(256) void k_pcapass(const float* __restrict__ X,
    const float* __restrict__ wvb, const float* __restrict__ parts,
    float* __restrict__ pbuf, float* __restrict__ subuf){
  __shared__ float shacc[4][DIM];
  __shared__ float shsu[4];
  int t = threadIdx.x, w = t >> 6, l = t & 63;
  float nrm2 = 0.f, mvr = 0.f;
  #pragma unroll
  for(int i = 0; i < 12; ++i){ nrm2 += parts[i]; mvr += parts[16 + i]; }
  float invD = 1.0f / (sqrtf(nrm2) + 1e-12f);
  const float4* v4 = (const float4*)(wvb + l * 12);
  float4 v0 = v4[0], v1 = v4[1], v2 = v4[2];
  float4 a0 = {0,0,0,0}, a1 = {0,0,0,0}, a2 = {0,0,0,0};
  float su = 0.f;
  int n = blockIdx.x * 4 + w;
  while(n + 16384 < NTOT){
    const float4* xa4 = (const float4*)(X + (size_t)n * DIM + l * 12);
    const float4* xb4 = (const float4*)(X + (size_t)(n + 4096) * DIM + l * 12);
    const float4* xc4 = (const float4*)(X + (size_t)(n + 8192) * DIM + l * 12);
    const float4* xd4 = (const float4*)(X + (size_t)(n + 12288) * DIM + l * 12);
    const float4* xe4 = (const float4*)(X + (size_t)(n + 16384) * DIM + l * 12);
    float4 xa0 = xa4[0], xa1 = xa4[1], xa2 = xa4[2];
    float4 xb0 = xb4[0], xb1 = xb4[1], xb2 = xb4[2];
    float4 xc0 = xc4[0], xc1 = xc4[1], xc2 = xc4[2];
    float4 xd0 = xd4[0], xd1 = xd4[1], xd2 = xd4[2];
    float4 xe0 = xe4[0], xe1 = xe4[1], xe2 = xe4[2];
    float tpA = xa0.x*v0.x + xa0.y*v0.y + xa0.z*v0.z + xa0.w*v0.w
              + xa1.x*v1.x + xa1.y*v1.y + xa1.z*v1.z + xa1.w*v1.w
              + xa2.x*v2.x + xa2.y*v2.y + xa2.z*v2.z + xa2.w*v2.w;
    float tpB = xb0.x*v0.x + xb0.y*v0.y + xb0.z*v0.z + xb0.w*v0.w
              + xb1.x*v1.x + xb1.y*v1.y + xb1.z*v1.z + xb1.w*v1.w
              + xb2.x*v2.x + xb2.y*v2.y + xb2.z*v2.z + xb2.w*v2.w;
    float tpC = xc0.x*v0.x + xc0.y*v0.y + xc0.z*v0.z + xc0.w*v0.w
              + xc1.x*v1.x + xc1.y*v1.y + xc1.z*v1.z + xc1.w*v1.w
              + xc2.x*v2.x + xc2.y*v2.y + xc2.z*v2.z + xc2.w*v2.w;
    float tpD = xd0.x*v0.x + xd0.y*v0.y + xd0.z*v0.z + xd0.w*v0.w
              + xd1.x*v1.x + xd1.y*v1.y + xd1.z*v1.z + xd1.w*v1.w
              + xd2.x*v2.x + xd2.y*v2.y + xd2.z*v2.z + xd2.w*v2.w;
    float tpE = xe0.x*v0.x + xe0.y*v0.y + xe0.z*v0.z + xe0.w*v0.w
              + xe1.x*v1.x + xe1.y*v1.y + xe1.z*v1.z + xe1.w*v1.w
              + xe2.x*v2.x + xe2.y*v2.y + xe2.z*v2.z + xe2.w*v2.w;
    #pragma unroll
    for(int o = 32; o > 0; o >>= 1){
      tpA += __shfl_xor(tpA, o);
      tpB += __shfl_xor(tpB, o);
      tpC += __shfl_xor(tpC, o);
      tpD += __shfl_xor(tpD, o);
      tpE += __shfl_xor(tpE, o);
    }
    tpA = (tpA - mvr) * invD;
    tpB = (tpB - mvr) * invD;
    tpC = (tpC - mvr) * invD;
    tpD = (tpD - mvr) * invD;
    tpE = (tpE - mvr) * invD;
    a0.x += tpA*xa0.x; a0.y += tpA*xa0.y; a0.z += tpA*xa0.z; a0.w += tpA*xa0.w;
    a1.x += tpA*xa1.x; a1.y += tpA*xa1.y; a1.z += tpA*xa1.z; a1.w += tpA*xa1.w;
    a2.x += tpA*xa2.x; a2.y += tpA*xa2.y; a2.z += tpA*xa2.z; a2.w += tpA*xa2.w;
    a0.x += tpB*xb0.x; a0.y += tpB*xb0.y; a0.z += tpB*xb0.z; a0.w += tpB*xb0.w;
    a1.x += tpB*xb1.x; a1.y += tpB*xb1.y; a1.z += tpB*xb1.z; a1.w += tpB*xb1.w;
    a2.x += tpB*xb2.x; a2.y += tpB*xb2.y; a2.z += tpB*xb2.z; a2.w += tpB*xb2.w;
    a0.x += tpC*xc0.x; a0.y += tpC*xc0.y; a0.z += tpC*xc0.z; a0.w += tpC*xc0.w;
    a1.x += tpC*xc1.x; a1.y += tpC*xc1.y; a1.z += tpC*xc1.z; a1.w += tpC*xc1.w;
    a2.x += tpC*xc2.x; a2.y += tpC*xc2.y; a2.z += tpC*xc2.z; a2.w += tpC*xc2.w;
    a0.x += tpD*xd0.x; a0.y += tpD*xd0.y; a0.z += tpD*xd0.z; a0.w += tpD*xd0.w;
    a1.x += tpD*xd1.x; a1.y += tpD*xd1.y; a1.z += tpD*xd1.z; a1.w += tpD*xd1.w;
    a2.x += tpD*xd2.x; a2.y += tpD*xd2.y; a2.z += tpD*xd2.z; a2.w += tpD*xd2.w;
    a0.x += tpE*xe0.x; a0.y += tpE*xe0.y; a0.z += tpE*xe0.z; a0.w += tpE*xe0.w;
    a1.x += tpE*xe1.x; a1.y += tpE*xe1.y; a1.z += tpE*xe1.z; a1.w += tpE*xe1.w;
    a2.x += tpE*xe2.x; a2.y += tpE*xe2.y; a2.z += tpE*xe2.z; a2.w += tpE*xe2.w;
    if(l == 0){ su += tpA; su += tpB; su += tpC; su += tpD; su += tpE; }
    n += 20480;
  }
  while(n < NTOT){
    const float4* x4 = (const float4*)(X + (size_t)n * DIM + l * 12);
    float4 x0 = x4[0], x1 = x4[1], x2 = x4[2];
    float tp = x0.x*v0.x + x0.y*v0.y + x0.z*v0.z + x0.w*v0.w
             + x1.x*v1.x + x1.y*v1.y + x1.z*v1.z + x1.w*v1.w
             + x2.x*v2.x + x2.y*v2.y + x2.z*v2.z + x2.w*v2.w;
    #pragma unroll
    for(int o = 32; o > 0; o >>= 1) tp += __shfl_xor(tp, o);
    tp = (tp - mvr) * invD;
    a0.x += tp*x0.x; a0.y += tp*x0.y; a0.z += tp*x0.z; a0.w += tp*x0.w;
    a1.x += tp*x1.x; a1.y += tp*x1.y; a1.z += tp*x1.z; a1.w += tp*x1.w;
    a2.x += tp*x2.x; a2.y += tp*x2.y; a2.z += tp*x2.z; a2.w += tp*x2.w;
    if(l == 0) su += tp;
    n += 4096;
  }
  float4* sh4 = (float4*)&shacc[w][l * 12];
  sh4[0] = a0; sh4[1] = a1; sh4[2] = a2;
  if(l == 0) shsu[w] = su;
  __syncthreads();
  for(int c = t; c < DIM; c += 256)
    pbuf[blockIdx.x * DIM + c] = shacc[0][c] + shacc[1][c] + shacc[2][c] + shacc[3][c];
  if(t == 0) subuf[blockIdx.x] = shsu[0] + shsu[1] + shsu[2] + shsu[3];
}

// ---------------- reduce partials -> new wv + 12-way parts (FROZEN ORDER; ILP unroll 64) ----------------
__global__ __launch_bounds__(256) void k_pcared(const float* __restrict__ pbuf,
    const float* __restrict__ subuf, const float* __restrict__ meanv,
    float* __restrict__ wvb, float* __restrict__ parts){
  __shared__ float sh[256];
  int cg = blockIdx.x, t = threadIdx.x;
  float sv = subuf[t] + subuf[t + 256] + subuf[t + 512] + subuf[t + 768];
  float su = red256(sv, sh);
  int tc = t & 63, th = t >> 6;
  int col = cg * 64 + tc;
  float s = 0.f;
  #pragma unroll 64
  for(int ch = th; ch < UCH; ch += 4) s += pbuf[(size_t)ch * DIM + col];
  sh[t] = s; __syncthreads();
  float csq = 0.f, cmd = 0.f;
  if(th == 0){
    float wvn = (sh[tc] + sh[64 + tc] + sh[128 + tc] + sh[192 + tc]) - meanv[col] * su;
    wvb[col] = wvn;
    csq = wvn * wvn;
    cmd = meanv[col] * wvn;
  }
  __syncthreads();
  float sq = red256(csq, sh);
  float md = red256(cmd, sh);
  if(t == 0){ parts[cg] = sq; parts[16 + cg] = md; }
}

// ---------------- final u = Xc v + min/max; PREP: fused rinv + bf16 hi/lo split (FROZEN; rows independent) ----------------
template<int PREP>
__global__ __launch_bounds__(256) void k_ufinal(const float* __restrict__ X,
    const float* __restrict__ wvb, const float* __restrict__ parts,
    float* __restrict__ u, unsigned* __restrict__ enc,
    float* __restrict__ rinv, unsigned short* __restrict__ Ahi, unsigned short* __restrict__ Alo){
  __shared__ float smn[4], smx[4];
  int t = threadIdx.x, w = t >> 6, l = t & 63;
  float nrm2 = 0.f, mvr = 0.f;
  #pragma unroll
  for(int i = 0; i < 12; ++i){ nrm2 += parts[i]; mvr += parts[16 + i]; }
  float invD = 1.0f / (sqrtf(nrm2) + 1e-12f);
  const float4* v4 = (const float4*)(wvb + l * 12);
  float4 v0 = v4[0], v1 = v4[1], v2 = v4[2];
  float lmn = 3.4e38f, lmx = -3.4e38f;
  int nend = PREP ? MPAD : NTOT;
  #pragma unroll 2
  for(int n = blockIdx.x * 4 + w; n < nend; n += 4096){
    size_t off = (size_t)n * DIM + l * 12;
    if(PREP && n >= NTOT){
      ushort4 z = make_ushort4(0, 0, 0, 0);
      #pragma unroll
      for(int j = 0; j < 3; ++j){
        *(ushort4*)(Ahi + off + j * 4) = z;
        *(ushort4*)(Alo + off + j * 4) = z;
      }
      continue;
    }
    const float4* x4 = (const float4*)(X + off);
    float4 x0 = x4[0], x1 = x4[1], x2 = x4[2];
    float tp = x0.x*v0.x + x0.y*v0.y + x0.z*v0.z + x0.w*v0.w
             + x1.x*v1.x + x1.y*v1.y + x1.z*v1.z + x1.w*v1.w
             + x2.x*v2.x + x2.y*v2.y + x2.z*v2.z + x2.w*v2.w;
    #pragma unroll
    for(int o = 32; o > 0; o >>= 1) tp += __shfl_xor(tp, o);
    tp = (tp - mvr) * invD;
    if(l == 0){ u[n] = tp; lmn = fminf(lmn, tp); lmx = fmaxf(lmx, tp); }
    if(PREP){
      float s = x0.x*x0.x + x0.y*x0.y + x0.z*x0.z + x0.w*x0.w
              + x1.x*x1.x + x1.y*x1.y + x1.z*x1.z + x1.w*x1.w
              + x2.x*x2.x + x2.y*x2.y + x2.z*x2.z + x2.w*x2.w;
      #pragma unroll
      for(int o = 32; o > 0; o >>= 1) s += __shfl_xor(s, o);
      float rv = 1.0f / (sqrtf(s) + 1e-12f);
      if(l == 0) rinv[n] = rv;
      float xs[12] = {x0.x*rv, x0.y*rv, x0.z*rv, x0.w*rv,
                      x1.x*rv, x1.y*rv, x1.z*rv, x1.w*rv,
                      x2.x*rv, x2.y*rv, x2.z*rv, x2.w*rv};
      unsigned short hi[12], lo[12];
      #pragma unroll
      for(int j = 0; j < 12; ++j){
        hi[j] = f2bf(xs[j]);
        lo[j] = f2bf(xs[j] - bf2f(hi[j]));
      }
      #pragma unroll
      for(int j = 0; j < 3; ++j){
        *(ushort4*)(Ahi + off + j * 4) = make_ushort4(hi[j*4], hi[j*4+1], hi[j*4+2], hi[j*4+3]);
        *(ushort4*)(Alo + off + j * 4) = make_ushort4(lo[j*4], lo[j*4+1], lo[j*4+2], lo[j*4+3]);
      }
    }
  }
  if(l == 0){ smn[w] = lmn; smx[w] = lmx; }
  __syncthreads();
  if(t == 0){
    float mn = fminf(fminf(smn[0], smn[1]), fminf(smn[2], smn[3]));
    float mx = fmaxf(fmaxf(smx[0], smx[1]), fmaxf(smx[2], smx[3]));
    atomicMin(&enc[0], encf(mn));
    atomicMax(&enc[1], encf(mx));
  }
}

// ---------------- pseudo labels (FROZEN) ----------------
__global__ __launch_bounds__(256) void k_pseudo(const float* __restrict__ u,
    const unsigned* __restrict__ enc, const int* __restrict__ labels,
    int* __restrict__ pl, float* __restrict__ pseudo_out,
    float* __restrict__ assign_out, int* __restrict__ counts){
  int n = blockIdx.x * 256 + threadIdx.x;
  if(n >= NTOT) return;
  float mn = decf(enc[0]), mx = decf(enc[1]);
  float us = (u[n] - mn) / (mx - mn);
  int b = n / NPATCH;
  int p = (us <= 0.5f) ? labels[b] : NCLS;
  pl[n] = p;
  pseudo_out[n] = (float)p;
  assign_out[n] = -1.0f;
  atomicAdd(&counts[p], 1);
}

// ---------------- row norms (fallback path) ----------------
__global__ __launch_bounds__(256) void k_rnorm(const float* __restrict__ X, float* __restrict__ rinv){
  int t = threadIdx.x, w = t >> 6, l = t & 63;
  int n = blockIdx.x * 4 + w;
  if(n >= NTOT) return;
  const float4* x4 = (const float4*)(X + (size_t)n * DIM + l * 12);
  float4 x0 = x4[0], x1 = x4[1], x2 = x4[2];
  float s = x0.x*x0.x + x0.y*x0.y + x0.z*x0.z + x0.w*x0.w
          + x1.x*x1.x + x1.y*x1.y + x1.z*x1.z + x1.w*x1.w
          + x2.x*x2.x + x2.y*x2.y + x2.z*x2.z + x2.w*x2.w;
  #pragma unroll
  for(int o = 32; o > 0; o >>= 1) s += __shfl_xor(s, o);
  if(l == 0) rinv[n] = 1.0f / (sqrtf(s) + 1e-12f);
}

// ---------------- normalized prototypes + bias2 ----------------
__global__ __launch_bounds__(256) void k_protn(const float* __restrict__ P,
    const float* __restrict__ bvec, float* __restrict__ protn, float* __restrict__ bias2){
  int t = threadIdx.x, w = t >> 6, l = t & 63;
  int r = blockIdx.x * 4 + w;
  if(r >= NCK) return;
  const float4* x4 = (const float4*)(P + (size_t)r * DIM + l * 12);
  float4 x0 = x4[0], x1 = x4[1], x2 = x4[2];
  float s = x0.x*x0.x + x0.y*x0.y + x0.z*x0.z + x0.w*x0.w
          + x1.x*x1.x + x1.y*x1.y + x1.z*x1.z + x1.w*x1.w
          + x2.x*x2.x + x2.y*x2.y + x2.z*x2.z + x2.w*x2.w;
  #pragma unroll
  for(int o = 32; o > 0; o >>= 1) s += __shfl_xor(s, o);
  float rv = 1.0f / (sqrtf(s) + 1e-12f);
  x0.x *= rv; x0.y *= rv; x0.z *= rv; x0.w *= rv;
  x1.x *= rv; x1.y *= rv; x1.z *= rv; x1.w *= rv;
  x2.x *= rv; x2.y *= rv; x2.z *= rv; x2.w *= rv;
  float4* o4 = (float4*)(protn + (size_t)r * DIM + l * 12);
  o4[0] = x0; o4[1] = x1; o4[2] = x2;
  const float4* b4 = (const float4*)(bvec + l * 12);
  float4 b0 = b4[0], b1 = b4[1], b2 = b4[2];
  float bb = b0.x*x0.x + b0.y*x0.y + b0.z*x0.z + b0.w*x0.w
           + b1.x*x1.x + b1.y*x1.y + b1.z*x1.z + b1.w*x1.w
           + b2.x*x2.x + b2.y*x2.y + b2.z*x2.z + b2.w*x2.w;
  #pragma unroll
  for(int o = 32; o > 0; o >>= 1) bb += __shfl_xor(bb, o);
  if(l == 0) bias2[r] = bb;
}

// ---------------- f32 NT GEMM; BF16OUT also emits hi/lo split (rows padded to 1024) ----------------
template<int HAS_SCALE, int HAS_BIAS, int HAS_ADD, int BF16OUT>
__global__ __launch_bounds__(256) void k_gemm_nt(const float* __restrict__ A,
    const float* __restrict__ B, float* __restrict__ C,
    const float* __restrict__ rowScale, const float* __restrict__ colBias,
    const float* __restrict__ addMat, unsigned short* __restrict__ Bh,
    unsigned short* __restrict__ Bl, int M, int N, int K){
  __shared__ float As[32][72];
  __shared__ float Bs[32][72];
  int t = threadIdx.x;
  int m0 = blockIdx.y * 64, n0 = blockIdx.x * 64;
  int srow = t >> 2, skq = (t & 3) * 8;
  int ty = t >> 4, tx = t & 15;
  int i0 = ty * 4, j0 = tx * 4;
  float acc[4][4] = {};
  int gra = m0 + srow; bool va = gra < M;
  int grb = n0 + srow; bool vb = grb < N;
  float scale = 1.0f;
  if(HAS_SCALE && va) scale = rowScale[gra];
  const float* Aptr = A + (size_t)gra * K + skq;
  const float* Bptr = B + (size_t)grb * K + skq;
  for(int k0 = 0; k0 < K; k0 += 32){
    float4 a0 = {0,0,0,0}, a1 = {0,0,0,0}, b0 = {0,0,0,0}, b1 = {0,0,0,0};
    if(va){ a0 = *(const float4*)(Aptr + k0); a1 = *(const float4*)(Aptr + k0 + 4); }
    if(vb){ b0 = *(const float4*)(Bptr + k0); b1 = *(const float4*)(Bptr + k0 + 4); }
    if(HAS_SCALE){
      a0.x *= scale; a0.y *= scale; a0.z *= scale; a0.w *= scale;
      a1.x *= scale; a1.y *= scale; a1.z *= scale; a1.w *= scale;
    }
    __syncthreads();
    As[skq+0][srow] = a0.x; As[skq+1][srow] = a0.y; As[skq+2][srow] = a0.z; As[skq+3][srow] = a0.w;
    As[skq+4][srow] = a1.x; As[skq+5][srow] = a1.y; As[skq+6][srow] = a1.z; As[skq+7][srow] = a1.w;
    Bs[skq+0][srow] = b0.x; Bs[skq+1][srow] = b0.y; Bs[skq+2][srow] = b0.z; Bs[skq+3][srow] = b0.w;
    Bs[skq+4][srow] = b1.x; Bs[skq+5][srow] = b1.y; Bs[skq+6][srow] = b1.z; Bs[skq+7][srow] = b1.w;
    __syncthreads();
    #pragma unroll
    for(int kk = 0; kk < 32; ++kk){
      float4 avv = *(const float4*)&As[kk][i0];
      float4 bvv = *(const float4*)&Bs[kk][j0];
      float a_[4] = {avv.x, avv.y, avv.z, avv.w};
      float b_[4] = {bvv.x, bvv.y, bvv.z, bvv.w};
      #pragma unroll
      for(int i = 0; i < 4; ++i)
        #pragma unroll
        for(int j = 0; j < 4; ++j)
          acc[i][j] += a_[i] * b_[j];
    }
  }
  #pragma unroll
  for(int i = 0; i < 4; ++i){
    int gr = m0 + i0 + i;
    #pragma unroll
    for(int j = 0; j < 4; ++j){
      int gc = n0 + j0 + j;
      if(gc >= N) continue;
      float v2 = 0.f;
      if(gr < M){
        v2 = acc[i][j];
        if(HAS_BIAS) v2 += colBias[gc];
        if(HAS_ADD) v2 += addMat[(size_t)gr * N + gc];
        C[(size_t)gr * N + gc] = v2;
      }
      if(BF16OUT && gr < 1024){
        unsigned short h = f2bf(v2);
        Bh[(size_t)gr * N + gc] = h;
        Bl[(size_t)gr * N + gc] = f2bf(v2 - bf2f(h));
      }
    }
  }
}

// ---------------- MFMA split-bf16 main GEMM: 128x256, triple-buffer, XCD-swizzled ----------------
__global__ __launch_bounds__(512, 1) void k_gemm_mfma(
    const unsigned short* __restrict__ Ahi, const unsigned short* __restrict__ Alo,
    const unsigned short* __restrict__ Bhi, const unsigned short* __restrict__ Blo,
    const float* __restrict__ bias2, float* __restrict__ C, float* __restrict__ poolPart){
  __shared__ __align__(16) unsigned short lds[73728];   // 144 KB = 3 buffers
  int h0 = blockIdx.x;
  int h = (h0 & 7) * 86 + (h0 >> 3);   // bijective XCD swizzle: 688 = 8 * 86 (T1)
  int nt = h & 3, mt = h >> 2;
  int m0 = mt * 128, n0 = nt * 256;
  int t = threadIdx.x;
  int w = t >> 6, l = t & 63;
  int wm = w >> 2, wn = w & 3;
  int lr = l & 15, lk = l >> 4;

  const unsigned short* gptr[6];
  int dofs[6];
  #pragma unroll
  for(int s = 0; s < 6; ++s){
    int cc = w * 6 + s;
    int r = (cc < 8) ? 0 : (cc < 16) ? 1 : (cc < 32) ? 2 : 3;
    int cc0 = (r == 0) ? 0 : (r == 1) ? 8 : (r == 2) ? 16 : 32;
    int regofs = (r == 0) ? 0 : (r == 1) ? 4096 : (r == 2) ? 8192 : 16384;
    int cloc = cc - cc0;
    int rloc = cloc * 16 + (l >> 2);
    int q = (l & 3) ^ ((rloc >> 1) & 3);
    const unsigned short* gs = (r == 0) ? Ahi : (r == 1) ? Alo : (r == 2) ? Bhi : Blo;
    int rbase = (r < 2) ? m0 : n0;
    gptr[s] = gs + (size_t)(rbase + rloc) * DIM + q * 8;
    dofs[s] = regofs + cloc * 512;
  }

  f32x4v acc[4][4];
  #pragma unroll
  for(int i = 0; i < 4; ++i)
    #pragma unroll
    for(int j = 0; j < 4; ++j) acc[i][j] = (f32x4v){0.f, 0.f, 0.f, 0.f};

  int aofs[4], bofs[4];
  #pragma unroll
  for(int f = 0; f < 4; ++f){
    int ar = wm * 64 + f * 16 + lr;
    aofs[f] = ar * 32 + (lk ^ ((ar >> 1) & 3)) * 8;
    int bc = wn * 64 + f * 16 + lr;
    bofs[f] = bc * 32 + (lk ^ ((bc >> 1) & 3)) * 8;
  }

  #pragma unroll
  for(int s = 0; s < 6; ++s) gload16(gptr[s], lds + dofs[s]);
  #pragma unroll
  for(int s = 0; s < 6; ++s) gload16(gptr[s] + 32, lds + 24576 + dofs[s]);

  const int NT = DIM / 32;  // 24
  for(int k = 0; k < NT; ++k){
    int k0 = k * 32;
    if(k + 2 < NT){
      unsigned short* dst = lds + ((k + 2) % 3) * 24576;
      #pragma unroll
      for(int s = 0; s < 6; ++s)
        gload16(gptr[s] + k0 + 64, dst + dofs[s]);
      asm volatile("s_waitcnt vmcnt(12)" ::: "memory");
    } else if(k + 1 < NT){
      asm volatile("s_waitcnt vmcnt(6)" ::: "memory");
    } else {
      asm volatile("s_waitcnt vmcnt(0)" ::: "memory");
    }
    asm volatile("s_barrier" ::: "memory");
    const unsigned short* Lb = lds + (k % 3) * 24576;
    bf16x8 bh[4], bl[4];
    #pragma unroll
    for(int f = 0; f < 4; ++f){
      bh[f] = *(const bf16x8*)&Lb[8192 + bofs[f]];
      bl[f] = *(const bf16x8*)&Lb[16384 + bofs[f]];
    }
    #pragma unroll
    for(int i = 0; i < 4; ++i){
      bf16x8 ahf = *(const bf16x8*)&Lb[aofs[i]];
      bf16x8 alf = *(const bf16x8*)&Lb[4096 + aofs[i]];
      #pragma unroll
      for(int j = 0; j < 4; ++j){
        acc[i][j] = __builtin_amdgcn_mfma_f32_16x16x32_bf16(ahf, bh[j], acc[i][j], 0, 0, 0);
        acc[i][j] = __builtin_amdgcn_mfma_f32_16x16x32_bf16(ahf, bl[j], acc[i][j], 0, 0, 0);
        acc[i][j] = __builtin_amdgcn_mfma_f32_16x16x32_bf16(alf, bh[j], acc[i][j], 0, 0, 0);
      }
    }
    asm volatile("s_barrier" ::: "memory");
  }
  #pragma unroll
  for(int i = 0; i < 4; ++i){
    #pragma unroll
    for(int j = 0; j < 4; ++j){
      int col = n0 + wn * 64 + j * 16 + lr;
      if(col >= NCK) continue;
      float bv = bias2[col];
      #pragma unroll
      for(int r2 = 0; r2 < 4; ++r2){
        int row = m0 + wm * 64 + i * 16 + lk * 4 + r2;
        if(row < NTOT) C[(size_t)row * NCK + col] = acc[i][j][r2] + bv;
      }
    }
  }
  // ---- pooled partials (indexed by logical tile h, not h0) ----
  float* psh = (float*)lds;
  int rb = ((m0 / NPATCH) + 1) * NPATCH;
  #pragma unroll
  for(int j = 0; j < 4; ++j){
    float s0 = 0.f, s1 = 0.f;
    #pragma unroll
    for(int i = 0; i < 4; ++i)
      #pragma unroll
      for(int r2 = 0; r2 < 4; ++r2){
        int row = m0 + wm * 64 + i * 16 + lk * 4 + r2;
        float v = acc[i][j][r2];
        if(row < rb) s0 += v; else s1 += v;
      }
    s0 += __shfl_xor(s0, 16); s0 += __shfl_xor(s0, 32);
    s1 += __shfl_xor(s1, 16); s1 += __shfl_xor(s1, 32);
    if(lk == 0){
      int cslot = wn * 64 + j * 16 + lr;
      if(wm == 0){ psh[cslot] = s0; psh[256 + cslot] = s1; }
      else        { psh[512 + cslot] = s0; psh[768 + cslot] = s1; }
    }
  }
  __syncthreads();
  if(t < 256){
    float* pp = poolPart + (size_t)h * 512;
    pp[t] = psh[t] + psh[512 + t];
    pp[256 + t] = psh[256 + t] + psh[768 + t];
  }
}

// ---------------- per-class masked Sinkhorn (rank computed in-block) ----------------
__global__ __launch_bounds__(256) void k_sinkhorn(const float* __restrict__ logits,
    const int* __restrict__ pl, const int* __restrict__ counts,
    const int* __restrict__ labels, float* __restrict__ Aw, float* __restrict__ assign_out){
  int c = blockIdx.x;
  int NcI = counts[c];
  if(NcI == 0) return;
  __shared__ int imgs[BIMG];
  __shared__ int nimgS;
  __shared__ float sh[256];
  int t = threadIdx.x;
  if(t == 0){
    int ni = 0;
    for(int b = 0; b < BIMG; ++b) if(labels[b] == c) imgs[ni++] = b;
    nimgS = ni;
  }
  __syncthreads();
  float prf = (t < NCLS && t < c && counts[t] > 0) ? 1.f : 0.f;
  int rankc = (int)(red256(prf, sh) + 0.5f);
  int tot = nimgS * NPATCH;
  float Ncf = (float)NcI;
  float invNc = 1.0f / Ncf;

  float sp = 0.f;
  #pragma unroll 4
  for(int ii = t; ii < tot; ii += 256){
    int n = imgs[ii / NPATCH] * NPATCH + (ii % NPATCH);
    if(pl[n] != c) continue;
    const float* lg = logits + (size_t)n * NCK + c * KP;
    float* aw = Aw + (size_t)n * KP;
    float l0 = expf(lg[0] / 0.05f), l1 = expf(lg[1] / 0.05f), l2 = expf(lg[2] / 0.05f),
          l3 = expf(lg[3] / 0.05f), l4 = expf(lg[4] / 0.05f);
    aw[0] = l0; aw[1] = l1; aw[2] = l2; aw[3] = l3; aw[4] = l4;
    sp += l0 + l1 + l2 + l3 + l4;
  }
  float S = red256(sp, sh);
  float sc = 1.0f / (S + 1e-16f);

  float cs0 = 0, cs1 = 0, cs2 = 0, cs3 = 0, cs4 = 0;
  #pragma unroll 4
  for(int ii = t; ii < tot; ii += 256){
    int n = imgs[ii / NPATCH] * NPATCH + (ii % NPATCH);
    if(pl[n] != c) continue;
    float* aw = Aw + (size_t)n * KP;
    float l0 = aw[0]*sc, l1 = aw[1]*sc, l2 = aw[2]*sc, l3 = aw[3]*sc, l4 = aw[4]*sc;
    aw[0] = l0; aw[1] = l1; aw[2] = l2; aw[3] = l3; aw[4] = l4;
    cs0 += l0; cs1 += l1; cs2 += l2; cs3 += l3; cs4 += l4;
  }
  cs0 = red256(cs0, sh); cs1 = red256(cs1, sh); cs2 = red256(cs2, sh);
  cs3 = red256(cs3, sh); cs4 = red256(cs4, sh);

  for(int it = 0; it < 3; ++it){
    float m0 = 1.0f/(cs0+1e-16f), m1 = 1.0f/(cs1+1e-16f), m2 = 1.0f/(cs2+1e-16f),
          m3 = 1.0f/(cs3+1e-16f), m4 = 1.0f/(cs4+1e-16f);
    bool last = (it == 2);
    float n0 = 0, n1 = 0, n2 = 0, n3 = 0, n4 = 0;
    #pragma unroll 4
    for(int ii = t; ii < tot; ii += 256){
      int n = imgs[ii / NPATCH] * NPATCH + (ii % NPATCH);
      if(pl[n] != c) continue;
      float* aw = Aw + (size_t)n * KP;
      float l0 = aw[0]*m0*0.2f, l1 = aw[1]*m1*0.2f, l2 = aw[2]*m2*0.2f,
            l3 = aw[3]*m3*0.2f, l4 = aw[4]*m4*0.2f;
      float rs = l0 + l1 + l2 + l3 + l4;
      float rw = 1.0f / (rs + 1e-16f);
      if(last){
        l0 *= rw; l1 *= rw; l2 *= rw; l3 *= rw; l4 *= rw;
        aw[0] = l0; aw[1] = l1; aw[2] = l2; aw[3] = l3; aw[4] = l4;
        int am = 0; float bv = l0;
        if(l1 > bv){ bv = l1; am = 1; }
        if(l2 > bv){ bv = l2; am = 2; }
        if(l3 > bv){ bv = l3; am = 3; }
        if(l4 > bv){ bv = l4; am = 4; }
        assign_out[n] = (float)(am + KP * rankc);
      } else {
        float w2 = rw * invNc;
        l0 *= w2; l1 *= w2; l2 *= w2; l3 *= w2; l4 *= w2;
        aw[0] = l0; aw[1] = l1; aw[2] = l2; aw[3] = l3; aw[4] = l4;
        n0 += l0; n1 += l1; n2 += l2; n3 += l3; n4 += l4;
      }
    }
    if(!last){
      cs0 = red256(n0, sh); cs1 = red256(n1, sh); cs2 = red256(n2, sh);
      cs3 = red256(n3, sh); cs4 = red256(n4, sh);
    }
  }
}

// ---------------- P_new partial sums (USEA: read bf16 normalized rows) ----------------
template<int USEA>
__global__ __launch_bounds__(256) void k_pnew_part(const float* __restrict__ X,
    const float* __restrict__ rinv, const unsigned short* __restrict__ Ahi,
    const float* __restrict__ Aw,
    const int* __restrict__ pl, const int* __restrict__ labels,
    float* __restrict__ part){
  int b = blockIdx.y, ch = blockIdx.x;
  int c = labels[b];
  int t = threadIdx.x;
  int j0 = ch * 86, j1 = j0 + 86; if(j1 > NPATCH) j1 = NPATCH;
  float acc[3][5] = {};
  #pragma unroll 2
  for(int j = j0; j < j1; ++j){
    int n = b * NPATCH + j;
    if(pl[n] != c) continue;
    const float* aw = Aw + (size_t)n * KP;
    float a0 = aw[0], a1 = aw[1], a2 = aw[2], a3 = aw[3], a4 = aw[4];
    float rv = USEA ? 1.0f : rinv[n];
    #pragma unroll
    for(int dj = 0; dj < 3; ++dj){
      float x;
      if(USEA) x = bf2f(Ahi[(size_t)n * DIM + t + dj * 256]);
      else     x = X[(size_t)n * DIM + t + dj * 256] * rv;
      acc[dj][0] += a0 * x; acc[dj][1] += a1 * x; acc[dj][2] += a2 * x;
      acc[dj][3] += a3 * x; acc[dj][4] += a4 * x;
    }
  }
  float* po = part + ((size_t)(b * PCH + ch)) * KP * DIM;
  #pragma unroll
  for(int k = 0; k < 5; ++k)
    #pragma unroll
    for(int dj = 0; dj < 3; ++dj)
      po[k * DIM + t + dj * 256] = acc[dj][k];
}

// ---------------- fused tail: P_new final (blocks 0..200) + pooled gather + sa head (blocks 201..216) ----------------
__global__ __launch_bounds__(256) void k_tailm(const float* __restrict__ P,
    const float* __restrict__ part, const int* __restrict__ counts,
    const int* __restrict__ labels, float* __restrict__ out_np,
    const float* __restrict__ poolPart, const float* __restrict__ bias2,
    const float* __restrict__ sa, float* __restrict__ pooled, float* __restrict__ out){
  __shared__ float ps[1024];
  __shared__ int imgs[BIMG];
  __shared__ int nimgS;
  int t = threadIdx.x;
  if(blockIdx.x < CDIM){
    int c = blockIdx.x;
    bool pres = (c < NCLS) && (counts[c] > 0);
    const float* Pc = P + (size_t)c * KP * DIM;
    float* Oc = out_np + (size_t)c * KP * DIM;
    if(!pres){
      for(int i = t; i < KP * DIM; i += 256) Oc[i] = Pc[i];
      return;
    }
    if(t == 0){
      int ni = 0;
      for(int b = 0; b < BIMG; ++b) if(labels[b] == c) imgs[ni++] = b;
      nimgS = ni;
    }
    __syncthreads();
    int ni = nimgS;
    for(int i = t; i < KP * DIM; i += 256){
      float s = 0.f;
      for(int q = 0; q < ni; ++q){
        const float* pb = part + ((size_t)(imgs[q] * PCH)) * KP * DIM + i;
        #pragma unroll 16
        for(int ch = 0; ch < PCH; ++ch) s += pb[(size_t)ch * KP * DIM];
      }
      Oc[i] = 0.99f * Pc[i] + 0.01f * s;
    }
  } else {
    int b = blockIdx.x - CDIM;
    int mt_lo = (b * NPATCH) >> 7;
    int mt_hi = ((b + 1) * NPATCH - 1) >> 7;
    #pragma unroll
    for(int g = 0; g < 4; ++g){
      int col = g * 256 + t;
      float s = 0.f;
      for(int mt = mt_lo; mt <= mt_hi; ++mt){
        int img0 = (mt * 128) / NPATCH;
        int buck = (img0 == b) ? 0 : 1;
        s += poolPart[((size_t)(mt * 4 + g)) * 512 + buck * 256 + t];
      }
      float pv = s / 1369.0f + ((col < NCK) ? bias2[col] : 0.f);
      if(col < NCK) pooled[(size_t)b * NCK + col] = pv;
      ps[col] = pv;
    }
    __syncthreads();
    if(t < NCLS){
      float sa0 = sa[t*5+0], sa1 = sa[t*5+1], sa2 = sa[t*5+2], sa3 = sa[t*5+3], sa4 = sa[t*5+4];
      float mx = fmaxf(fmaxf(fmaxf(sa0, sa1), fmaxf(sa2, sa3)), sa4);
      float e0 = expf(sa0 - mx), e1 = expf(sa1 - mx), e2 = expf(sa2 - mx),
            e3 = expf(sa3 - mx), e4 = expf(sa4 - mx);
      float se = e0 + e1 + e2 + e3 + e4;
      float iv = 5.0f / se;
      const float* p = ps + t * KP;
      out[b * NCLS + t] = p[0]*e0*iv + p[1]*e1*iv + p[2]*e2*iv + p[3]*e3*iv + p[4]*e4*iv;
    }
  }
}

// ---------------- P_new final (fallback) ----------------
__global__ __launch_bounds__(256) void k_pnew_fin(const float* __restrict__ P,
    const float* __restrict__ part, const int* __restrict__ counts,
    const int* __restrict__ labels, float* __restrict__ out_np){
  int c = blockIdx.x;
  int t = threadIdx.x;
  bool pres = (c < NCLS) && (counts[c] > 0);
  const float* Pc = P + (size_t)c * KP * DIM;
  float* Oc = out_np + (size_t)c * KP * DIM;
  if(!pres){
    for(int i = t; i < KP * DIM; i += 256) Oc[i] = Pc[i];
    return;
  }
  __shared__ int imgs[BIMG];
  __shared__ int nimgS;
  if(t == 0){
    int ni = 0;
    for(int b = 0; b < BIMG; ++b) if(labels[b] == c) imgs[ni++] = b;
    nimgS = ni;
  }
  __syncthreads();
  int ni = nimgS;
  for(int i = t; i < KP * DIM; i += 256){
    float s = 0.f;
    for(int q = 0; q < ni; ++q){
      const float* pb = part + ((size_t)(imgs[q] * PCH)) * KP * DIM + i;
      for(int ch = 0; ch < PCH; ++ch) s += pb[(size_t)ch * KP * DIM];
    }
    Oc[i] = 0.99f * Pc[i] + 0.01f * s;
  }
}

// ---------------- pooled stage 1 (fallback only) ----------------
__global__ __launch_bounds__(256) void k_pool1(const float* __restrict__ logits,
    float* __restrict__ poolPart){
  int b = blockIdx.y, ch = blockIdx.x;
  int t = threadIdx.x;
  int j0 = ch * 43, j1 = j0 + 43; if(j1 > NPATCH) j1 = NPATCH;
  float a0 = 0, a1 = 0, a2 = 0, a3 = 0;
  for(int j = j0; j < j1; ++j){
    const float* row = logits + ((size_t)(b * NPATCH + j)) * NCK;
    a0 += row[t]; a1 += row[t + 256]; a2 += row[t + 512];
    if(t < 237) a3 += row[t + 768];
  }
  float* po = poolPart + ((size_t)(b * QCH + ch)) * 1024;
  po[t] = a0; po[t + 256] = a1; po[t + 512] = a2;
  if(t < 237) po[t + 768] = a3;
}

// ---------------- pooled stage 2 + sa head (fallback) ----------------
__global__ __launch_bounds__(256) void k_pool2cls(const float* __restrict__ poolPart,
    const float* __restrict__ bias2, const float* __restrict__ sa,
    float* __restrict__ pooled, float* __restrict__ out){
  __shared__ float ps[1024];
  int b = blockIdx.x;
  int t = threadIdx.x;
  float s0 = 0, s1 = 0, s2 = 0, s3 = 0;
  const float* pb = poolPart + ((size_t)(b * QCH)) * 1024;
  for(int ch = 0; ch < QCH; ++ch){
    const float* p = pb + (size_t)ch * 1024;
    s0 += p[t]; s1 += p[t + 256]; s2 += p[t + 512];
    if(t < 237) s3 += p[t + 768];
  }
  float* o = pooled + (size_t)b * NCK;
  float o0 = s0 / 1369.0f, o1 = s1 / 1369.0f, o2 = s2 / 1369.0f, o3 = s3 / 1369.0f;
  o[t] = o0; o[t + 256] = o1; o[t + 512] = o2;
  if(t < 237) o[t + 768] = o3;
  ps[t] = o0; ps[t + 256] = o1; ps[t + 512] = o2;
  if(t < 237) ps[t + 768] = o3;
  __syncthreads();
  if(t < NCLS){
    float sa0 = sa[t*5+0], sa1 = sa[t*5+1], sa2 = sa[t*5+2], sa3 = sa[t*5+3], sa4 = sa[t*5+4];
    float mx = fmaxf(fmaxf(fmaxf(sa0, sa1), fmaxf(sa2, sa3)), sa4);
    float e0 = expf(sa0 - mx), e1 = expf(sa1 - mx), e2 = expf(sa2 - mx),
          e3 = expf(sa3 - mx), e4 = expf(sa4 - mx);
    float se = e0 + e1 + e2 + e3 + e4;
    float iv = 5.0f / se;
    const float* p = ps + t * KP;
    out[b * NCLS + t] = p[0]*e0*iv + p[1]*e1*iv + p[2]*e2*iv + p[3]*e3*iv + p[4]*e4*iv;
  }
}

extern "C" void kernel_launch(void* const* d_in, const int* in_sizes, int n_in,
                              void* d_out, int out_size, void* d_ws, size_t ws_size,
                              hipStream_t stream){
  const float* X      = (const float*)d_in[0];
  const int*   labels = (const int*)d_in[1];
  const float* P      = (const float*)d_in[2];
  const float* W      = (const float*)d_in[3];
  const float* bvec   = (const float*)d_in[4];
  const float* sa     = (const float*)d_in[5];

  float* out        = (float*)d_out;
  float* out_cls    = out;
  float* out_logits = out + 3200;
  float* out_pooled = out_logits + (size_t)NTOT * NCK;
  float* out_assign = out_pooled + BIMG * NCK;
  float* out_np     = out_assign + NTOT;
  float* out_pseudo = out_np + (size_t)CDIM * KP * DIM;

  const size_t AHI_F = (size_t)MPAD * DIM / 2;   // ushort array in float units
  const size_t BHI_F = (size_t)1024 * DIM / 2;
  const size_t MFMA_F = 2 * AHI_F + 2 * BHI_F;
  const size_t BASE_F = 4050000;
  bool use_mfma = ws_size >= (MFMA_F + BASE_F) * sizeof(float);

  float* ws = (float*)d_ws;
  unsigned short* Ahi = (unsigned short*)ws;
  unsigned short* Alo = (unsigned short*)(ws + AHI_F);
  unsigned short* Bhi = (unsigned short*)(ws + 2 * AHI_F);
  unsigned short* Blo = (unsigned short*)(ws + 2 * AHI_F + BHI_F);
  float* base = use_mfma ? (ws + MFMA_F) : ws;

  float* protn  = base;
  float* Bmat   = protn + (size_t)NCK * DIM;
  float* bias2  = Bmat + (size_t)NCK * DIM;
  float* rinv   = bias2 + 1024;
  float* uvec   = rinv + NTOT;
  float* Aw     = uvec + NTOT;
  float* meanv  = Aw + (size_t)NTOT * KP;
  float* wvb    = meanv + DIM;
  float* pbuf   = wvb + DIM;
  float* subuf  = pbuf + (size_t)UCH * DIM;
  float* parts  = subuf + UCH;
  float* scal   = parts + 32;
  int*   pli    = (int*)(scal + 8);
  int*   counts = pli + NTOT;
  float* pnewP  = (float*)(counts + 256);
  float* poolP  = pnewP + (size_t)BIMG * PCH * KP * DIM;
  unsigned* enc = (unsigned*)(scal + 1);

  k_colmean1<<<512, 256, 0, stream>>>(X, pbuf);
  k_meanred<<<12, 256, 0, stream>>>(pbuf, meanv, wvb, parts, counts, enc);
  for(int i = 0; i < 10; ++i){
    k_pcapass<<<UCH, 256, 0, stream>>>(X, wvb, parts, pbuf, subuf);
    k_pcared<<<12, 256, 0, stream>>>(pbuf, subuf, meanv, wvb, parts);
  }
  if(use_mfma){
    k_ufinal<1><<<UCH, 256, 0, stream>>>(X, wvb, parts, uvec, enc, rinv, Ahi, Alo);
  } else {
    k_ufinal<0><<<UCH, 256, 0, stream>>>(X, wvb, parts, uvec, enc, nullptr, nullptr, nullptr);
    k_rnorm<<<5476, 256, 0, stream>>>(X, rinv);
  }
  k_pseudo<<<86, 256, 0, stream>>>(uvec, enc, labels, pli, out_pseudo, out_assign, counts);
  k_protn<<<252, 256, 0, stream>>>(P, bvec, protn, bias2);
  if(use_mfma){
    k_gemm_nt<0, 0, 1, 1><<<dim3(12, 16), 256, 0, stream>>>(protn, W, Bmat, nullptr, nullptr,
                                                            protn, Bhi, Blo, NCK, DIM, DIM);
    k_gemm_mfma<<<688, 512, 0, stream>>>(Ahi, Alo, Bhi, Blo, bias2, out_logits, poolP);
  } else {
    k_gemm_nt<0, 0, 1, 0><<<dim3(12, 16), 256, 0, stream>>>(protn, W, Bmat, nullptr, nullptr,
                                                            protn, nullptr, nullptr, NCK, DIM, DIM);
    k_gemm_nt<1, 1, 0, 0><<<dim3(16, 343), 256, 0, stream>>>(X, Bmat, out_logits, rinv, bias2,
                                                             nullptr, nullptr, nullptr, NTOT, NCK, DIM);
  }
  k_sinkhorn<<<NCLS, 256, 0, stream>>>(out_logits, pli, counts, labels, Aw, out_assign);
  if(use_mfma){
    k_pnew_part<1><<<dim3(PCH, BIMG), 256, 0, stream>>>(nullptr, nullptr, Ahi, Aw, pli, labels, pnewP);
    k_tailm<<<CDIM + BIMG, 256, 0, stream>>>(P, pnewP, counts, labels, out_np,
                                             poolP, bias2, sa, out_pooled, out_cls);
  } else {
    k_pnew_part<0><<<dim3(PCH, BIMG), 256, 0, stream>>>(X, rinv, nullptr, Aw, pli, labels, pnewP);
    k_pnew_fin<<<CDIM, 256, 0, stream>>>(P, pnewP, counts, labels, out_np);
    k_pool1<<<dim3(QCH, BIMG), 256, 0, stream>>>(out_logits, poolP);
    k_pool2cls<<<BIMG, 256, 0, stream>>>(poolP, bias2, sa, out_pooled, out_cls);
  }
}

// Round 15
// 687.128 us; speedup vs baseline: 1.0109x; 1.0109x over previous
//
#include <hip/hip_runtime.h>

#define NTOT 21904
#define MPAD 22016
#define NPATCH 1369
#define BIMG 16
#define DIM 768
#define NCLS 200
#define CDIM 201
#define KP 5
#define NCK 1005
#define PCH 16   // pnew patch chunks per image
#define QCH 32   // pool patch chunks per image (fallback)
#define UCH 1024 // pca pass partial chunks

typedef short bf16x8 __attribute__((ext_vector_type(8)));
typedef float f32x4v __attribute__((ext_vector_type(4)));

__device__ __forceinline__ unsigned encf(float x){
  unsigned b = __float_as_uint(x);
  return (b & 0x80000000u) ? ~b : (b | 0x80000000u);
}
__device__ __forceinline__ float decf(unsigned e){
  return (e & 0x80000000u) ? __uint_as_float(e ^ 0x80000000u) : __uint_as_float(~e);
}
__device__ __forceinline__ unsigned short f2bf(float f){
  unsigned u = __float_as_uint(f);
  u += 0x7FFFu + ((u >> 16) & 1u);
  return (unsigned short)(u >> 16);
}
__device__ __forceinline__ float bf2f(unsigned short h){
  return __uint_as_float(((unsigned)h) << 16);
}
__device__ __forceinline__ void gload16(const unsigned short* g, unsigned short* l){
  __builtin_amdgcn_global_load_lds(
      (const __attribute__((address_space(1))) unsigned int*)g,
      (__attribute__((address_space(3))) unsigned int*)l, 16, 0, 0);
}

__device__ __forceinline__ float red256(float v, float* sh){
  int t = threadIdx.x;
  sh[t] = v; __syncthreads();
  for(int s = 128; s > 0; s >>= 1){ if(t < s) sh[t] += sh[t+s]; __syncthreads(); }
  float r = sh[0]; __syncthreads();
  return r;
}

// ---------------- column sums, 512 chunks x 43 rows (FROZEN ORDER; unroll = load batching only) ----------------
__global__ __launch_bounds__(256) void k_colmean1(const float* __restrict__ X, float* __restrict__ pbuf){
  int b = blockIdx.x, t = threadIdx.x;
  int n0 = b * 43, n1 = n0 + 43; if(n1 > NTOT) n1 = NTOT;
  float s0 = 0.f, s1 = 0.f, s2 = 0.f;
  #pragma unroll 4
  for(int n = n0; n < n1; ++n){
    const float* row = X + (size_t)n * DIM;
    s0 += row[t]; s1 += row[t + 256]; s2 += row[t + 512];
  }
  float* pb = pbuf + (size_t)b * DIM;
  pb[t] = s0; pb[t + 256] = s1; pb[t + 512] = s2;
}

// ---------------- mean + wv init + 12-way parts; also init counts/enc (FROZEN ORDER; ILP unroll) ----------------
__global__ __launch_bounds__(256) void k_meanred(const float* __restrict__ pbuf,
    float* __restrict__ meanv, float* __restrict__ wvb, float* __restrict__ parts,
    int* __restrict__ counts, unsigned* __restrict__ enc){
  __shared__ float sh[256];
  int cg = blockIdx.x, t = threadIdx.x;
  if(cg == 0){
    if(t < CDIM) counts[t] = 0;
    if(t == 0){ enc[0] = 0xFFFFFFFFu; enc[1] = 0u; }
  }
  int tc = t & 63, th = t >> 6;
  int col = cg * 64 + tc;
  const float v0 = 0.036084391824351615f;   // 1/sqrt(768)
  float s = 0.f;
  #pragma unroll 32
  for(int ch = th; ch < 512; ch += 4) s += pbuf[ch * DIM + col];
  sh[t] = s; __syncthreads();
  float mcontrib = 0.f;
  if(th == 0){
    float m = (sh[tc] + sh[64 + tc] + sh[128 + tc] + sh[192 + tc]) / 21904.0f;
    meanv[col] = m;
    wvb[col] = v0;
    mcontrib = m * v0;
  }
  __syncthreads();
  float md = red256(mcontrib, sh);
  if(t == 0){ parts[cg] = 64.0f * v0 * v0; parts[16 + cg] = md; }
}

// ---------------- power-iteration pass (FROZEN ORDER; unroll-3 for MLP, bit-identical accumulation) ----------------
__global__ __launch_bounds__(256) void k_pcapass(const float* __restrict__ X,
    const float* __restrict__ wvb, const float* __restrict__ parts,
    float* __restrict__ pbuf, float* __restrict__ subuf){
  __shared__ float shacc[4][DIM];
  __shared__ float shsu[4];
  int t = threadIdx.x, w = t >> 6, l = t & 63;
  float nrm2 = 0.f, mvr = 0.f;
  #pragma unroll
  for(int i = 0; i < 12; ++i){ nrm2 += parts[i]; mvr += parts[16 + i]; }
  float invD = 1.0f / (sqrtf(nrm2) + 1e-12f);
  const float4* v4 = (const float4*)(wvb + l * 12);
  float4 v0 = v4[0], v1 = v4[1], v2 = v4[2];
  float4 a0 = {0,0,0,0}, a1 = {0,0,0,0}, a2 = {0,0,0,0};
  float su = 0.f;
  int n = blockIdx.x * 4 + w;
  while(n + 8192 < NTOT){
    const float4* xa4 = (const float4*)(X + (size_t)n * DIM + l * 12);
    const float4* xb4 = (const float4*)(X + (size_t)(n + 4096) * DIM + l * 12);
    const float4* xc4 = (const float4*)(X + (size_t)(n + 8192) * DIM + l * 12);
    float4 xa0 = xa4[0], xa1 = xa4[1], xa2 = xa4[2];
    float4 xb0 = xb4[0], xb1 = xb4[1], xb2 = xb4[2];
    float4 xc0 = xc4[0], xc1 = xc4[1], xc2 = xc4[2];
    float tpA = xa0.x*v0.x + xa0.y*v0.y + xa0.z*v0.z + xa0.w*v0.w
              + xa1.x*v1.x + xa1.y*v1.y + xa1.z*v1.z + xa1.w*v1.w
              + xa2.x*v2.x + xa2.y*v2.y + xa2.z*v2.z + xa2.w*v2.w;
    float tpB = xb0.x*v0.x + xb0.y*v0.y + xb0.z*v0.z + xb0.w*v0.w
              + xb1.x*v1.x + xb1.y*v1.y + xb1.z*v1.z + xb1.w*v1.w
              + xb2.x*v2.x + xb2.y*v2.y + xb2.z*v2.z + xb2.w*v2.w;
    float tpC = xc0.x*v0.x + xc0.y*v0.y + xc0.z*v0.z + xc0.w*v0.w
              + xc1.x*v1.x + xc1.y*v1.y + xc1.z*v1.z + xc1.w*v1.w
              + xc2.x*v2.x + xc2.y*v2.y + xc2.z*v2.z + xc2.w*v2.w;
    #pragma unroll
    for(int o = 32; o > 0; o >>= 1){
      tpA += __shfl_xor(tpA, o);
      tpB += __shfl_xor(tpB, o);
      tpC += __shfl_xor(tpC, o);
    }
    tpA = (tpA - mvr) * invD;
    tpB = (tpB - mvr) * invD;
    tpC = (tpC - mvr) * invD;
    a0.x += tpA*xa0.x; a0.y += tpA*xa0.y; a0.z += tpA*xa0.z; a0.w += tpA*xa0.w;
    a1.x += tpA*xa1.x; a1.y += tpA*xa1.y; a1.z += tpA*xa1.z; a1.w += tpA*xa1.w;
    a2.x += tpA*xa2.x; a2.y += tpA*xa2.y; a2.z += tpA*xa2.z; a2.w += tpA*xa2.w;
    a0.x += tpB*xb0.x; a0.y += tpB*xb0.y; a0.z += tpB*xb0.z; a0.w += tpB*xb0.w;
    a1.x += tpB*xb1.x; a1.y += tpB*xb1.y; a1.z += tpB*xb1.z; a1.w += tpB*xb1.w;
    a2.x += tpB*xb2.x; a2.y += tpB*xb2.y; a2.z += tpB*xb2.z; a2.w += tpB*xb2.w;
    a0.x += tpC*xc0.x; a0.y += tpC*xc0.y; a0.z += tpC*xc0.z; a0.w += tpC*xc0.w;
    a1.x += tpC*xc1.x; a1.y += tpC*xc1.y; a1.z += tpC*xc1.z; a1.w += tpC*xc1.w;
    a2.x += tpC*xc2.x; a2.y += tpC*xc2.y; a2.z += tpC*xc2.z; a2.w += tpC*xc2.w;
    if(l == 0){ su += tpA; su += tpB; su += tpC; }
    n += 12288;
  }
  while(n < NTOT){
    const float4* x4 = (const float4*)(X + (size_t)n * DIM + l * 12);
    float4 x0 = x4[0], x1 = x4[1], x2 = x4[2];
    float tp = x0.x*v0.x + x0.y*v0.y + x0.z*v0.z + x0.w*v0.w
             + x1.x*v1.x + x1.y*v1.y + x1.z*v1.z + x1.w*v1.w
             + x2.x*v2.x + x2.y*v2.y + x2.z*v2.z + x2.w*v2.w;
    #pragma unroll
    for(int o = 32; o > 0; o >>= 1) tp += __shfl_xor(tp, o);
    tp = (tp - mvr) * invD;
    a0.x += tp*x0.x; a0.y += tp*x0.y; a0.z += tp*x0.z; a0.w += tp*x0.w;
    a1.x += tp*x1.x; a1.y += tp*x1.y; a1.z += tp*x1.z; a1.w += tp*x1.w;
    a2.x += tp*x2.x; a2.y += tp*x2.y; a2.z += tp*x2.z; a2.w += tp*x2.w;
    if(l == 0) su += tp;
    n += 4096;
  }
  float4* sh4 = (float4*)&shacc[w][l * 12];
  sh4[0] = a0; sh4[1] = a1; sh4[2] = a2;
  if(l == 0) shsu[w] = su;
  __syncthreads();
  for(int c = t; c < DIM; c += 256)
    pbuf[blockIdx.x * DIM + c] = shacc[0][c] + shacc[1][c] + shacc[2][c] + shacc[3][c];
  if(t == 0) subuf[blockIdx.x] = shsu[0] + shsu[1] + shsu[2] + shsu[3];
}

// ---------------- reduce partials -> new wv + 12-way parts (FROZEN ORDER; ILP unroll 64) ----------------
__global__ __launch_bounds__(256) void k_pcared(const float* __restrict__ pbuf,
    const float* __restrict__ subuf, const float* __restrict__ meanv,
    float* __restrict__ wvb, float* __restrict__ parts){
  __shared__ float sh[256];
  int cg = blockIdx.x, t = threadIdx.x;
  float sv = subuf[t] + subuf[t + 256] + subuf[t + 512] + subuf[t + 768];
  float su = red256(sv, sh);
  int tc = t & 63, th = t >> 6;
  int col = cg * 64 + tc;
  float s = 0.f;
  #pragma unroll 64
  for(int ch = th; ch < UCH; ch += 4) s += pbuf[(size_t)ch * DIM + col];
  sh[t] = s; __syncthreads();
  float csq = 0.f, cmd = 0.f;
  if(th == 0){
    float wvn = (sh[tc] + sh[64 + tc] + sh[128 + tc] + sh[192 + tc]) - meanv[col] * su;
    wvb[col] = wvn;
    csq = wvn * wvn;
    cmd = meanv[col] * wvn;
  }
  __syncthreads();
  float sq = red256(csq, sh);
  float md = red256(cmd, sh);
  if(t == 0){ parts[cg] = sq; parts[16 + cg] = md; }
}

// ---------------- final u = Xc v + min/max; PREP: fused rinv + bf16 hi/lo split (FROZEN) ----------------
template<int PREP>
__global__ __launch_bounds__(256) void k_ufinal(const float* __restrict__ X,
    const float* __restrict__ wvb, const float* __restrict__ parts,
    float* __restrict__ u, unsigned* __restrict__ enc,
    float* __restrict__ rinv, unsigned short* __restrict__ Ahi, unsigned short* __restrict__ Alo){
  __shared__ float smn[4], smx[4];
  int t = threadIdx.x, w = t >> 6, l = t & 63;
  float nrm2 = 0.f, mvr = 0.f;
  #pragma unroll
  for(int i = 0; i < 12; ++i){ nrm2 += parts[i]; mvr += parts[16 + i]; }
  float invD = 1.0f / (sqrtf(nrm2) + 1e-12f);
  const float4* v4 = (const float4*)(wvb + l * 12);
  float4 v0 = v4[0], v1 = v4[1], v2 = v4[2];
  float lmn = 3.4e38f, lmx = -3.4e38f;
  int nend = PREP ? MPAD : NTOT;
  for(int n = blockIdx.x * 4 + w; n < nend; n += 4096){
    size_t off = (size_t)n * DIM + l * 12;
    if(PREP && n >= NTOT){
      ushort4 z = make_ushort4(0, 0, 0, 0);
      #pragma unroll
      for(int j = 0; j < 3; ++j){
        *(ushort4*)(Ahi + off + j * 4) = z;
        *(ushort4*)(Alo + off + j * 4) = z;
      }
      continue;
    }
    const float4* x4 = (const float4*)(X + off);
    float4 x0 = x4[0], x1 = x4[1], x2 = x4[2];
    float tp = x0.x*v0.x + x0.y*v0.y + x0.z*v0.z + x0.w*v0.w
             + x1.x*v1.x + x1.y*v1.y + x1.z*v1.z + x1.w*v1.w
             + x2.x*v2.x + x2.y*v2.y + x2.z*v2.z + x2.w*v2.w;
    #pragma unroll
    for(int o = 32; o > 0; o >>= 1) tp += __shfl_xor(tp, o);
    tp = (tp - mvr) * invD;
    if(l == 0){ u[n] = tp; lmn = fminf(lmn, tp); lmx = fmaxf(lmx, tp); }
    if(PREP){
      float s = x0.x*x0.x + x0.y*x0.y + x0.z*x0.z + x0.w*x0.w
              + x1.x*x1.x + x1.y*x1.y + x1.z*x1.z + x1.w*x1.w
              + x2.x*x2.x + x2.y*x2.y + x2.z*x2.z + x2.w*x2.w;
      #pragma unroll
      for(int o = 32; o > 0; o >>= 1) s += __shfl_xor(s, o);
      float rv = 1.0f / (sqrtf(s) + 1e-12f);
      if(l == 0) rinv[n] = rv;
      float xs[12] = {x0.x*rv, x0.y*rv, x0.z*rv, x0.w*rv,
                      x1.x*rv, x1.y*rv, x1.z*rv, x1.w*rv,
                      x2.x*rv, x2.y*rv, x2.z*rv, x2.w*rv};
      unsigned short hi[12], lo[12];
      #pragma unroll
      for(int j = 0; j < 12; ++j){
        hi[j] = f2bf(xs[j]);
        lo[j] = f2bf(xs[j] - bf2f(hi[j]));
      }
      #pragma unroll
      for(int j = 0; j < 3; ++j){
        *(ushort4*)(Ahi + off + j * 4) = make_ushort4(hi[j*4], hi[j*4+1], hi[j*4+2], hi[j*4+3]);
        *(ushort4*)(Alo + off + j * 4) = make_ushort4(lo[j*4], lo[j*4+1], lo[j*4+2], lo[j*4+3]);
      }
    }
  }
  if(l == 0){ smn[w] = lmn; smx[w] = lmx; }
  __syncthreads();
  if(t == 0){
    float mn = fminf(fminf(smn[0], smn[1]), fminf(smn[2], smn[3]));
    float mx = fmaxf(fmaxf(smx[0], smx[1]), fmaxf(smx[2], smx[3]));
    atomicMin(&enc[0], encf(mn));
    atomicMax(&enc[1], encf(mx));
  }
}

// ---------------- pseudo labels (FROZEN) ----------------
__global__ __launch_bounds__(256) void k_pseudo(const float* __restrict__ u,
    const unsigned* __restrict__ enc, const int* __restrict__ labels,
    int* __restrict__ pl, float* __restrict__ pseudo_out,
    float* __restrict__ assign_out, int* __restrict__ counts){
  int n = blockIdx.x * 256 + threadIdx.x;
  if(n >= NTOT) return;
  float mn = decf(enc[0]), mx = decf(enc[1]);
  float us = (u[n] - mn) / (mx - mn);
  int b = n / NPATCH;
  int p = (us <= 0.5f) ? labels[b] : NCLS;
  pl[n] = p;
  pseudo_out[n] = (float)p;
  assign_out[n] = -1.0f;
  atomicAdd(&counts[p], 1);
}

// ---------------- row norms (fallback path) ----------------
__global__ __launch_bounds__(256) void k_rnorm(const float* __restrict__ X, float* __restrict__ rinv){
  int t = threadIdx.x, w = t >> 6, l = t & 63;
  int n = blockIdx.x * 4 + w;
  if(n >= NTOT) return;
  const float4* x4 = (const float4*)(X + (size_t)n * DIM + l * 12);
  float4 x0 = x4[0], x1 = x4[1], x2 = x4[2];
  float s = x0.x*x0.x + x0.y*x0.y + x0.z*x0.z + x0.w*x0.w
          + x1.x*x1.x + x1.y*x1.y + x1.z*x1.z + x1.w*x1.w
          + x2.x*x2.x + x2.y*x2.y + x2.z*x2.z + x2.w*x2.w;
  #pragma unroll
  for(int o = 32; o > 0; o >>= 1) s += __shfl_xor(s, o);
  if(l == 0) rinv[n] = 1.0f / (sqrtf(s) + 1e-12f);
}

// ---------------- normalized prototypes + bias2 ----------------
__global__ __launch_bounds__(256) void k_protn(const float* __restrict__ P,
    const float* __restrict__ bvec, float* __restrict__ protn, float* __restrict__ bias2){
  int t = threadIdx.x, w = t >> 6, l = t & 63;
  int r = blockIdx.x * 4 + w;
  if(r >= NCK) return;
  const float4* x4 = (const float4*)(P + (size_t)r * DIM + l * 12);
  float4 x0 = x4[0], x1 = x4[1], x2 = x4[2];
  float s = x0.x*x0.x + x0.y*x0.y + x0.z*x0.z + x0.w*x0.w
          + x1.x*x1.x + x1.y*x1.y + x1.z*x1.z + x1.w*x1.w
          + x2.x*x2.x + x2.y*x2.y + x2.z*x2.z + x2.w*x2.w;
  #pragma unroll
  for(int o = 32; o > 0; o >>= 1) s += __shfl_xor(s, o);
  float rv = 1.0f / (sqrtf(s) + 1e-12f);
  x0.x *= rv; x0.y *= rv; x0.z *= rv; x0.w *= rv;
  x1.x *= rv; x1.y *= rv; x1.z *= rv; x1.w *= rv;
  x2.x *= rv; x2.y *= rv; x2.z *= rv; x2.w *= rv;
  float4* o4 = (float4*)(protn + (size_t)r * DIM + l * 12);
  o4[0] = x0; o4[1] = x1; o4[2] = x2;
  const float4* b4 = (const float4*)(bvec + l * 12);
  float4 b0 = b4[0], b1 = b4[1], b2 = b4[2];
  float bb = b0.x*x0.x + b0.y*x0.y + b0.z*x0.z + b0.w*x0.w
           + b1.x*x1.x + b1.y*x1.y + b1.z*x1.z + b1.w*x1.w
           + b2.x*x2.x + b2.y*x2.y + b2.z*x2.z + b2.w*x2.w;
  #pragma unroll
  for(int o = 32; o > 0; o >>= 1) bb += __shfl_xor(bb, o);
  if(l == 0) bias2[r] = bb;
}

// ---------------- f32 NT GEMM; BF16OUT also emits hi/lo split (rows padded to 1024) ----------------
template<int HAS_SCALE, int HAS_BIAS, int HAS_ADD, int BF16OUT>
__global__ __launch_bounds__(256) void k_gemm_nt(const float* __restrict__ A,
    const float* __restrict__ B, float* __restrict__ C,
    const float* __restrict__ rowScale, const float* __restrict__ colBias,
    const float* __restrict__ addMat, unsigned short* __restrict__ Bh,
    unsigned short* __restrict__ Bl, int M, int N, int K){
  __shared__ float As[32][72];
  __shared__ float Bs[32][72];
  int t = threadIdx.x;
  int m0 = blockIdx.y * 64, n0 = blockIdx.x * 64;
  int srow = t >> 2, skq = (t & 3) * 8;
  int ty = t >> 4, tx = t & 15;
  int i0 = ty * 4, j0 = tx * 4;
  float acc[4][4] = {};
  int gra = m0 + srow; bool va = gra < M;
  int grb = n0 + srow; bool vb = grb < N;
  float scale = 1.0f;
  if(HAS_SCALE && va) scale = rowScale[gra];
  const float* Aptr = A + (size_t)gra * K + skq;
  const float* Bptr = B + (size_t)grb * K + skq;
  for(int k0 = 0; k0 < K; k0 += 32){
    float4 a0 = {0,0,0,0}, a1 = {0,0,0,0}, b0 = {0,0,0,0}, b1 = {0,0,0,0};
    if(va){ a0 = *(const float4*)(Aptr + k0); a1 = *(const float4*)(Aptr + k0 + 4); }
    if(vb){ b0 = *(const float4*)(Bptr + k0); b1 = *(const float4*)(Bptr + k0 + 4); }
    if(HAS_SCALE){
      a0.x *= scale; a0.y *= scale; a0.z *= scale; a0.w *= scale;
      a1.x *= scale; a1.y *= scale; a1.z *= scale; a1.w *= scale;
    }
    __syncthreads();
    As[skq+0][srow] = a0.x; As[skq+1][srow] = a0.y; As[skq+2][srow] = a0.z; As[skq+3][srow] = a0.w;
    As[skq+4][srow] = a1.x; As[skq+5][srow] = a1.y; As[skq+6][srow] = a1.z; As[skq+7][srow] = a1.w;
    Bs[skq+0][srow] = b0.x; Bs[skq+1][srow] = b0.y; Bs[skq+2][srow] = b0.z; Bs[skq+3][srow] = b0.w;
    Bs[skq+4][srow] = b1.x; Bs[skq+5][srow] = b1.y; Bs[skq+6][srow] = b1.z; Bs[skq+7][srow] = b1.w;
    __syncthreads();
    #pragma unroll
    for(int kk = 0; kk < 32; ++kk){
      float4 avv = *(const float4*)&As[kk][i0];
      float4 bvv = *(const float4*)&Bs[kk][j0];
      float a_[4] = {avv.x, avv.y, avv.z, avv.w};
      float b_[4] = {bvv.x, bvv.y, bvv.z, bvv.w};
      #pragma unroll
      for(int i = 0; i < 4; ++i)
        #pragma unroll
        for(int j = 0; j < 4; ++j)
          acc[i][j] += a_[i] * b_[j];
    }
  }
  #pragma unroll
  for(int i = 0; i < 4; ++i){
    int gr = m0 + i0 + i;
    #pragma unroll
    for(int j = 0; j < 4; ++j){
      int gc = n0 + j0 + j;
      if(gc >= N) continue;
      float v2 = 0.f;
      if(gr < M){
        v2 = acc[i][j];
        if(HAS_BIAS) v2 += colBias[gc];
        if(HAS_ADD) v2 += addMat[(size_t)gr * N + gc];
        C[(size_t)gr * N + gc] = v2;
      }
      if(BF16OUT && gr < 1024){
        unsigned short h = f2bf(v2);
        Bh[(size_t)gr * N + gc] = h;
        Bl[(size_t)gr * N + gc] = f2bf(v2 - bf2f(h));
      }
    }
  }
}

// ---------------- MFMA split-bf16 main GEMM: 128x256, triple-buffer, XCD-swizzled ----------------
__global__ __launch_bounds__(512, 1) void k_gemm_mfma(
    const unsigned short* __restrict__ Ahi, const unsigned short* __restrict__ Alo,
    const unsigned short* __restrict__ Bhi, const unsigned short* __restrict__ Blo,
    const float* __restrict__ bias2, float* __restrict__ C, float* __restrict__ poolPart){
  __shared__ __align__(16) unsigned short lds[73728];   // 144 KB = 3 buffers
  int h0 = blockIdx.x;
  int h = (h0 & 7) * 86 + (h0 >> 3);   // bijective XCD swizzle: 688 = 8 * 86 (T1)
  int nt = h & 3, mt = h >> 2;
  int m0 = mt * 128, n0 = nt * 256;
  int t = threadIdx.x;
  int w = t >> 6, l = t & 63;
  int wm = w >> 2, wn = w & 3;
  int lr = l & 15, lk = l >> 4;

  const unsigned short* gptr[6];
  int dofs[6];
  #pragma unroll
  for(int s = 0; s < 6; ++s){
    int cc = w * 6 + s;
    int r = (cc < 8) ? 0 : (cc < 16) ? 1 : (cc < 32) ? 2 : 3;
    int cc0 = (r == 0) ? 0 : (r == 1) ? 8 : (r == 2) ? 16 : 32;
    int regofs = (r == 0) ? 0 : (r == 1) ? 4096 : (r == 2) ? 8192 : 16384;
    int cloc = cc - cc0;
    int rloc = cloc * 16 + (l >> 2);
    int q = (l & 3) ^ ((rloc >> 1) & 3);
    const unsigned short* gs = (r == 0) ? Ahi : (r == 1) ? Alo : (r == 2) ? Bhi : Blo;
    int rbase = (r < 2) ? m0 : n0;
    gptr[s] = gs + (size_t)(rbase + rloc) * DIM + q * 8;
    dofs[s] = regofs + cloc * 512;
  }

  f32x4v acc[4][4];
  #pragma unroll
  for(int i = 0; i < 4; ++i)
    #pragma unroll
    for(int j = 0; j < 4; ++j) acc[i][j] = (f32x4v){0.f, 0.f, 0.f, 0.f};

  int aofs[4], bofs[4];
  #pragma unroll
  for(int f = 0; f < 4; ++f){
    int ar = wm * 64 + f * 16 + lr;
    aofs[f] = ar * 32 + (lk ^ ((ar >> 1) & 3)) * 8;
    int bc = wn * 64 + f * 16 + lr;
    bofs[f] = bc * 32 + (lk ^ ((bc >> 1) & 3)) * 8;
  }

  #pragma unroll
  for(int s = 0; s < 6; ++s) gload16(gptr[s], lds + dofs[s]);
  #pragma unroll
  for(int s = 0; s < 6; ++s) gload16(gptr[s] + 32, lds + 24576 + dofs[s]);

  const int NT = DIM / 32;  // 24
  for(int k = 0; k < NT; ++k){
    int k0 = k * 32;
    if(k + 2 < NT){
      unsigned short* dst = lds + ((k + 2) % 3) * 24576;
      #pragma unroll
      for(int s = 0; s < 6; ++s)
        gload16(gptr[s] + k0 + 64, dst + dofs[s]);
      asm volatile("s_waitcnt vmcnt(12)" ::: "memory");
    } else if(k + 1 < NT){
      asm volatile("s_waitcnt vmcnt(6)" ::: "memory");
    } else {
      asm volatile("s_waitcnt vmcnt(0)" ::: "memory");
    }
    asm volatile("s_barrier" ::: "memory");
    const unsigned short* Lb = lds + (k % 3) * 24576;
    bf16x8 bh[4], bl[4];
    #pragma unroll
    for(int f = 0; f < 4; ++f){
      bh[f] = *(const bf16x8*)&Lb[8192 + bofs[f]];
      bl[f] = *(const bf16x8*)&Lb[16384 + bofs[f]];
    }
    #pragma unroll
    for(int i = 0; i < 4; ++i){
      bf16x8 ahf = *(const bf16x8*)&Lb[aofs[i]];
      bf16x8 alf = *(const bf16x8*)&Lb[4096 + aofs[i]];
      #pragma unroll
      for(int j = 0; j < 4; ++j){
        acc[i][j] = __builtin_amdgcn_mfma_f32_16x16x32_bf16(ahf, bh[j], acc[i][j], 0, 0, 0);
        acc[i][j] = __builtin_amdgcn_mfma_f32_16x16x32_bf16(ahf, bl[j], acc[i][j], 0, 0, 0);
        acc[i][j] = __builtin_amdgcn_mfma_f32_16x16x32_bf16(alf, bh[j], acc[i][j], 0, 0, 0);
      }
    }
    asm volatile("s_barrier" ::: "memory");
  }
  #pragma unroll
  for(int i = 0; i < 4; ++i){
    #pragma unroll
    for(int j = 0; j < 4; ++j){
      int col = n0 + wn * 64 + j * 16 + lr;
      if(col >= NCK) continue;
      float bv = bias2[col];
      #pragma unroll
      for(int r2 = 0; r2 < 4; ++r2){
        int row = m0 + wm * 64 + i * 16 + lk * 4 + r2;
        if(row < NTOT) C[(size_t)row * NCK + col] = acc[i][j][r2] + bv;
      }
    }
  }
  // ---- pooled partials (indexed by logical tile h, not h0) ----
  float* psh = (float*)lds;
  int rb = ((m0 / NPATCH) + 1) * NPATCH;
  #pragma unroll
  for(int j = 0; j < 4; ++j){
    float s0 = 0.f, s1 = 0.f;
    #pragma unroll
    for(int i = 0; i < 4; ++i)
      #pragma unroll
      for(int r2 = 0; r2 < 4; ++r2){
        int row = m0 + wm * 64 + i * 16 + lk * 4 + r2;
        float v = acc[i][j][r2];
        if(row < rb) s0 += v; else s1 += v;
      }
    s0 += __shfl_xor(s0, 16); s0 += __shfl_xor(s0, 32);
    s1 += __shfl_xor(s1, 16); s1 += __shfl_xor(s1, 32);
    if(lk == 0){
      int cslot = wn * 64 + j * 16 + lr;
      if(wm == 0){ psh[cslot] = s0; psh[256 + cslot] = s1; }
      else        { psh[512 + cslot] = s0; psh[768 + cslot] = s1; }
    }
  }
  __syncthreads();
  if(t < 256){
    float* pp = poolPart + (size_t)h * 512;
    pp[t] = psh[t] + psh[512 + t];
    pp[256 + t] = psh[256 + t] + psh[768 + t];
  }
}

// ---------------- per-class masked Sinkhorn (rank computed in-block) ----------------
__global__ __launch_bounds__(256) void k_sinkhorn(const float* __restrict__ logits,
    const int* __restrict__ pl, const int* __restrict__ counts,
    const int* __restrict__ labels, float* __restrict__ Aw, float* __restrict__ assign_out){
  int c = blockIdx.x;
  int NcI = counts[c];
  if(NcI == 0) return;
  __shared__ int imgs[BIMG];
  __shared__ int nimgS;
  __shared__ float sh[256];
  int t = threadIdx.x;
  if(t == 0){
    int ni = 0;
    for(int b = 0; b < BIMG; ++b) if(labels[b] == c) imgs[ni++] = b;
    nimgS = ni;
  }
  __syncthreads();
  float prf = (t < NCLS && t < c && counts[t] > 0) ? 1.f : 0.f;
  int rankc = (int)(red256(prf, sh) + 0.5f);
  int tot = nimgS * NPATCH;
  float Ncf = (float)NcI;
  float invNc = 1.0f / Ncf;

  float sp = 0.f;
  for(int ii = t; ii < tot; ii += 256){
    int n = imgs[ii / NPATCH] * NPATCH + (ii % NPATCH);
    if(pl[n] != c) continue;
    const float* lg = logits + (size_t)n * NCK + c * KP;
    float* aw = Aw + (size_t)n * KP;
    float l0 = expf(lg[0] / 0.05f), l1 = expf(lg[1] / 0.05f), l2 = expf(lg[2] / 0.05f),
          l3 = expf(lg[3] / 0.05f), l4 = expf(lg[4] / 0.05f);
    aw[0] = l0; aw[1] = l1; aw[2] = l2; aw[3] = l3; aw[4] = l4;
    sp += l0 + l1 + l2 + l3 + l4;
  }
  float S = red256(sp, sh);
  float sc = 1.0f / (S + 1e-16f);

  float cs0 = 0, cs1 = 0, cs2 = 0, cs3 = 0, cs4 = 0;
  for(int ii = t; ii < tot; ii += 256){
    int n = imgs[ii / NPATCH] * NPATCH + (ii % NPATCH);
    if(pl[n] != c) continue;
    float* aw = Aw + (size_t)n * KP;
    float l0 = aw[0]*sc, l1 = aw[1]*sc, l2 = aw[2]*sc, l3 = aw[3]*sc, l4 = aw[4]*sc;
    aw[0] = l0; aw[1] = l1; aw[2] = l2; aw[3] = l3; aw[4] = l4;
    cs0 += l0; cs1 += l1; cs2 += l2; cs3 += l3; cs4 += l4;
  }
  cs0 = red256(cs0, sh); cs1 = red256(cs1, sh); cs2 = red256(cs2, sh);
  cs3 = red256(cs3, sh); cs4 = red256(cs4, sh);

  for(int it = 0; it < 3; ++it){
    float m0 = 1.0f/(cs0+1e-16f), m1 = 1.0f/(cs1+1e-16f), m2 = 1.0f/(cs2+1e-16f),
          m3 = 1.0f/(cs3+1e-16f), m4 = 1.0f/(cs4+1e-16f);
    bool last = (it == 2);
    float n0 = 0, n1 = 0, n2 = 0, n3 = 0, n4 = 0;
    for(int ii = t; ii < tot; ii += 256){
      int n = imgs[ii / NPATCH] * NPATCH + (ii % NPATCH);
      if(pl[n] != c) continue;
      float* aw = Aw + (size_t)n * KP;
      float l0 = aw[0]*m0*0.2f, l1 = aw[1]*m1*0.2f, l2 = aw[2]*m2*0.2f,
            l3 = aw[3]*m3*0.2f, l4 = aw[4]*m4*0.2f;
      float rs = l0 + l1 + l2 + l3 + l4;
      float rw = 1.0f / (rs + 1e-16f);
      if(last){
        l0 *= rw; l1 *= rw; l2 *= rw; l3 *= rw; l4 *= rw;
        aw[0] = l0; aw[1] = l1; aw[2] = l2; aw[3] = l3; aw[4] = l4;
        int am = 0; float bv = l0;
        if(l1 > bv){ bv = l1; am = 1; }
        if(l2 > bv){ bv = l2; am = 2; }
        if(l3 > bv){ bv = l3; am = 3; }
        if(l4 > bv){ bv = l4; am = 4; }
        assign_out[n] = (float)(am + KP * rankc);
      } else {
        float w2 = rw * invNc;
        l0 *= w2; l1 *= w2; l2 *= w2; l3 *= w2; l4 *= w2;
        aw[0] = l0; aw[1] = l1; aw[2] = l2; aw[3] = l3; aw[4] = l4;
        n0 += l0; n1 += l1; n2 += l2; n3 += l3; n4 += l4;
      }
    }
    if(!last){
      cs0 = red256(n0, sh); cs1 = red256(n1, sh); cs2 = red256(n2, sh);
      cs3 = red256(n3, sh); cs4 = red256(n4, sh);
    }
  }
}

// ---------------- P_new partial sums (USEA: read bf16 normalized rows) ----------------
template<int USEA>
__global__ __launch_bounds__(256) void k_pnew_part(const float* __restrict__ X,
    const float* __restrict__ rinv, const unsigned short* __restrict__ Ahi,
    const float* __restrict__ Aw,
    const int* __restrict__ pl, const int* __restrict__ labels,
    float* __restrict__ part){
  int b = blockIdx.y, ch = blockIdx.x;
  int c = labels[b];
  int t = threadIdx.x;
  int j0 = ch * 86, j1 = j0 + 86; if(j1 > NPATCH) j1 = NPATCH;
  float acc[3][5] = {};
  for(int j = j0; j < j1; ++j){
    int n = b * NPATCH + j;
    if(pl[n] != c) continue;
    const float* aw = Aw + (size_t)n * KP;
    float a0 = aw[0], a1 = aw[1], a2 = aw[2], a3 = aw[3], a4 = aw[4];
    float rv = USEA ? 1.0f : rinv[n];
    #pragma unroll
    for(int dj = 0; dj < 3; ++dj){
      float x;
      if(USEA) x = bf2f(Ahi[(size_t)n * DIM + t + dj * 256]);
      else     x = X[(size_t)n * DIM + t + dj * 256] * rv;
      acc[dj][0] += a0 * x; acc[dj][1] += a1 * x; acc[dj][2] += a2 * x;
      acc[dj][3] += a3 * x; acc[dj][4] += a4 * x;
    }
  }
  float* po = part + ((size_t)(b * PCH + ch)) * KP * DIM;
  #pragma unroll
  for(int k = 0; k < 5; ++k)
    #pragma unroll
    for(int dj = 0; dj < 3; ++dj)
      po[k * DIM + t + dj * 256] = acc[dj][k];
}

// ---------------- fused tail: P_new final (blocks 0..200) + pooled gather + sa head (blocks 201..216) ----------------
__global__ __launch_bounds__(256) void k_tailm(const float* __restrict__ P,
    const float* __restrict__ part, const int* __restrict__ counts,
    const int* __restrict__ labels, float* __restrict__ out_np,
    const float* __restrict__ poolPart, const float* __restrict__ bias2,
    const float* __restrict__ sa, float* __restrict__ pooled, float* __restrict__ out){
  __shared__ float ps[1024];
  __shared__ int imgs[BIMG];
  __shared__ int nimgS;
  int t = threadIdx.x;
  if(blockIdx.x < CDIM){
    int c = blockIdx.x;
    bool pres = (c < NCLS) && (counts[c] > 0);
    const float* Pc = P + (size_t)c * KP * DIM;
    float* Oc = out_np + (size_t)c * KP * DIM;
    if(!pres){
      for(int i = t; i < KP * DIM; i += 256) Oc[i] = Pc[i];
      return;
    }
    if(t == 0){
      int ni = 0;
      for(int b = 0; b < BIMG; ++b) if(labels[b] == c) imgs[ni++] = b;
      nimgS = ni;
    }
    __syncthreads();
    int ni = nimgS;
    for(int i = t; i < KP * DIM; i += 256){
      float s = 0.f;
      for(int q = 0; q < ni; ++q){
        const float* pb = part + ((size_t)(imgs[q] * PCH)) * KP * DIM + i;
        for(int ch = 0; ch < PCH; ++ch) s += pb[(size_t)ch * KP * DIM];
      }
      Oc[i] = 0.99f * Pc[i] + 0.01f * s;
    }
  } else {
    int b = blockIdx.x - CDIM;
    int mt_lo = (b * NPATCH) >> 7;
    int mt_hi = ((b + 1) * NPATCH - 1) >> 7;
    #pragma unroll
    for(int g = 0; g < 4; ++g){
      int col = g * 256 + t;
      float s = 0.f;
      for(int mt = mt_lo; mt <= mt_hi; ++mt){
        int img0 = (mt * 128) / NPATCH;
        int buck = (img0 == b) ? 0 : 1;
        s += poolPart[((size_t)(mt * 4 + g)) * 512 + buck * 256 + t];
      }
      float pv = s / 1369.0f + ((col < NCK) ? bias2[col] : 0.f);
      if(col < NCK) pooled[(size_t)b * NCK + col] = pv;
      ps[col] = pv;
    }
    __syncthreads();
    if(t < NCLS){
      float sa0 = sa[t*5+0], sa1 = sa[t*5+1], sa2 = sa[t*5+2], sa3 = sa[t*5+3], sa4 = sa[t*5+4];
      float mx = fmaxf(fmaxf(fmaxf(sa0, sa1), fmaxf(sa2, sa3)), sa4);
      float e0 = expf(sa0 - mx), e1 = expf(sa1 - mx), e2 = expf(sa2 - mx),
            e3 = expf(sa3 - mx), e4 = expf(sa4 - mx);
      float se = e0 + e1 + e2 + e3 + e4;
      float iv = 5.0f / se;
      const float* p = ps + t * KP;
      out[b * NCLS + t] = p[0]*e0*iv + p[1]*e1*iv + p[2]*e2*iv + p[3]*e3*iv + p[4]*e4*iv;
    }
  }
}

// ---------------- P_new final (fallback) ----------------
__global__ __launch_bounds__(256) void k_pnew_fin(const float* __restrict__ P,
    const float* __restrict__ part, const int* __restrict__ counts,
    const int* __restrict__ labels, float* __restrict__ out_np){
  int c = blockIdx.x;
  int t = threadIdx.x;
  bool pres = (c < NCLS) && (counts[c] > 0);
  const float* Pc = P + (size_t)c * KP * DIM;
  float* Oc = out_np + (size_t)c * KP * DIM;
  if(!pres){
    for(int i = t; i < KP * DIM; i += 256) Oc[i] = Pc[i];
    return;
  }
  __shared__ int imgs[BIMG];
  __shared__ int nimgS;
  if(t == 0){
    int ni = 0;
    for(int b = 0; b < BIMG; ++b) if(labels[b] == c) imgs[ni++] = b;
    nimgS = ni;
  }
  __syncthreads();
  int ni = nimgS;
  for(int i = t; i < KP * DIM; i += 256){
    float s = 0.f;
    for(int q = 0; q < ni; ++q){
      const float* pb = part + ((size_t)(imgs[q] * PCH)) * KP * DIM + i;
      for(int ch = 0; ch < PCH; ++ch) s += pb[(size_t)ch * KP * DIM];
    }
    Oc[i] = 0.99f * Pc[i] + 0.01f * s;
  }
}

// ---------------- pooled stage 1 (fallback only) ----------------
__global__ __launch_bounds__(256) void k_pool1(const float* __restrict__ logits,
    float* __restrict__ poolPart){
  int b = blockIdx.y, ch = blockIdx.x;
  int t = threadIdx.x;
  int j0 = ch * 43, j1 = j0 + 43; if(j1 > NPATCH) j1 = NPATCH;
  float a0 = 0, a1 = 0, a2 = 0, a3 = 0;
  for(int j = j0; j < j1; ++j){
    const float* row = logits + ((size_t)(b * NPATCH + j)) * NCK;
    a0 += row[t]; a1 += row[t + 256]; a2 += row[t + 512];
    if(t < 237) a3 += row[t + 768];
  }
  float* po = poolPart + ((size_t)(b * QCH + ch)) * 1024;
  po[t] = a0; po[t + 256] = a1; po[t + 512] = a2;
  if(t < 237) po[t + 768] = a3;
}

// ---------------- pooled stage 2 + sa head (fallback) ----------------
__global__ __launch_bounds__(256) void k_pool2cls(const float* __restrict__ poolPart,
    const float* __restrict__ bias2, const float* __restrict__ sa,
    float* __restrict__ pooled, float* __restrict__ out){
  __shared__ float ps[1024];
  int b = blockIdx.x;
  int t = threadIdx.x;
  float s0 = 0, s1 = 0, s2 = 0, s3 = 0;
  const float* pb = poolPart + ((size_t)(b * QCH)) * 1024;
  for(int ch = 0; ch < QCH; ++ch){
    const float* p = pb + (size_t)ch * 1024;
    s0 += p[t]; s1 += p[t + 256]; s2 += p[t + 512];
    if(t < 237) s3 += p[t + 768];
  }
  float* o = pooled + (size_t)b * NCK;
  float o0 = s0 / 1369.0f, o1 = s1 / 1369.0f, o2 = s2 / 1369.0f, o3 = s3 / 1369.0f;
  o[t] = o0; o[t + 256] = o1; o[t + 512] = o2;
  if(t < 237) o[t + 768] = o3;
  ps[t] = o0; ps[t + 256] = o1; ps[t + 512] = o2;
  if(t < 237) ps[t + 768] = o3;
  __syncthreads();
  if(t < NCLS){
    float sa0 = sa[t*5+0], sa1 = sa[t*5+1], sa2 = sa[t*5+2], sa3 = sa[t*5+3], sa4 = sa[t*5+4];
    float mx = fmaxf(fmaxf(fmaxf(sa0, sa1), fmaxf(sa2, sa3)), sa4);
    float e0 = expf(sa0 - mx), e1 = expf(sa1 - mx), e2 = expf(sa2 - mx),
          e3 = expf(sa3 - mx), e4 = expf(sa4 - mx);
    float se = e0 + e1 + e2 + e3 + e4;
    float iv = 5.0f / se;
    const float* p = ps + t * KP;
    out[b * NCLS + t] = p[0]*e0*iv + p[1]*e1*iv + p[2]*e2*iv + p[3]*e3*iv + p[4]*e4*iv;
  }
}

extern "C" void kernel_launch(void* const* d_in, const int* in_sizes, int n_in,
                              void* d_out, int out_size, void* d_ws, size_t ws_size,
                              hipStream_t stream){
  const float* X      = (const float*)d_in[0];
  const int*   labels = (const int*)d_in[1];
  const float* P      = (const float*)d_in[2];
  const float* W      = (const float*)d_in[3];
  const float* bvec   = (const float*)d_in[4];
  const float* sa     = (const float*)d_in[5];

  float* out        = (float*)d_out;
  float* out_cls    = out;
  float* out_logits = out + 3200;
  float* out_pooled = out_logits + (size_t)NTOT * NCK;
  float* out_assign = out_pooled + BIMG * NCK;
  float* out_np     = out_assign + NTOT;
  float* out_pseudo = out_np + (size_t)CDIM * KP * DIM;

  const size_t AHI_F = (size_t)MPAD * DIM / 2;   // ushort array in float units
  const size_t BHI_F = (size_t)1024 * DIM / 2;
  const size_t MFMA_F = 2 * AHI_F + 2 * BHI_F;
  const size_t BASE_F = 4050000;
  bool use_mfma = ws_size >= (MFMA_F + BASE_F) * sizeof(float);

  float* ws = (float*)d_ws;
  unsigned short* Ahi = (unsigned short*)ws;
  unsigned short* Alo = (unsigned short*)(ws + AHI_F);
  unsigned short* Bhi = (unsigned short*)(ws + 2 * AHI_F);
  unsigned short* Blo = (unsigned short*)(ws + 2 * AHI_F + BHI_F);
  float* base = use_mfma ? (ws + MFMA_F) : ws;

  float* protn  = base;
  float* Bmat   = protn + (size_t)NCK * DIM;
  float* bias2  = Bmat + (size_t)NCK * DIM;
  float* rinv   = bias2 + 1024;
  float* uvec   = rinv + NTOT;
  float* Aw     = uvec + NTOT;
  float* meanv  = Aw + (size_t)NTOT * KP;
  float* wvb    = meanv + DIM;
  float* pbuf   = wvb + DIM;
  float* subuf  = pbuf + (size_t)UCH * DIM;
  float* parts  = subuf + UCH;
  float* scal   = parts + 32;
  int*   pli    = (int*)(scal + 8);
  int*   counts = pli + NTOT;
  float* pnewP  = (float*)(counts + 256);
  float* poolP  = pnewP + (size_t)BIMG * PCH * KP * DIM;
  unsigned* enc = (unsigned*)(scal + 1);

  k_colmean1<<<512, 256, 0, stream>>>(X, pbuf);
  k_meanred<<<12, 256, 0, stream>>>(pbuf, meanv, wvb, parts, counts, enc);
  for(int i = 0; i < 10; ++i){
    k_pcapass<<<UCH, 256, 0, stream>>>(X, wvb, parts, pbuf, subuf);
    k_pcared<<<12, 256, 0, stream>>>(pbuf, subuf, meanv, wvb, parts);
  }
  if(use_mfma){
    k_ufinal<1><<<UCH, 256, 0, stream>>>(X, wvb, parts, uvec, enc, rinv, Ahi, Alo);
  } else {
    k_ufinal<0><<<UCH, 256, 0, stream>>>(X, wvb, parts, uvec, enc, nullptr, nullptr, nullptr);
    k_rnorm<<<5476, 256, 0, stream>>>(X, rinv);
  }
  k_pseudo<<<86, 256, 0, stream>>>(uvec, enc, labels, pli, out_pseudo, out_assign, counts);
  k_protn<<<252, 256, 0, stream>>>(P, bvec, protn, bias2);
  if(use_mfma){
    k_gemm_nt<0, 0, 1, 1><<<dim3(12, 16), 256, 0, stream>>>(protn, W, Bmat, nullptr, nullptr,
                                                            protn, Bhi, Blo, NCK, DIM, DIM);
    k_gemm_mfma<<<688, 512, 0, stream>>>(Ahi, Alo, Bhi, Blo, bias2, out_logits, poolP);
  } else {
    k_gemm_nt<0, 0, 1, 0><<<dim3(12, 16), 256, 0, stream>>>(protn, W, Bmat, nullptr, nullptr,
                                                            protn, nullptr, nullptr, NCK, DIM, DIM);
    k_gemm_nt<1, 1, 0, 0><<<dim3(16, 343), 256, 0, stream>>>(X, Bmat, out_logits, rinv, bias2,
                                                             nullptr, nullptr, nullptr, NTOT, NCK, DIM);
  }
  k_sinkhorn<<<NCLS, 256, 0, stream>>>(out_logits, pli, counts, labels, Aw, out_assign);
  if(use_mfma){
    k_pnew_part<1><<<dim3(PCH, BIMG), 256, 0, stream>>>(nullptr, nullptr, Ahi, Aw, pli, labels, pnewP);
    k_tailm<<<CDIM + BIMG, 256, 0, stream>>>(P, pnewP, counts, labels, out_np,
                                             poolP, bias2, sa, out_pooled, out_cls);
  } else {
    k_pnew_part<0><<<dim3(PCH, BIMG), 256, 0, stream>>>(X, rinv, nullptr, Aw, pli, labels, pnewP);
    k_pnew_fin<<<CDIM, 256, 0, stream>>>(P, pnewP, counts, labels, out_np);
    k_pool1<<<dim3(QCH, BIMG), 256, 0, stream>>>(out_logits, poolP);
    k_pool2cls<<<BIMG, 256, 0, stream>>>(poolP, bias2, sa, out_pooled, out_cls);
  }
}

// Round 16
// 676.614 us; speedup vs baseline: 1.0266x; 1.0155x over previous
//
#include <hip/hip_runtime.h>

#define NTOT 21904
#define MPAD 22016
#define NPATCH 1369
#define BIMG 16
#define DIM 768
#define NCLS 200
#define CDIM 201
#define KP 5
#define NCK 1005
#define PCH 16   // pnew patch chunks per image
#define QCH 32   // pool patch chunks per image (fallback)
#define UCH 1024 // pca pass partial chunks

typedef short bf16x8 __attribute__((ext_vector_type(8)));
typedef float f32x4v __attribute__((ext_vector_type(4)));

__device__ __forceinline__ unsigned encf(float x){
  unsigned b = __float_as_uint(x);
  return (b & 0x80000000u) ? ~b : (b | 0x80000000u);
}
__device__ __forceinline__ float decf(unsigned e){
  return (e & 0x80000000u) ? __uint_as_float(e ^ 0x80000000u) : __uint_as_float(~e);
}
__device__ __forceinline__ unsigned short f2bf(float f){
  unsigned u = __float_as_uint(f);
  u += 0x7FFFu + ((u >> 16) & 1u);
  return (unsigned short)(u >> 16);
}
__device__ __forceinline__ float bf2f(unsigned short h){
  return __uint_as_float(((unsigned)h) << 16);
}
__device__ __forceinline__ void gload16(const unsigned short* g, unsigned short* l){
  __builtin_amdgcn_global_load_lds(
      (const __attribute__((address_space(1))) unsigned int*)g,
      (__attribute__((address_space(3))) unsigned int*)l, 16, 0, 0);
}

__device__ __forceinline__ float red256(float v, float* sh){
  int t = threadIdx.x;
  sh[t] = v; __syncthreads();
  for(int s = 128; s > 0; s >>= 1){ if(t < s) sh[t] += sh[t+s]; __syncthreads(); }
  float r = sh[0]; __syncthreads();
  return r;
}

// ---------------- column sums, 512 chunks x 43 rows (FROZEN ORDER; unroll = load batching only) ----------------
__global__ __launch_bounds__(256) void k_colmean1(const float* __restrict__ X, float* __restrict__ pbuf){
  int b = blockIdx.x, t = threadIdx.x;
  int n0 = b * 43, n1 = n0 + 43; if(n1 > NTOT) n1 = NTOT;
  float s0 = 0.f, s1 = 0.f, s2 = 0.f;
  #pragma unroll 4
  for(int n = n0; n < n1; ++n){
    const float* row = X + (size_t)n * DIM;
    s0 += row[t]; s1 += row[t + 256]; s2 += row[t + 512];
  }
  float* pb = pbuf + (size_t)b * DIM;
  pb[t] = s0; pb[t + 256] = s1; pb[t + 512] = s2;
}

// ---------------- mean + wv init + 12-way parts; also init counts/enc (FROZEN ORDER; ILP unroll) ----------------
__global__ __launch_bounds__(256) void k_meanred(const float* __restrict__ pbuf,
    float* __restrict__ meanv, float* __restrict__ wvb, float* __restrict__ parts,
    int* __restrict__ counts, unsigned* __restrict__ enc){
  __shared__ float sh[256];
  int cg = blockIdx.x, t = threadIdx.x;
  if(cg == 0){
    if(t < CDIM) counts[t] = 0;
    if(t == 0){ enc[0] = 0xFFFFFFFFu; enc[1] = 0u; }
  }
  int tc = t & 63, th = t >> 6;
  int col = cg * 64 + tc;
  const float v0 = 0.036084391824351615f;   // 1/sqrt(768)
  float s = 0.f;
  #pragma unroll 32
  for(int ch = th; ch < 512; ch += 4) s += pbuf[ch * DIM + col];
  sh[t] = s; __syncthreads();
  float mcontrib = 0.f;
  if(th == 0){
    float m = (sh[tc] + sh[64 + tc] + sh[128 + tc] + sh[192 + tc]) / 21904.0f;
    meanv[col] = m;
    wvb[col] = v0;
    mcontrib = m * v0;
  }
  __syncthreads();
  float md = red256(mcontrib, sh);
  if(t == 0){ parts[cg] = 64.0f * v0 * v0; parts[16 + cg] = md; }
}

// ---------------- power-iteration pass (FROZEN ORDER; unroll-3 for MLP, bit-identical accumulation) ----------------
__global__ __launch_bounds__(256) void k_pcapass(const float* __restrict__ X,
    const float* __restrict__ wvb, const float* __restrict__ parts,
    float* __restrict__ pbuf, float* __restrict__ subuf){
  __shared__ float shacc[4][DIM];
  __shared__ float shsu[4];
  int t = threadIdx.x, w = t >> 6, l = t & 63;
  float nrm2 = 0.f, mvr = 0.f;
  #pragma unroll
  for(int i = 0; i < 12; ++i){ nrm2 += parts[i]; mvr += parts[16 + i]; }
  float invD = 1.0f / (sqrtf(nrm2) + 1e-12f);
  const float4* v4 = (const float4*)(wvb + l * 12);
  float4 v0 = v4[0], v1 = v4[1], v2 = v4[2];
  float4 a0 = {0,0,0,0}, a1 = {0,0,0,0}, a2 = {0,0,0,0};
  float su = 0.f;
  int n = blockIdx.x * 4 + w;
  while(n + 8192 < NTOT){
    const float4* xa4 = (const float4*)(X + (size_t)n * DIM + l * 12);
    const float4* xb4 = (const float4*)(X + (size_t)(n + 4096) * DIM + l * 12);
    const float4* xc4 = (const float4*)(X + (size_t)(n + 8192) * DIM + l * 12);
    float4 xa0 = xa4[0], xa1 = xa4[1], xa2 = xa4[2];
    float4 xb0 = xb4[0], xb1 = xb4[1], xb2 = xb4[2];
    float4 xc0 = xc4[0], xc1 = xc4[1], xc2 = xc4[2];
    float tpA = xa0.x*v0.x + xa0.y*v0.y + xa0.z*v0.z + xa0.w*v0.w
              + xa1.x*v1.x + xa1.y*v1.y + xa1.z*v1.z + xa1.w*v1.w
              + xa2.x*v2.x + xa2.y*v2.y + xa2.z*v2.z + xa2.w*v2.w;
    float tpB = xb0.x*v0.x + xb0.y*v0.y + xb0.z*v0.z + xb0.w*v0.w
              + xb1.x*v1.x + xb1.y*v1.y + xb1.z*v1.z + xb1.w*v1.w
              + xb2.x*v2.x + xb2.y*v2.y + xb2.z*v2.z + xb2.w*v2.w;
    float tpC = xc0.x*v0.x + xc0.y*v0.y + xc0.z*v0.z + xc0.w*v0.w
              + xc1.x*v1.x + xc1.y*v1.y + xc1.z*v1.z + xc1.w*v1.w
              + xc2.x*v2.x + xc2.y*v2.y + xc2.z*v2.z + xc2.w*v2.w;
    #pragma unroll
    for(int o = 32; o > 0; o >>= 1){
      tpA += __shfl_xor(tpA, o);
      tpB += __shfl_xor(tpB, o);
      tpC += __shfl_xor(tpC, o);
    }
    tpA = (tpA - mvr) * invD;
    tpB = (tpB - mvr) * invD;
    tpC = (tpC - mvr) * invD;
    a0.x += tpA*xa0.x; a0.y += tpA*xa0.y; a0.z += tpA*xa0.z; a0.w += tpA*xa0.w;
    a1.x += tpA*xa1.x; a1.y += tpA*xa1.y; a1.z += tpA*xa1.z; a1.w += tpA*xa1.w;
    a2.x += tpA*xa2.x; a2.y += tpA*xa2.y; a2.z += tpA*xa2.z; a2.w += tpA*xa2.w;
    a0.x += tpB*xb0.x; a0.y += tpB*xb0.y; a0.z += tpB*xb0.z; a0.w += tpB*xb0.w;
    a1.x += tpB*xb1.x; a1.y += tpB*xb1.y; a1.z += tpB*xb1.z; a1.w += tpB*xb1.w;
    a2.x += tpB*xb2.x; a2.y += tpB*xb2.y; a2.z += tpB*xb2.z; a2.w += tpB*xb2.w;
    a0.x += tpC*xc0.x; a0.y += tpC*xc0.y; a0.z += tpC*xc0.z; a0.w += tpC*xc0.w;
    a1.x += tpC*xc1.x; a1.y += tpC*xc1.y; a1.z += tpC*xc1.z; a1.w += tpC*xc1.w;
    a2.x += tpC*xc2.x; a2.y += tpC*xc2.y; a2.z += tpC*xc2.z; a2.w += tpC*xc2.w;
    if(l == 0){ su += tpA; su += tpB; su += tpC; }
    n += 12288;
  }
  while(n < NTOT){
    const float4* x4 = (const float4*)(X + (size_t)n * DIM + l * 12);
    float4 x0 = x4[0], x1 = x4[1], x2 = x4[2];
    float tp = x0.x*v0.x + x0.y*v0.y + x0.z*v0.z + x0.w*v0.w
             + x1.x*v1.x + x1.y*v1.y + x1.z*v1.z + x1.w*v1.w
             + x2.x*v2.x + x2.y*v2.y + x2.z*v2.z + x2.w*v2.w;
    #pragma unroll
    for(int o = 32; o > 0; o >>= 1) tp += __shfl_xor(tp, o);
    tp = (tp - mvr) * invD;
    a0.x += tp*x0.x; a0.y += tp*x0.y; a0.z += tp*x0.z; a0.w += tp*x0.w;
    a1.x += tp*x1.x; a1.y += tp*x1.y; a1.z += tp*x1.z; a1.w += tp*x1.w;
    a2.x += tp*x2.x; a2.y += tp*x2.y; a2.z += tp*x2.z; a2.w += tp*x2.w;
    if(l == 0) su += tp;
    n += 4096;
  }
  float4* sh4 = (float4*)&shacc[w][l * 12];
  sh4[0] = a0; sh4[1] = a1; sh4[2] = a2;
  if(l == 0) shsu[w] = su;
  __syncthreads();
  for(int c = t; c < DIM; c += 256)
    pbuf[blockIdx.x * DIM + c] = shacc[0][c] + shacc[1][c] + shacc[2][c] + shacc[3][c];
  if(t == 0) subuf[blockIdx.x] = shsu[0] + shsu[1] + shsu[2] + shsu[3];
}

// ---------------- reduce partials -> new wv + 12-way parts (FROZEN ORDER; ILP unroll 64) ----------------
__global__ __launch_bounds__(256) void k_pcared(const float* __restrict__ pbuf,
    const float* __restrict__ subuf, const float* __restrict__ meanv,
    float* __restrict__ wvb, float* __restrict__ parts){
  __shared__ float sh[256];
  int cg = blockIdx.x, t = threadIdx.x;
  float sv = subuf[t] + subuf[t + 256] + subuf[t + 512] + subuf[t + 768];
  float su = red256(sv, sh);
  int tc = t & 63, th = t >> 6;
  int col = cg * 64 + tc;
  float s = 0.f;
  #pragma unroll 64
  for(int ch = th; ch < UCH; ch += 4) s += pbuf[(size_t)ch * DIM + col];
  sh[t] = s; __syncthreads();
  float csq = 0.f, cmd = 0.f;
  if(th == 0){
    float wvn = (sh[tc] + sh[64 + tc] + sh[128 + tc] + sh[192 + tc]) - meanv[col] * su;
    wvb[col] = wvn;
    csq = wvn * wvn;
    cmd = meanv[col] * wvn;
  }
  __syncthreads();
  float sq = red256(csq, sh);
  float md = red256(cmd, sh);
  if(t == 0){ parts[cg] = sq; parts[16 + cg] = md; }
}

// ---------------- final u = Xc v + min/max; PREP: fused rinv + bf16 hi/lo split (FROZEN) ----------------
template<int PREP>
__global__ __launch_bounds__(256) void k_ufinal(const float* __restrict__ X,
    const float* __restrict__ wvb, const float* __restrict__ parts,
    float* __restrict__ u, unsigned* __restrict__ enc,
    float* __restrict__ rinv, unsigned short* __restrict__ Ahi, unsigned short* __restrict__ Alo){
  __shared__ float smn[4], smx[4];
  int t = threadIdx.x, w = t >> 6, l = t & 63;
  float nrm2 = 0.f, mvr = 0.f;
  #pragma unroll
  for(int i = 0; i < 12; ++i){ nrm2 += parts[i]; mvr += parts[16 + i]; }
  float invD = 1.0f / (sqrtf(nrm2) + 1e-12f);
  const float4* v4 = (const float4*)(wvb + l * 12);
  float4 v0 = v4[0], v1 = v4[1], v2 = v4[2];
  float lmn = 3.4e38f, lmx = -3.4e38f;
  int nend = PREP ? MPAD : NTOT;
  for(int n = blockIdx.x * 4 + w; n < nend; n += 4096){
    size_t off = (size_t)n * DIM + l * 12;
    if(PREP && n >= NTOT){
      ushort4 z = make_ushort4(0, 0, 0, 0);
      #pragma unroll
      for(int j = 0; j < 3; ++j){
        *(ushort4*)(Ahi + off + j * 4) = z;
        *(ushort4*)(Alo + off + j * 4) = z;
      }
      continue;
    }
    const float4* x4 = (const float4*)(X + off);
    float4 x0 = x4[0], x1 = x4[1], x2 = x4[2];
    float tp = x0.x*v0.x + x0.y*v0.y + x0.z*v0.z + x0.w*v0.w
             + x1.x*v1.x + x1.y*v1.y + x1.z*v1.z + x1.w*v1.w
             + x2.x*v2.x + x2.y*v2.y + x2.z*v2.z + x2.w*v2.w;
    #pragma unroll
    for(int o = 32; o > 0; o >>= 1) tp += __shfl_xor(tp, o);
    tp = (tp - mvr) * invD;
    if(l == 0){ u[n] = tp; lmn = fminf(lmn, tp); lmx = fmaxf(lmx, tp); }
    if(PREP){
      float s = x0.x*x0.x + x0.y*x0.y + x0.z*x0.z + x0.w*x0.w
              + x1.x*x1.x + x1.y*x1.y + x1.z*x1.z + x1.w*x1.w
              + x2.x*x2.x + x2.y*x2.y + x2.z*x2.z + x2.w*x2.w;
      #pragma unroll
      for(int o = 32; o > 0; o >>= 1) s += __shfl_xor(s, o);
      float rv = 1.0f / (sqrtf(s) + 1e-12f);
      if(l == 0) rinv[n] = rv;
      float xs[12] = {x0.x*rv, x0.y*rv, x0.z*rv, x0.w*rv,
                      x1.x*rv, x1.y*rv, x1.z*rv, x1.w*rv,
                      x2.x*rv, x2.y*rv, x2.z*rv, x2.w*rv};
      unsigned short hi[12], lo[12];
      #pragma unroll
      for(int j = 0; j < 12; ++j){
        hi[j] = f2bf(xs[j]);
        lo[j] = f2bf(xs[j] - bf2f(hi[j]));
      }
      #pragma unroll
      for(int j = 0; j < 3; ++j){
        *(ushort4*)(Ahi + off + j * 4) = make_ushort4(hi[j*4], hi[j*4+1], hi[j*4+2], hi[j*4+3]);
        *(ushort4*)(Alo + off + j * 4) = make_ushort4(lo[j*4], lo[j*4+1], lo[j*4+2], lo[j*4+3]);
      }
    }
  }
  if(l == 0){ smn[w] = lmn; smx[w] = lmx; }
  __syncthreads();
  if(t == 0){
    float mn = fminf(fminf(smn[0], smn[1]), fminf(smn[2], smn[3]));
    float mx = fmaxf(fmaxf(smx[0], smx[1]), fmaxf(smx[2], smx[3]));
    atomicMin(&enc[0], encf(mn));
    atomicMax(&enc[1], encf(mx));
  }
}

// ---------------- pseudo labels (FROZEN) ----------------
__global__ __launch_bounds__(256) void k_pseudo(const float* __restrict__ u,
    const unsigned* __restrict__ enc, const int* __restrict__ labels,
    int* __restrict__ pl, float* __restrict__ pseudo_out,
    float* __restrict__ assign_out, int* __restrict__ counts){
  int n = blockIdx.x * 256 + threadIdx.x;
  if(n >= NTOT) return;
  float mn = decf(enc[0]), mx = decf(enc[1]);
  float us = (u[n] - mn) / (mx - mn);
  int b = n / NPATCH;
  int p = (us <= 0.5f) ? labels[b] : NCLS;
  pl[n] = p;
  pseudo_out[n] = (float)p;
  assign_out[n] = -1.0f;
  atomicAdd(&counts[p], 1);
}

// ---------------- row norms (fallback path) ----------------
__global__ __launch_bounds__(256) void k_rnorm(const float* __restrict__ X, float* __restrict__ rinv){
  int t = threadIdx.x, w = t >> 6, l = t & 63;
  int n = blockIdx.x * 4 + w;
  if(n >= NTOT) return;
  const float4* x4 = (const float4*)(X + (size_t)n * DIM + l * 12);
  float4 x0 = x4[0], x1 = x4[1], x2 = x4[2];
  float s = x0.x*x0.x + x0.y*x0.y + x0.z*x0.z + x0.w*x0.w
          + x1.x*x1.x + x1.y*x1.y + x1.z*x1.z + x1.w*x1.w
          + x2.x*x2.x + x2.y*x2.y + x2.z*x2.z + x2.w*x2.w;
  #pragma unroll
  for(int o = 32; o > 0; o >>= 1) s += __shfl_xor(s, o);
  if(l == 0) rinv[n] = 1.0f / (sqrtf(s) + 1e-12f);
}

// ---------------- normalized prototypes + bias2 ----------------
__global__ __launch_bounds__(256) void k_protn(const float* __restrict__ P,
    const float* __restrict__ bvec, float* __restrict__ protn, float* __restrict__ bias2){
  int t = threadIdx.x, w = t >> 6, l = t & 63;
  int r = blockIdx.x * 4 + w;
  if(r >= NCK) return;
  const float4* x4 = (const float4*)(P + (size_t)r * DIM + l * 12);
  float4 x0 = x4[0], x1 = x4[1], x2 = x4[2];
  float s = x0.x*x0.x + x0.y*x0.y + x0.z*x0.z + x0.w*x0.w
          + x1.x*x1.x + x1.y*x1.y + x1.z*x1.z + x1.w*x1.w
          + x2.x*x2.x + x2.y*x2.y + x2.z*x2.z + x2.w*x2.w;
  #pragma unroll
  for(int o = 32; o > 0; o >>= 1) s += __shfl_xor(s, o);
  float rv = 1.0f / (sqrtf(s) + 1e-12f);
  x0.x *= rv; x0.y *= rv; x0.z *= rv; x0.w *= rv;
  x1.x *= rv; x1.y *= rv; x1.z *= rv; x1.w *= rv;
  x2.x *= rv; x2.y *= rv; x2.z *= rv; x2.w *= rv;
  float4* o4 = (float4*)(protn + (size_t)r * DIM + l * 12);
  o4[0] = x0; o4[1] = x1; o4[2] = x2;
  const float4* b4 = (const float4*)(bvec + l * 12);
  float4 b0 = b4[0], b1 = b4[1], b2 = b4[2];
  float bb = b0.x*x0.x + b0.y*x0.y + b0.z*x0.z + b0.w*x0.w
           + b1.x*x1.x + b1.y*x1.y + b1.z*x1.z + b1.w*x1.w
           + b2.x*x2.x + b2.y*x2.y + b2.z*x2.z + b2.w*x2.w;
  #pragma unroll
  for(int o = 32; o > 0; o >>= 1) bb += __shfl_xor(bb, o);
  if(l == 0) bias2[r] = bb;
}

// ---------------- f32 NT GEMM; BF16OUT also emits hi/lo split (rows padded to 1024) ----------------
template<int HAS_SCALE, int HAS_BIAS, int HAS_ADD, int BF16OUT>
__global__ __launch_bounds__(256) void k_gemm_nt(const float* __restrict__ A,
    const float* __restrict__ B, float* __restrict__ C,
    const float* __restrict__ rowScale, const float* __restrict__ colBias,
    const float* __restrict__ addMat, unsigned short* __restrict__ Bh,
    unsigned short* __restrict__ Bl, int M, int N, int K){
  __shared__ float As[32][72];
  __shared__ float Bs[32][72];
  int t = threadIdx.x;
  int m0 = blockIdx.y * 64, n0 = blockIdx.x * 64;
  int srow = t >> 2, skq = (t & 3) * 8;
  int ty = t >> 4, tx = t & 15;
  int i0 = ty * 4, j0 = tx * 4;
  float acc[4][4] = {};
  int gra = m0 + srow; bool va = gra < M;
  int grb = n0 + srow; bool vb = grb < N;
  float scale = 1.0f;
  if(HAS_SCALE && va) scale = rowScale[gra];
  const float* Aptr = A + (size_t)gra * K + skq;
  const float* Bptr = B + (size_t)grb * K + skq;
  for(int k0 = 0; k0 < K; k0 += 32){
    float4 a0 = {0,0,0,0}, a1 = {0,0,0,0}, b0 = {0,0,0,0}, b1 = {0,0,0,0};
    if(va){ a0 = *(const float4*)(Aptr + k0); a1 = *(const float4*)(Aptr + k0 + 4); }
    if(vb){ b0 = *(const float4*)(Bptr + k0); b1 = *(const float4*)(Bptr + k0 + 4); }
    if(HAS_SCALE){
      a0.x *= scale; a0.y *= scale; a0.z *= scale; a0.w *= scale;
      a1.x *= scale; a1.y *= scale; a1.z *= scale; a1.w *= scale;
    }
    __syncthreads();
    As[skq+0][srow] = a0.x; As[skq+1][srow] = a0.y; As[skq+2][srow] = a0.z; As[skq+3][srow] = a0.w;
    As[skq+4][srow] = a1.x; As[skq+5][srow] = a1.y; As[skq+6][srow] = a1.z; As[skq+7][srow] = a1.w;
    Bs[skq+0][srow] = b0.x; Bs[skq+1][srow] = b0.y; Bs[skq+2][srow] = b0.z; Bs[skq+3][srow] = b0.w;
    Bs[skq+4][srow] = b1.x; Bs[skq+5][srow] = b1.y; Bs[skq+6][srow] = b1.z; Bs[skq+7][srow] = b1.w;
    __syncthreads();
    #pragma unroll
    for(int kk = 0; kk < 32; ++kk){
      float4 avv = *(const float4*)&As[kk][i0];
      float4 bvv = *(const float4*)&Bs[kk][j0];
      float a_[4] = {avv.x, avv.y, avv.z, avv.w};
      float b_[4] = {bvv.x, bvv.y, bvv.z, bvv.w};
      #pragma unroll
      for(int i = 0; i < 4; ++i)
        #pragma unroll
        for(int j = 0; j < 4; ++j)
          acc[i][j] += a_[i] * b_[j];
    }
  }
  #pragma unroll
  for(int i = 0; i < 4; ++i){
    int gr = m0 + i0 + i;
    #pragma unroll
    for(int j = 0; j < 4; ++j){
      int gc = n0 + j0 + j;
      if(gc >= N) continue;
      float v2 = 0.f;
      if(gr < M){
        v2 = acc[i][j];
        if(HAS_BIAS) v2 += colBias[gc];
        if(HAS_ADD) v2 += addMat[(size_t)gr * N + gc];
        C[(size_t)gr * N + gc] = v2;
      }
      if(BF16OUT && gr < 1024){
        unsigned short h = f2bf(v2);
        Bh[(size_t)gr * N + gc] = h;
        Bl[(size_t)gr * N + gc] = f2bf(v2 - bf2f(h));
      }
    }
  }
}

// ---------------- MFMA split-bf16 main GEMM: 128x256, 3-buffer ring, SINGLE barrier per K-step ----------------
// Invariant: buffer (k+2)%3 was last READ at step k-1; stage of tile k+2 is issued AFTER the
// step-k barrier, so no wave can still be reading it. vmcnt(6) waits the 6 OLDEST loads (tile k).
__global__ __launch_bounds__(512, 1) void k_gemm_mfma(
    const unsigned short* __restrict__ Ahi, const unsigned short* __restrict__ Alo,
    const unsigned short* __restrict__ Bhi, const unsigned short* __restrict__ Blo,
    const float* __restrict__ bias2, float* __restrict__ C, float* __restrict__ poolPart){
  __shared__ __align__(16) unsigned short lds[73728];   // 144 KB = 3 buffers
  int h0 = blockIdx.x;
  int h = (h0 & 7) * 86 + (h0 >> 3);   // bijective XCD swizzle: 688 = 8 * 86 (T1)
  int nt = h & 3, mt = h >> 2;
  int m0 = mt * 128, n0 = nt * 256;
  int t = threadIdx.x;
  int w = t >> 6, l = t & 63;
  int wm = w >> 2, wn = w & 3;
  int lr = l & 15, lk = l >> 4;

  const unsigned short* gptr[6];
  int dofs[6];
  #pragma unroll
  for(int s = 0; s < 6; ++s){
    int cc = w * 6 + s;
    int r = (cc < 8) ? 0 : (cc < 16) ? 1 : (cc < 32) ? 2 : 3;
    int cc0 = (r == 0) ? 0 : (r == 1) ? 8 : (r == 2) ? 16 : 32;
    int regofs = (r == 0) ? 0 : (r == 1) ? 4096 : (r == 2) ? 8192 : 16384;
    int cloc = cc - cc0;
    int rloc = cloc * 16 + (l >> 2);
    int q = (l & 3) ^ ((rloc >> 1) & 3);
    const unsigned short* gs = (r == 0) ? Ahi : (r == 1) ? Alo : (r == 2) ? Bhi : Blo;
    int rbase = (r < 2) ? m0 : n0;
    gptr[s] = gs + (size_t)(rbase + rloc) * DIM + q * 8;
    dofs[s] = regofs + cloc * 512;
  }

  f32x4v acc[4][4];
  #pragma unroll
  for(int i = 0; i < 4; ++i)
    #pragma unroll
    for(int j = 0; j < 4; ++j) acc[i][j] = (f32x4v){0.f, 0.f, 0.f, 0.f};

  int aofs[4], bofs[4];
  #pragma unroll
  for(int f = 0; f < 4; ++f){
    int ar = wm * 64 + f * 16 + lr;
    aofs[f] = ar * 32 + (lk ^ ((ar >> 1) & 3)) * 8;
    int bc = wn * 64 + f * 16 + lr;
    bofs[f] = bc * 32 + (lk ^ ((bc >> 1) & 3)) * 8;
  }

  // prologue: stage tiles 0 and 1 (12 loads in flight per wave)
  #pragma unroll
  for(int s = 0; s < 6; ++s) gload16(gptr[s], lds + dofs[s]);
  #pragma unroll
  for(int s = 0; s < 6; ++s) gload16(gptr[s] + 32, lds + 24576 + dofs[s]);

  const int NT = DIM / 32;  // 24
  for(int k = 0; k < NT; ++k){
    int k0 = k * 32;
    if(k + 1 < NT){
      asm volatile("s_waitcnt vmcnt(6)" ::: "memory");   // tile k's 6 (oldest) complete
    } else {
      asm volatile("s_waitcnt vmcnt(0)" ::: "memory");
    }
    asm volatile("s_barrier" ::: "memory");              // all waves: tile k visible; prior reads of buf[(k+2)%3] done
    if(k + 2 < NT){
      unsigned short* dst = lds + ((k + 2) % 3) * 24576;
      #pragma unroll
      for(int s = 0; s < 6; ++s)
        gload16(gptr[s] + k0 + 64, dst + dofs[s]);
    }
    const unsigned short* Lb = lds + (k % 3) * 24576;
    bf16x8 bh[4], bl[4];
    #pragma unroll
    for(int f = 0; f < 4; ++f){
      bh[f] = *(const bf16x8*)&Lb[8192 + bofs[f]];
      bl[f] = *(const bf16x8*)&Lb[16384 + bofs[f]];
    }
    #pragma unroll
    for(int i = 0; i < 4; ++i){
      bf16x8 ahf = *(const bf16x8*)&Lb[aofs[i]];
      bf16x8 alf = *(const bf16x8*)&Lb[4096 + aofs[i]];
      #pragma unroll
      for(int j = 0; j < 4; ++j){
        acc[i][j] = __builtin_amdgcn_mfma_f32_16x16x32_bf16(ahf, bh[j], acc[i][j], 0, 0, 0);
        acc[i][j] = __builtin_amdgcn_mfma_f32_16x16x32_bf16(ahf, bl[j], acc[i][j], 0, 0, 0);
        acc[i][j] = __builtin_amdgcn_mfma_f32_16x16x32_bf16(alf, bh[j], acc[i][j], 0, 0, 0);
      }
    }
    // no end barrier: next step's start barrier orders reads-before-overwrite (3-buffer ring)
  }
  #pragma unroll
  for(int i = 0; i < 4; ++i){
    #pragma unroll
    for(int j = 0; j < 4; ++j){
      int col = n0 + wn * 64 + j * 16 + lr;
      if(col >= NCK) continue;
      float bv = bias2[col];
      #pragma unroll
      for(int r2 = 0; r2 < 4; ++r2){
        int row = m0 + wm * 64 + i * 16 + lk * 4 + r2;
        if(row < NTOT) C[(size_t)row * NCK + col] = acc[i][j][r2] + bv;
      }
    }
  }
  // ---- pooled partials (psh aliases buffer 0: last read at step 21, disjoint from step-23 reads) ----
  float* psh = (float*)lds;
  int rb = ((m0 / NPATCH) + 1) * NPATCH;
  #pragma unroll
  for(int j = 0; j < 4; ++j){
    float s0 = 0.f, s1 = 0.f;
    #pragma unroll
    for(int i = 0; i < 4; ++i)
      #pragma unroll
      for(int r2 = 0; r2 < 4; ++r2){
        int row = m0 + wm * 64 + i * 16 + lk * 4 + r2;
        float v = acc[i][j][r2];
        if(row < rb) s0 += v; else s1 += v;
      }
    s0 += __shfl_xor(s0, 16); s0 += __shfl_xor(s0, 32);
    s1 += __shfl_xor(s1, 16); s1 += __shfl_xor(s1, 32);
    if(lk == 0){
      int cslot = wn * 64 + j * 16 + lr;
      if(wm == 0){ psh[cslot] = s0; psh[256 + cslot] = s1; }
      else        { psh[512 + cslot] = s0; psh[768 + cslot] = s1; }
    }
  }
  __syncthreads();
  if(t < 256){
    float* pp = poolPart + (size_t)h * 512;
    pp[t] = psh[t] + psh[512 + t];
    pp[256 + t] = psh[256 + t] + psh[768 + t];
  }
}

// ---------------- per-class masked Sinkhorn (rank computed in-block) ----------------
__global__ __launch_bounds__(256) void k_sinkhorn(const float* __restrict__ logits,
    const int* __restrict__ pl, const int* __restrict__ counts,
    const int* __restrict__ labels, float* __restrict__ Aw, float* __restrict__ assign_out){
  int c = blockIdx.x;
  int NcI = counts[c];
  if(NcI == 0) return;
  __shared__ int imgs[BIMG];
  __shared__ int nimgS;
  __shared__ float sh[256];
  int t = threadIdx.x;
  if(t == 0){
    int ni = 0;
    for(int b = 0; b < BIMG; ++b) if(labels[b] == c) imgs[ni++] = b;
    nimgS = ni;
  }
  __syncthreads();
  float prf = (t < NCLS && t < c && counts[t] > 0) ? 1.f : 0.f;
  int rankc = (int)(red256(prf, sh) + 0.5f);
  int tot = nimgS * NPATCH;
  float Ncf = (float)NcI;
  float invNc = 1.0f / Ncf;

  float sp = 0.f;
  for(int ii = t; ii < tot; ii += 256){
    int n = imgs[ii / NPATCH] * NPATCH + (ii % NPATCH);
    if(pl[n] != c) continue;
    const float* lg = logits + (size_t)n * NCK + c * KP;
    float* aw = Aw + (size_t)n * KP;
    float l0 = expf(lg[0] / 0.05f), l1 = expf(lg[1] / 0.05f), l2 = expf(lg[2] / 0.05f),
          l3 = expf(lg[3] / 0.05f), l4 = expf(lg[4] / 0.05f);
    aw[0] = l0; aw[1] = l1; aw[2] = l2; aw[3] = l3; aw[4] = l4;
    sp += l0 + l1 + l2 + l3 + l4;
  }
  float S = red256(sp, sh);
  float sc = 1.0f / (S + 1e-16f);

  float cs0 = 0, cs1 = 0, cs2 = 0, cs3 = 0, cs4 = 0;
  for(int ii = t; ii < tot; ii += 256){
    int n = imgs[ii / NPATCH] * NPATCH + (ii % NPATCH);
    if(pl[n] != c) continue;
    float* aw = Aw + (size_t)n * KP;
    float l0 = aw[0]*sc, l1 = aw[1]*sc, l2 = aw[2]*sc, l3 = aw[3]*sc, l4 = aw[4]*sc;
    aw[0] = l0; aw[1] = l1; aw[2] = l2; aw[3] = l3; aw[4] = l4;
    cs0 += l0; cs1 += l1; cs2 += l2; cs3 += l3; cs4 += l4;
  }
  cs0 = red256(cs0, sh); cs1 = red256(cs1, sh); cs2 = red256(cs2, sh);
  cs3 = red256(cs3, sh); cs4 = red256(cs4, sh);

  for(int it = 0; it < 3; ++it){
    float m0 = 1.0f/(cs0+1e-16f), m1 = 1.0f/(cs1+1e-16f), m2 = 1.0f/(cs2+1e-16f),
          m3 = 1.0f/(cs3+1e-16f), m4 = 1.0f/(cs4+1e-16f);
    bool last = (it == 2);
    float n0 = 0, n1 = 0, n2 = 0, n3 = 0, n4 = 0;
    for(int ii = t; ii < tot; ii += 256){
      int n = imgs[ii / NPATCH] * NPATCH + (ii % NPATCH);
      if(pl[n] != c) continue;
      float* aw = Aw + (size_t)n * KP;
      float l0 = aw[0]*m0*0.2f, l1 = aw[1]*m1*0.2f, l2 = aw[2]*m2*0.2f,
            l3 = aw[3]*m3*0.2f, l4 = aw[4]*m4*0.2f;
      float rs = l0 + l1 + l2 + l3 + l4;
      float rw = 1.0f / (rs + 1e-16f);
      if(last){
        l0 *= rw; l1 *= rw; l2 *= rw; l3 *= rw; l4 *= rw;
        aw[0] = l0; aw[1] = l1; aw[2] = l2; aw[3] = l3; aw[4] = l4;
        int am = 0; float bv = l0;
        if(l1 > bv){ bv = l1; am = 1; }
        if(l2 > bv){ bv = l2; am = 2; }
        if(l3 > bv){ bv = l3; am = 3; }
        if(l4 > bv){ bv = l4; am = 4; }
        assign_out[n] = (float)(am + KP * rankc);
      } else {
        float w2 = rw * invNc;
        l0 *= w2; l1 *= w2; l2 *= w2; l3 *= w2; l4 *= w2;
        aw[0] = l0; aw[1] = l1; aw[2] = l2; aw[3] = l3; aw[4] = l4;
        n0 += l0; n1 += l1; n2 += l2; n3 += l3; n4 += l4;
      }
    }
    if(!last){
      cs0 = red256(n0, sh); cs1 = red256(n1, sh); cs2 = red256(n2, sh);
      cs3 = red256(n3, sh); cs4 = red256(n4, sh);
    }
  }
}

// ---------------- P_new partial sums (USEA: read bf16 normalized rows) ----------------
template<int USEA>
__global__ __launch_bounds__(256) void k_pnew_part(const float* __restrict__ X,
    const float* __restrict__ rinv, const unsigned short* __restrict__ Ahi,
    const float* __restrict__ Aw,
    const int* __restrict__ pl, const int* __restrict__ labels,
    float* __restrict__ part){
  int b = blockIdx.y, ch = blockIdx.x;
  int c = labels[b];
  int t = threadIdx.x;
  int j0 = ch * 86, j1 = j0 + 86; if(j1 > NPATCH) j1 = NPATCH;
  float acc[3][5] = {};
  for(int j = j0; j < j1; ++j){
    int n = b * NPATCH + j;
    if(pl[n] != c) continue;
    const float* aw = Aw + (size_t)n * KP;
    float a0 = aw[0], a1 = aw[1], a2 = aw[2], a3 = aw[3], a4 = aw[4];
    float rv = USEA ? 1.0f : rinv[n];
    #pragma unroll
    for(int dj = 0; dj < 3; ++dj){
      float x;
      if(USEA) x = bf2f(Ahi[(size_t)n * DIM + t + dj * 256]);
      else     x = X[(size_t)n * DIM + t + dj * 256] * rv;
      acc[dj][0] += a0 * x; acc[dj][1] += a1 * x; acc[dj][2] += a2 * x;
      acc[dj][3] += a3 * x; acc[dj][4] += a4 * x;
    }
  }
  float* po = part + ((size_t)(b * PCH + ch)) * KP * DIM;
  #pragma unroll
  for(int k = 0; k < 5; ++k)
    #pragma unroll
    for(int dj = 0; dj < 3; ++dj)
      po[k * DIM + t + dj * 256] = acc[dj][k];
}

// ---------------- fused tail: P_new final (blocks 0..200) + pooled gather + sa head (blocks 201..216) ----------------
__global__ __launch_bounds__(256) void k_tailm(const float* __restrict__ P,
    const float* __restrict__ part, const int* __restrict__ counts,
    const int* __restrict__ labels, float* __restrict__ out_np,
    const float* __restrict__ poolPart, const float* __restrict__ bias2,
    const float* __restrict__ sa, float* __restrict__ pooled, float* __restrict__ out){
  __shared__ float ps[1024];
  __shared__ int imgs[BIMG];
  __shared__ int nimgS;
  int t = threadIdx.x;
  if(blockIdx.x < CDIM){
    int c = blockIdx.x;
    bool pres = (c < NCLS) && (counts[c] > 0);
    const float* Pc = P + (size_t)c * KP * DIM;
    float* Oc = out_np + (size_t)c * KP * DIM;
    if(!pres){
      for(int i = t; i < KP * DIM; i += 256) Oc[i] = Pc[i];
      return;
    }
    if(t == 0){
      int ni = 0;
      for(int b = 0; b < BIMG; ++b) if(labels[b] == c) imgs[ni++] = b;
      nimgS = ni;
    }
    __syncthreads();
    int ni = nimgS;
    for(int i = t; i < KP * DIM; i += 256){
      float s = 0.f;
      for(int q = 0; q < ni; ++q){
        const float* pb = part + ((size_t)(imgs[q] * PCH)) * KP * DIM + i;
        for(int ch = 0; ch < PCH; ++ch) s += pb[(size_t)ch * KP * DIM];
      }
      Oc[i] = 0.99f * Pc[i] + 0.01f * s;
    }
  } else {
    int b = blockIdx.x - CDIM;
    int mt_lo = (b * NPATCH) >> 7;
    int mt_hi = ((b + 1) * NPATCH - 1) >> 7;
    #pragma unroll
    for(int g = 0; g < 4; ++g){
      int col = g * 256 + t;
      float s = 0.f;
      for(int mt = mt_lo; mt <= mt_hi; ++mt){
        int img0 = (mt * 128) / NPATCH;
        int buck = (img0 == b) ? 0 : 1;
        s += poolPart[((size_t)(mt * 4 + g)) * 512 + buck * 256 + t];
      }
      float pv = s / 1369.0f + ((col < NCK) ? bias2[col] : 0.f);
      if(col < NCK) pooled[(size_t)b * NCK + col] = pv;
      ps[col] = pv;
    }
    __syncthreads();
    if(t < NCLS){
      float sa0 = sa[t*5+0], sa1 = sa[t*5+1], sa2 = sa[t*5+2], sa3 = sa[t*5+3], sa4 = sa[t*5+4];
      float mx = fmaxf(fmaxf(fmaxf(sa0, sa1), fmaxf(sa2, sa3)), sa4);
      float e0 = expf(sa0 - mx), e1 = expf(sa1 - mx), e2 = expf(sa2 - mx),
            e3 = expf(sa3 - mx), e4 = expf(sa4 - mx);
      float se = e0 + e1 + e2 + e3 + e4;
      float iv = 5.0f / se;
      const float* p = ps + t * KP;
      out[b * NCLS + t] = p[0]*e0*iv + p[1]*e1*iv + p[2]*e2*iv + p[3]*e3*iv + p[4]*e4*iv;
    }
  }
}

// ---------------- P_new final (fallback) ----------------
__global__ __launch_bounds__(256) void k_pnew_fin(const float* __restrict__ P,
    const float* __restrict__ part, const int* __restrict__ counts,
    const int* __restrict__ labels, float* __restrict__ out_np){
  int c = blockIdx.x;
  int t = threadIdx.x;
  bool pres = (c < NCLS) && (counts[c] > 0);
  const float* Pc = P + (size_t)c * KP * DIM;
  float* Oc = out_np + (size_t)c * KP * DIM;
  if(!pres){
    for(int i = t; i < KP * DIM; i += 256) Oc[i] = Pc[i];
    return;
  }
  __shared__ int imgs[BIMG];
  __shared__ int nimgS;
  if(t == 0){
    int ni = 0;
    for(int b = 0; b < BIMG; ++b) if(labels[b] == c) imgs[ni++] = b;
    nimgS = ni;
  }
  __syncthreads();
  int ni = nimgS;
  for(int i = t; i < KP * DIM; i += 256){
    float s = 0.f;
    for(int q = 0; q < ni; ++q){
      const float* pb = part + ((size_t)(imgs[q] * PCH)) * KP * DIM + i;
      for(int ch = 0; ch < PCH; ++ch) s += pb[(size_t)ch * KP * DIM];
    }
    Oc[i] = 0.99f * Pc[i] + 0.01f * s;
  }
}

// ---------------- pooled stage 1 (fallback only) ----------------
__global__ __launch_bounds__(256) void k_pool1(const float* __restrict__ logits,
    float* __restrict__ poolPart){
  int b = blockIdx.y, ch = blockIdx.x;
  int t = threadIdx.x;
  int j0 = ch * 43, j1 = j0 + 43; if(j1 > NPATCH) j1 = NPATCH;
  float a0 = 0, a1 = 0, a2 = 0, a3 = 0;
  for(int j = j0; j < j1; ++j){
    const float* row = logits + ((size_t)(b * NPATCH + j)) * NCK;
    a0 += row[t]; a1 += row[t + 256]; a2 += row[t + 512];
    if(t < 237) a3 += row[t + 768];
  }
  float* po = poolPart + ((size_t)(b * QCH + ch)) * 1024;
  po[t] = a0; po[t + 256] = a1; po[t + 512] = a2;
  if(t < 237) po[t + 768] = a3;
}

// ---------------- pooled stage 2 + sa head (fallback) ----------------
__global__ __launch_bounds__(256) void k_pool2cls(const float* __restrict__ poolPart,
    const float* __restrict__ bias2, const float* __restrict__ sa,
    float* __restrict__ pooled, float* __restrict__ out){
  __shared__ float ps[1024];
  int b = blockIdx.x;
  int t = threadIdx.x;
  float s0 = 0, s1 = 0, s2 = 0, s3 = 0;
  const float* pb = poolPart + ((size_t)(b * QCH)) * 1024;
  for(int ch = 0; ch < QCH; ++ch){
    const float* p = pb + (size_t)ch * 1024;
    s0 += p[t]; s1 += p[t + 256]; s2 += p[t + 512];
    if(t < 237) s3 += p[t + 768];
  }
  float* o = pooled + (size_t)b * NCK;
  float o0 = s0 / 1369.0f, o1 = s1 / 1369.0f, o2 = s2 / 1369.0f, o3 = s3 / 1369.0f;
  o[t] = o0; o[t + 256] = o1; o[t + 512] = o2;
  if(t < 237) o[t + 768] = o3;
  ps[t] = o0; ps[t + 256] = o1; ps[t + 512] = o2;
  if(t < 237) ps[t + 768] = o3;
  __syncthreads();
  if(t < NCLS){
    float sa0 = sa[t*5+0], sa1 = sa[t*5+1], sa2 = sa[t*5+2], sa3 = sa[t*5+3], sa4 = sa[t*5+4];
    float mx = fmaxf(fmaxf(fmaxf(sa0, sa1), fmaxf(sa2, sa3)), sa4);
    float e0 = expf(sa0 - mx), e1 = expf(sa1 - mx), e2 = expf(sa2 - mx),
          e3 = expf(sa3 - mx), e4 = expf(sa4 - mx);
    float se = e0 + e1 + e2 + e3 + e4;
    float iv = 5.0f / se;
    const float* p = ps + t * KP;
    out[b * NCLS + t] = p[0]*e0*iv + p[1]*e1*iv + p[2]*e2*iv + p[3]*e3*iv + p[4]*e4*iv;
  }
}

extern "C" void kernel_launch(void* const* d_in, const int* in_sizes, int n_in,
                              void* d_out, int out_size, void* d_ws, size_t ws_size,
                              hipStream_t stream){
  const float* X      = (const float*)d_in[0];
  const int*   labels = (const int*)d_in[1];
  const float* P      = (const float*)d_in[2];
  const float* W      = (const float*)d_in[3];
  const float* bvec   = (const float*)d_in[4];
  const float* sa     = (const float*)d_in[5];

  float* out        = (float*)d_out;
  float* out_cls    = out;
  float* out_logits = out + 3200;
  float* out_pooled = out_logits + (size_t)NTOT * NCK;
  float* out_assign = out_pooled + BIMG * NCK;
  float* out_np     = out_assign + NTOT;
  float* out_pseudo = out_np + (size_t)CDIM * KP * DIM;

  const size_t AHI_F = (size_t)MPAD * DIM / 2;   // ushort array in float units
  const size_t BHI_F = (size_t)1024 * DIM / 2;
  const size_t MFMA_F = 2 * AHI_F + 2 * BHI_F;
  const size_t BASE_F = 4050000;
  bool use_mfma = ws_size >= (MFMA_F + BASE_F) * sizeof(float);

  float* ws = (float*)d_ws;
  unsigned short* Ahi = (unsigned short*)ws;
  unsigned short* Alo = (unsigned short*)(ws + AHI_F);
  unsigned short* Bhi = (unsigned short*)(ws + 2 * AHI_F);
  unsigned short* Blo = (unsigned short*)(ws + 2 * AHI_F + BHI_F);
  float* base = use_mfma ? (ws + MFMA_F) : ws;

  float* protn  = base;
  float* Bmat   = protn + (size_t)NCK * DIM;
  float* bias2  = Bmat + (size_t)NCK * DIM;
  float* rinv   = bias2 + 1024;
  float* uvec   = rinv + NTOT;
  float* Aw     = uvec + NTOT;
  float* meanv  = Aw + (size_t)NTOT * KP;
  float* wvb    = meanv + DIM;
  float* pbuf   = wvb + DIM;
  float* subuf  = pbuf + (size_t)UCH * DIM;
  float* parts  = subuf + UCH;
  float* scal   = parts + 32;
  int*   pli    = (int*)(scal + 8);
  int*   counts = pli + NTOT;
  float* pnewP  = (float*)(counts + 256);
  float* poolP  = pnewP + (size_t)BIMG * PCH * KP * DIM;
  unsigned* enc = (unsigned*)(scal + 1);

  k_colmean1<<<512, 256, 0, stream>>>(X, pbuf);
  k_meanred<<<12, 256, 0, stream>>>(pbuf, meanv, wvb, parts, counts, enc);
  for(int i = 0; i < 10; ++i){
    k_pcapass<<<UCH, 256, 0, stream>>>(X, wvb, parts, pbuf, subuf);
    k_pcared<<<12, 256, 0, stream>>>(pbuf, subuf, meanv, wvb, parts);
  }
  if(use_mfma){
    k_ufinal<1><<<UCH, 256, 0, stream>>>(X, wvb, parts, uvec, enc, rinv, Ahi, Alo);
  } else {
    k_ufinal<0><<<UCH, 256, 0, stream>>>(X, wvb, parts, uvec, enc, nullptr, nullptr, nullptr);
    k_rnorm<<<5476, 256, 0, stream>>>(X, rinv);
  }
  k_pseudo<<<86, 256, 0, stream>>>(uvec, enc, labels, pli, out_pseudo, out_assign, counts);
  k_protn<<<252, 256, 0, stream>>>(P, bvec, protn, bias2);
  if(use_mfma){
    k_gemm_nt<0, 0, 1, 1><<<dim3(12, 16), 256, 0, stream>>>(protn, W, Bmat, nullptr, nullptr,
                                                            protn, Bhi, Blo, NCK, DIM, DIM);
    k_gemm_mfma<<<688, 512, 0, stream>>>(Ahi, Alo, Bhi, Blo, bias2, out_logits, poolP);
  } else {
    k_gemm_nt<0, 0, 1, 0><<<dim3(12, 16), 256, 0, stream>>>(protn, W, Bmat, nullptr, nullptr,
                                                            protn, nullptr, nullptr, NCK, DIM, DIM);
    k_gemm_nt<1, 1, 0, 0><<<dim3(16, 343), 256, 0, stream>>>(X, Bmat, out_logits, rinv, bias2,
                                                             nullptr, nullptr, nullptr, NTOT, NCK, DIM);
  }
  k_sinkhorn<<<NCLS, 256, 0, stream>>>(out_logits, pli, counts, labels, Aw, out_assign);
  if(use_mfma){
    k_pnew_part<1><<<dim3(PCH, BIMG), 256, 0, stream>>>(nullptr, nullptr, Ahi, Aw, pli, labels, pnewP);
    k_tailm<<<CDIM + BIMG, 256, 0, stream>>>(P, pnewP, counts, labels, out_np,
                                             poolP, bias2, sa, out_pooled, out_cls);
  } else {
    k_pnew_part<0><<<dim3(PCH, BIMG), 256, 0, stream>>>(X, rinv, nullptr, Aw, pli, labels, pnewP);
    k_pnew_fin<<<CDIM, 256, 0, stream>>>(P, pnewP, counts, labels, out_np);
    k_pool1<<<dim3(QCH, BIMG), 256, 0, stream>>>(out_logits, poolP);
    k_pool2cls<<<BIMG, 256, 0, stream>>>(poolP, bias2, sa, out_pooled, out_cls);
  }
}

// Round 17
// 561.938 us; speedup vs baseline: 1.2361x; 1.2041x over previous
//
#include <hip/hip_runtime.h>

#define NTOT 21904
#define MPAD 22016
#define NPATCH 1369
#define BIMG 16
#define DIM 768
#define NCLS 200
#define CDIM 201
#define KP 5
#define NCK 1005
#define PCH 16   // pnew patch chunks per image
#define QCH 32   // pool patch chunks per image (fallback)
#define UCH 1024 // pca pass partial chunks

typedef short bf16x8 __attribute__((ext_vector_type(8)));
typedef float f32x4v __attribute__((ext_vector_type(4)));

__device__ __forceinline__ unsigned encf(float x){
  unsigned b = __float_as_uint(x);
  return (b & 0x80000000u) ? ~b : (b | 0x80000000u);
}
__device__ __forceinline__ float decf(unsigned e){
  return (e & 0x80000000u) ? __uint_as_float(e ^ 0x80000000u) : __uint_as_float(~e);
}
__device__ __forceinline__ unsigned short f2bf(float f){
  unsigned u = __float_as_uint(f);
  u += 0x7FFFu + ((u >> 16) & 1u);
  return (unsigned short)(u >> 16);
}
__device__ __forceinline__ float bf2f(unsigned short h){
  return __uint_as_float(((unsigned)h) << 16);
}
__device__ __forceinline__ void gload16(const unsigned short* g, unsigned short* l){
  __builtin_amdgcn_global_load_lds(
      (const __attribute__((address_space(1))) unsigned int*)g,
      (__attribute__((address_space(3))) unsigned int*)l, 16, 0, 0);
}

__device__ __forceinline__ float red256(float v, float* sh){
  int t = threadIdx.x;
  sh[t] = v; __syncthreads();
  for(int s = 128; s > 0; s >>= 1){ if(t < s) sh[t] += sh[t+s]; __syncthreads(); }
  float r = sh[0]; __syncthreads();
  return r;
}

// ---------------- column sums, 512 chunks x 43 rows (FROZEN ORDER; unroll = load batching only) ----------------
__global__ __launch_bounds__(256) void k_colmean1(const float* __restrict__ X, float* __restrict__ pbuf){
  int b = blockIdx.x, t = threadIdx.x;
  int n0 = b * 43, n1 = n0 + 43; if(n1 > NTOT) n1 = NTOT;
  float s0 = 0.f, s1 = 0.f, s2 = 0.f;
  #pragma unroll 4
  for(int n = n0; n < n1; ++n){
    const float* row = X + (size_t)n * DIM;
    s0 += row[t]; s1 += row[t + 256]; s2 += row[t + 512];
  }
  float* pb = pbuf + (size_t)b * DIM;
  pb[t] = s0; pb[t + 256] = s1; pb[t + 512] = s2;
}

// ---------------- mean + wv init + 12-way parts; also init counts/enc (FROZEN ORDER; ILP unroll) ----------------
__global__ __launch_bounds__(256) void k_meanred(const float* __restrict__ pbuf,
    float* __restrict__ meanv, float* __restrict__ wvb, float* __restrict__ parts,
    int* __restrict__ counts, unsigned* __restrict__ enc){
  __shared__ float sh[256];
  int cg = blockIdx.x, t = threadIdx.x;
  if(cg == 0){
    if(t < CDIM) counts[t] = 0;
    if(t == 0){ enc[0] = 0xFFFFFFFFu; enc[1] = 0u; }
  }
  int tc = t & 63, th = t >> 6;
  int col = cg * 64 + tc;
  const float v0 = 0.036084391824351615f;   // 1/sqrt(768)
  float s = 0.f;
  #pragma unroll 32
  for(int ch = th; ch < 512; ch += 4) s += pbuf[ch * DIM + col];
  sh[t] = s; __syncthreads();
  float mcontrib = 0.f;
  if(th == 0){
    float m = (sh[tc] + sh[64 + tc] + sh[128 + tc] + sh[192 + tc]) / 21904.0f;
    meanv[col] = m;
    wvb[col] = v0;
    mcontrib = m * v0;
  }
  __syncthreads();
  float md = red256(mcontrib, sh);
  if(t == 0){ parts[cg] = 64.0f * v0 * v0; parts[16 + cg] = md; }
}

// ---------------- power-iteration pass (FROZEN ORDER; unroll-3 for MLP, bit-identical accumulation) ----------------
__global__ __launch_bounds__(256) void k_pcapass(const float* __restrict__ X,
    const float* __restrict__ wvb, const float* __restrict__ parts,
    float* __restrict__ pbuf, float* __restrict__ subuf){
  __shared__ float shacc[4][DIM];
  __shared__ float shsu[4];
  int t = threadIdx.x, w = t >> 6, l = t & 63;
  float nrm2 = 0.f, mvr = 0.f;
  #pragma unroll
  for(int i = 0; i < 12; ++i){ nrm2 += parts[i]; mvr += parts[16 + i]; }
  float invD = 1.0f / (sqrtf(nrm2) + 1e-12f);
  const float4* v4 = (const float4*)(wvb + l * 12);
  float4 v0 = v4[0], v1 = v4[1], v2 = v4[2];
  float4 a0 = {0,0,0,0}, a1 = {0,0,0,0}, a2 = {0,0,0,0};
  float su = 0.f;
  int n = blockIdx.x * 4 + w;
  while(n + 8192 < NTOT){
    const float4* xa4 = (const float4*)(X + (size_t)n * DIM + l * 12);
    const float4* xb4 = (const float4*)(X + (size_t)(n + 4096) * DIM + l * 12);
    const float4* xc4 = (const float4*)(X + (size_t)(n + 8192) * DIM + l * 12);
    float4 xa0 = xa4[0], xa1 = xa4[1], xa2 = xa4[2];
    float4 xb0 = xb4[0], xb1 = xb4[1], xb2 = xb4[2];
    float4 xc0 = xc4[0], xc1 = xc4[1], xc2 = xc4[2];
    float tpA = xa0.x*v0.x + xa0.y*v0.y + xa0.z*v0.z + xa0.w*v0.w
              + xa1.x*v1.x + xa1.y*v1.y + xa1.z*v1.z + xa1.w*v1.w
              + xa2.x*v2.x + xa2.y*v2.y + xa2.z*v2.z + xa2.w*v2.w;
    float tpB = xb0.x*v0.x + xb0.y*v0.y + xb0.z*v0.z + xb0.w*v0.w
              + xb1.x*v1.x + xb1.y*v1.y + xb1.z*v1.z + xb1.w*v1.w
              + xb2.x*v2.x + xb2.y*v2.y + xb2.z*v2.z + xb2.w*v2.w;
    float tpC = xc0.x*v0.x + xc0.y*v0.y + xc0.z*v0.z + xc0.w*v0.w
              + xc1.x*v1.x + xc1.y*v1.y + xc1.z*v1.z + xc1.w*v1.w
              + xc2.x*v2.x + xc2.y*v2.y + xc2.z*v2.z + xc2.w*v2.w;
    #pragma unroll
    for(int o = 32; o > 0; o >>= 1){
      tpA += __shfl_xor(tpA, o);
      tpB += __shfl_xor(tpB, o);
      tpC += __shfl_xor(tpC, o);
    }
    tpA = (tpA - mvr) * invD;
    tpB = (tpB - mvr) * invD;
    tpC = (tpC - mvr) * invD;
    a0.x += tpA*xa0.x; a0.y += tpA*xa0.y; a0.z += tpA*xa0.z; a0.w += tpA*xa0.w;
    a1.x += tpA*xa1.x; a1.y += tpA*xa1.y; a1.z += tpA*xa1.z; a1.w += tpA*xa1.w;
    a2.x += tpA*xa2.x; a2.y += tpA*xa2.y; a2.z += tpA*xa2.z; a2.w += tpA*xa2.w;
    a0.x += tpB*xb0.x; a0.y += tpB*xb0.y; a0.z += tpB*xb0.z; a0.w += tpB*xb0.w;
    a1.x += tpB*xb1.x; a1.y += tpB*xb1.y; a1.z += tpB*xb1.z; a1.w += tpB*xb1.w;
    a2.x += tpB*xb2.x; a2.y += tpB*xb2.y; a2.z += tpB*xb2.z; a2.w += tpB*xb2.w;
    a0.x += tpC*xc0.x; a0.y += tpC*xc0.y; a0.z += tpC*xc0.z; a0.w += tpC*xc0.w;
    a1.x += tpC*xc1.x; a1.y += tpC*xc1.y; a1.z += tpC*xc1.z; a1.w += tpC*xc1.w;
    a2.x += tpC*xc2.x; a2.y += tpC*xc2.y; a2.z += tpC*xc2.z; a2.w += tpC*xc2.w;
    if(l == 0){ su += tpA; su += tpB; su += tpC; }
    n += 12288;
  }
  while(n < NTOT){
    const float4* x4 = (const float4*)(X + (size_t)n * DIM + l * 12);
    float4 x0 = x4[0], x1 = x4[1], x2 = x4[2];
    float tp = x0.x*v0.x + x0.y*v0.y + x0.z*v0.z + x0.w*v0.w
             + x1.x*v1.x + x1.y*v1.y + x1.z*v1.z + x1.w*v1.w
             + x2.x*v2.x + x2.y*v2.y + x2.z*v2.z + x2.w*v2.w;
    #pragma unroll
    for(int o = 32; o > 0; o >>= 1) tp += __shfl_xor(tp, o);
    tp = (tp - mvr) * invD;
    a0.x += tp*x0.x; a0.y += tp*x0.y; a0.z += tp*x0.z; a0.w += tp*x0.w;
    a1.x += tp*x1.x; a1.y += tp*x1.y; a1.z += tp*x1.z; a1.w += tp*x1.w;
    a2.x += tp*x2.x; a2.y += tp*x2.y; a2.z += tp*x2.z; a2.w += tp*x2.w;
    if(l == 0) su += tp;
    n += 4096;
  }
  float4* sh4 = (float4*)&shacc[w][l * 12];
  sh4[0] = a0; sh4[1] = a1; sh4[2] = a2;
  if(l == 0) shsu[w] = su;
  __syncthreads();
  for(int c = t; c < DIM; c += 256)
    pbuf[blockIdx.x * DIM + c] = shacc[0][c] + shacc[1][c] + shacc[2][c] + shacc[3][c];
  if(t == 0) subuf[blockIdx.x] = shsu[0] + shsu[1] + shsu[2] + shsu[3];
}

// ---------------- reduce partials -> new wv + 12-way parts (FROZEN ORDER; ILP unroll 64) ----------------
__global__ __launch_bounds__(256) void k_pcared(const float* __restrict__ pbuf,
    const float* __restrict__ subuf, const float* __restrict__ meanv,
    float* __restrict__ wvb, float* __restrict__ parts){
  __shared__ float sh[256];
  int cg = blockIdx.x, t = threadIdx.x;
  float sv = subuf[t] + subuf[t + 256] + subuf[t + 512] + subuf[t + 768];
  float su = red256(sv, sh);
  int tc = t & 63, th = t >> 6;
  int col = cg * 64 + tc;
  float s = 0.f;
  #pragma unroll 64
  for(int ch = th; ch < UCH; ch += 4) s += pbuf[(size_t)ch * DIM + col];
  sh[t] = s; __syncthreads();
  float csq = 0.f, cmd = 0.f;
  if(th == 0){
    float wvn = (sh[tc] + sh[64 + tc] + sh[128 + tc] + sh[192 + tc]) - meanv[col] * su;
    wvb[col] = wvn;
    csq = wvn * wvn;
    cmd = meanv[col] * wvn;
  }
  __syncthreads();
  float sq = red256(csq, sh);
  float md = red256(cmd, sh);
  if(t == 0){ parts[cg] = sq; parts[16 + cg] = md; }
}

// ---------------- final u = Xc v + min/max; PREP: fused rinv + bf16 hi/lo split (FROZEN) ----------------
template<int PREP>
__global__ __launch_bounds__(256) void k_ufinal(const float* __restrict__ X,
    const float* __restrict__ wvb, const float* __restrict__ parts,
    float* __restrict__ u, unsigned* __restrict__ enc,
    float* __restrict__ rinv, unsigned short* __restrict__ Ahi, unsigned short* __restrict__ Alo){
  __shared__ float smn[4], smx[4];
  int t = threadIdx.x, w = t >> 6, l = t & 63;
  float nrm2 = 0.f, mvr = 0.f;
  #pragma unroll
  for(int i = 0; i < 12; ++i){ nrm2 += parts[i]; mvr += parts[16 + i]; }
  float invD = 1.0f / (sqrtf(nrm2) + 1e-12f);
  const float4* v4 = (const float4*)(wvb + l * 12);
  float4 v0 = v4[0], v1 = v4[1], v2 = v4[2];
  float lmn = 3.4e38f, lmx = -3.4e38f;
  int nend = PREP ? MPAD : NTOT;
  for(int n = blockIdx.x * 4 + w; n < nend; n += 4096){
    size_t off = (size_t)n * DIM + l * 12;
    if(PREP && n >= NTOT){
      ushort4 z = make_ushort4(0, 0, 0, 0);
      #pragma unroll
      for(int j = 0; j < 3; ++j){
        *(ushort4*)(Ahi + off + j * 4) = z;
        *(ushort4*)(Alo + off + j * 4) = z;
      }
      continue;
    }
    const float4* x4 = (const float4*)(X + off);
    float4 x0 = x4[0], x1 = x4[1], x2 = x4[2];
    float tp = x0.x*v0.x + x0.y*v0.y + x0.z*v0.z + x0.w*v0.w
             + x1.x*v1.x + x1.y*v1.y + x1.z*v1.z + x1.w*v1.w
             + x2.x*v2.x + x2.y*v2.y + x2.z*v2.z + x2.w*v2.w;
    #pragma unroll
    for(int o = 32; o > 0; o >>= 1) tp += __shfl_xor(tp, o);
    tp = (tp - mvr) * invD;
    if(l == 0){ u[n] = tp; lmn = fminf(lmn, tp); lmx = fmaxf(lmx, tp); }
    if(PREP){
      float s = x0.x*x0.x + x0.y*x0.y + x0.z*x0.z + x0.w*x0.w
              + x1.x*x1.x + x1.y*x1.y + x1.z*x1.z + x1.w*x1.w
              + x2.x*x2.x + x2.y*x2.y + x2.z*x2.z + x2.w*x2.w;
      #pragma unroll
      for(int o = 32; o > 0; o >>= 1) s += __shfl_xor(s, o);
      float rv = 1.0f / (sqrtf(s) + 1e-12f);
      if(l == 0) rinv[n] = rv;
      float xs[12] = {x0.x*rv, x0.y*rv, x0.z*rv, x0.w*rv,
                      x1.x*rv, x1.y*rv, x1.z*rv, x1.w*rv,
                      x2.x*rv, x2.y*rv, x2.z*rv, x2.w*rv};
      unsigned short hi[12], lo[12];
      #pragma unroll
      for(int j = 0; j < 12; ++j){
        hi[j] = f2bf(xs[j]);
        lo[j] = f2bf(xs[j] - bf2f(hi[j]));
      }
      #pragma unroll
      for(int j = 0; j < 3; ++j){
        *(ushort4*)(Ahi + off + j * 4) = make_ushort4(hi[j*4], hi[j*4+1], hi[j*4+2], hi[j*4+3]);
        *(ushort4*)(Alo + off + j * 4) = make_ushort4(lo[j*4], lo[j*4+1], lo[j*4+2], lo[j*4+3]);
      }
    }
  }
  if(l == 0){ smn[w] = lmn; smx[w] = lmx; }
  __syncthreads();
  if(t == 0){
    float mn = fminf(fminf(smn[0], smn[1]), fminf(smn[2], smn[3]));
    float mx = fmaxf(fmaxf(smx[0], smx[1]), fmaxf(smx[2], smx[3]));
    atomicMin(&enc[0], encf(mn));
    atomicMax(&enc[1], encf(mx));
  }
}

// ---------------- pseudo labels (FROZEN threshold path; counts via LDS histogram, G12) ----------------
__global__ __launch_bounds__(256) void k_pseudo(const float* __restrict__ u,
    const unsigned* __restrict__ enc, const int* __restrict__ labels,
    int* __restrict__ pl, float* __restrict__ pseudo_out,
    float* __restrict__ assign_out, int* __restrict__ counts){
  __shared__ int lc[CDIM];
  int t = threadIdx.x;
  for(int i = t; i < CDIM; i += 256) lc[i] = 0;
  __syncthreads();
  int n = blockIdx.x * 256 + t;
  if(n < NTOT){
    float mn = decf(enc[0]), mx = decf(enc[1]);
    float us = (u[n] - mn) / (mx - mn);
    int b = n / NPATCH;
    int p = (us <= 0.5f) ? labels[b] : NCLS;
    pl[n] = p;
    pseudo_out[n] = (float)p;
    assign_out[n] = -1.0f;
    atomicAdd(&lc[p], 1);              // LDS atomic: cheap, block-local
  }
  __syncthreads();
  for(int i = t; i < CDIM; i += 256)
    if(lc[i] > 0) atomicAdd(&counts[i], lc[i]);   // <=3 global atomics per block
}

// ---------------- row norms (fallback path) ----------------
__global__ __launch_bounds__(256) void k_rnorm(const float* __restrict__ X, float* __restrict__ rinv){
  int t = threadIdx.x, w = t >> 6, l = t & 63;
  int n = blockIdx.x * 4 + w;
  if(n >= NTOT) return;
  const float4* x4 = (const float4*)(X + (size_t)n * DIM + l * 12);
  float4 x0 = x4[0], x1 = x4[1], x2 = x4[2];
  float s = x0.x*x0.x + x0.y*x0.y + x0.z*x0.z + x0.w*x0.w
          + x1.x*x1.x + x1.y*x1.y + x1.z*x1.z + x1.w*x1.w
          + x2.x*x2.x + x2.y*x2.y + x2.z*x2.z + x2.w*x2.w;
  #pragma unroll
  for(int o = 32; o > 0; o >>= 1) s += __shfl_xor(s, o);
  if(l == 0) rinv[n] = 1.0f / (sqrtf(s) + 1e-12f);
}

// ---------------- normalized prototypes + bias2 ----------------
__global__ __launch_bounds__(256) void k_protn(const float* __restrict__ P,
    const float* __restrict__ bvec, float* __restrict__ protn, float* __restrict__ bias2){
  int t = threadIdx.x, w = t >> 6, l = t & 63;
  int r = blockIdx.x * 4 + w;
  if(r >= NCK) return;
  const float4* x4 = (const float4*)(P + (size_t)r * DIM + l * 12);
  float4 x0 = x4[0], x1 = x4[1], x2 = x4[2];
  float s = x0.x*x0.x + x0.y*x0.y + x0.z*x0.z + x0.w*x0.w
          + x1.x*x1.x + x1.y*x1.y + x1.z*x1.z + x1.w*x1.w
          + x2.x*x2.x + x2.y*x2.y + x2.z*x2.z + x2.w*x2.w;
  #pragma unroll
  for(int o = 32; o > 0; o >>= 1) s += __shfl_xor(s, o);
  float rv = 1.0f / (sqrtf(s) + 1e-12f);
  x0.x *= rv; x0.y *= rv; x0.z *= rv; x0.w *= rv;
  x1.x *= rv; x1.y *= rv; x1.z *= rv; x1.w *= rv;
  x2.x *= rv; x2.y *= rv; x2.z *= rv; x2.w *= rv;
  float4* o4 = (float4*)(protn + (size_t)r * DIM + l * 12);
  o4[0] = x0; o4[1] = x1; o4[2] = x2;
  const float4* b4 = (const float4*)(bvec + l * 12);
  float4 b0 = b4[0], b1 = b4[1], b2 = b4[2];
  float bb = b0.x*x0.x + b0.y*x0.y + b0.z*x0.z + b0.w*x0.w
           + b1.x*x1.x + b1.y*x1.y + b1.z*x1.z + b1.w*x1.w
           + b2.x*x2.x + b2.y*x2.y + b2.z*x2.z + b2.w*x2.w;
  #pragma unroll
  for(int o = 32; o > 0; o >>= 1) bb += __shfl_xor(bb, o);
  if(l == 0) bias2[r] = bb;
}

// ---------------- f32 NT GEMM; BF16OUT also emits hi/lo split (rows padded to 1024) ----------------
template<int HAS_SCALE, int HAS_BIAS, int HAS_ADD, int BF16OUT>
__global__ __launch_bounds__(256) void k_gemm_nt(const float* __restrict__ A,
    const float* __restrict__ B, float* __restrict__ C,
    const float* __restrict__ rowScale, const float* __restrict__ colBias,
    const float* __restrict__ addMat, unsigned short* __restrict__ Bh,
    unsigned short* __restrict__ Bl, int M, int N, int K){
  __shared__ float As[32][72];
  __shared__ float Bs[32][72];
  int t = threadIdx.x;
  int m0 = blockIdx.y * 64, n0 = blockIdx.x * 64;
  int srow = t >> 2, skq = (t & 3) * 8;
  int ty = t >> 4, tx = t & 15;
  int i0 = ty * 4, j0 = tx * 4;
  float acc[4][4] = {};
  int gra = m0 + srow; bool va = gra < M;
  int grb = n0 + srow; bool vb = grb < N;
  float scale = 1.0f;
  if(HAS_SCALE && va) scale = rowScale[gra];
  const float* Aptr = A + (size_t)gra * K + skq;
  const float* Bptr = B + (size_t)grb * K + skq;
  for(int k0 = 0; k0 < K; k0 += 32){
    float4 a0 = {0,0,0,0}, a1 = {0,0,0,0}, b0 = {0,0,0,0}, b1 = {0,0,0,0};
    if(va){ a0 = *(const float4*)(Aptr + k0); a1 = *(const float4*)(Aptr + k0 + 4); }
    if(vb){ b0 = *(const float4*)(Bptr + k0); b1 = *(const float4*)(Bptr + k0 + 4); }
    if(HAS_SCALE){
      a0.x *= scale; a0.y *= scale; a0.z *= scale; a0.w *= scale;
      a1.x *= scale; a1.y *= scale; a1.z *= scale; a1.w *= scale;
    }
    __syncthreads();
    As[skq+0][srow] = a0.x; As[skq+1][srow] = a0.y; As[skq+2][srow] = a0.z; As[skq+3][srow] = a0.w;
    As[skq+4][srow] = a1.x; As[skq+5][srow] = a1.y; As[skq+6][srow] = a1.z; As[skq+7][srow] = a1.w;
    Bs[skq+0][srow] = b0.x; Bs[skq+1][srow] = b0.y; Bs[skq+2][srow] = b0.z; Bs[skq+3][srow] = b0.w;
    Bs[skq+4][srow] = b1.x; Bs[skq+5][srow] = b1.y; Bs[skq+6][srow] = b1.z; Bs[skq+7][srow] = b1.w;
    __syncthreads();
    #pragma unroll
    for(int kk = 0; kk < 32; ++kk){
      float4 avv = *(const float4*)&As[kk][i0];
      float4 bvv = *(const float4*)&Bs[kk][j0];
      float a_[4] = {avv.x, avv.y, avv.z, avv.w};
      float b_[4] = {bvv.x, bvv.y, bvv.z, bvv.w};
      #pragma unroll
      for(int i = 0; i < 4; ++i)
        #pragma unroll
        for(int j = 0; j < 4; ++j)
          acc[i][j] += a_[i] * b_[j];
    }
  }
  #pragma unroll
  for(int i = 0; i < 4; ++i){
    int gr = m0 + i0 + i;
    #pragma unroll
    for(int j = 0; j < 4; ++j){
      int gc = n0 + j0 + j;
      if(gc >= N) continue;
      float v2 = 0.f;
      if(gr < M){
        v2 = acc[i][j];
        if(HAS_BIAS) v2 += colBias[gc];
        if(HAS_ADD) v2 += addMat[(size_t)gr * N + gc];
        C[(size_t)gr * N + gc] = v2;
      }
      if(BF16OUT && gr < 1024){
        unsigned short h = f2bf(v2);
        Bh[(size_t)gr * N + gc] = h;
        Bl[(size_t)gr * N + gc] = f2bf(v2 - bf2f(h));
      }
    }
  }
}

// ---------------- MFMA split-bf16 main GEMM: 128x256, 3-buffer ring, SINGLE barrier per K-step ----------------
__global__ __launch_bounds__(512, 1) void k_gemm_mfma(
    const unsigned short* __restrict__ Ahi, const unsigned short* __restrict__ Alo,
    const unsigned short* __restrict__ Bhi, const unsigned short* __restrict__ Blo,
    const float* __restrict__ bias2, float* __restrict__ C, float* __restrict__ poolPart){
  __shared__ __align__(16) unsigned short lds[73728];   // 144 KB = 3 buffers
  int h0 = blockIdx.x;
  int h = (h0 & 7) * 86 + (h0 >> 3);   // bijective XCD swizzle: 688 = 8 * 86 (T1)
  int nt = h & 3, mt = h >> 2;
  int m0 = mt * 128, n0 = nt * 256;
  int t = threadIdx.x;
  int w = t >> 6, l = t & 63;
  int wm = w >> 2, wn = w & 3;
  int lr = l & 15, lk = l >> 4;

  const unsigned short* gptr[6];
  int dofs[6];
  #pragma unroll
  for(int s = 0; s < 6; ++s){
    int cc = w * 6 + s;
    int r = (cc < 8) ? 0 : (cc < 16) ? 1 : (cc < 32) ? 2 : 3;
    int cc0 = (r == 0) ? 0 : (r == 1) ? 8 : (r == 2) ? 16 : 32;
    int regofs = (r == 0) ? 0 : (r == 1) ? 4096 : (r == 2) ? 8192 : 16384;
    int cloc = cc - cc0;
    int rloc = cloc * 16 + (l >> 2);
    int q = (l & 3) ^ ((rloc >> 1) & 3);
    const unsigned short* gs = (r == 0) ? Ahi : (r == 1) ? Alo : (r == 2) ? Bhi : Blo;
    int rbase = (r < 2) ? m0 : n0;
    gptr[s] = gs + (size_t)(rbase + rloc) * DIM + q * 8;
    dofs[s] = regofs + cloc * 512;
  }

  f32x4v acc[4][4];
  #pragma unroll
  for(int i = 0; i < 4; ++i)
    #pragma unroll
    for(int j = 0; j < 4; ++j) acc[i][j] = (f32x4v){0.f, 0.f, 0.f, 0.f};

  int aofs[4], bofs[4];
  #pragma unroll
  for(int f = 0; f < 4; ++f){
    int ar = wm * 64 + f * 16 + lr;
    aofs[f] = ar * 32 + (lk ^ ((ar >> 1) & 3)) * 8;
    int bc = wn * 64 + f * 16 + lr;
    bofs[f] = bc * 32 + (lk ^ ((bc >> 1) & 3)) * 8;
  }

  #pragma unroll
  for(int s = 0; s < 6; ++s) gload16(gptr[s], lds + dofs[s]);
  #pragma unroll
  for(int s = 0; s < 6; ++s) gload16(gptr[s] + 32, lds + 24576 + dofs[s]);

  const int NT = DIM / 32;  // 24
  for(int k = 0; k < NT; ++k){
    int k0 = k * 32;
    if(k + 1 < NT){
      asm volatile("s_waitcnt vmcnt(6)" ::: "memory");   // tile k's 6 (oldest) complete
    } else {
      asm volatile("s_waitcnt vmcnt(0)" ::: "memory");
    }
    asm volatile("s_barrier" ::: "memory");              // tile k visible; prior reads of buf[(k+2)%3] done
    if(k + 2 < NT){
      unsigned short* dst = lds + ((k + 2) % 3) * 24576;
      #pragma unroll
      for(int s = 0; s < 6; ++s)
        gload16(gptr[s] + k0 + 64, dst + dofs[s]);
    }
    const unsigned short* Lb = lds + (k % 3) * 24576;
    bf16x8 bh[4], bl[4];
    #pragma unroll
    for(int f = 0; f < 4; ++f){
      bh[f] = *(const bf16x8*)&Lb[8192 + bofs[f]];
      bl[f] = *(const bf16x8*)&Lb[16384 + bofs[f]];
    }
    #pragma unroll
    for(int i = 0; i < 4; ++i){
      bf16x8 ahf = *(const bf16x8*)&Lb[aofs[i]];
      bf16x8 alf = *(const bf16x8*)&Lb[4096 + aofs[i]];
      #pragma unroll
      for(int j = 0; j < 4; ++j){
        acc[i][j] = __builtin_amdgcn_mfma_f32_16x16x32_bf16(ahf, bh[j], acc[i][j], 0, 0, 0);
        acc[i][j] = __builtin_amdgcn_mfma_f32_16x16x32_bf16(ahf, bl[j], acc[i][j], 0, 0, 0);
        acc[i][j] = __builtin_amdgcn_mfma_f32_16x16x32_bf16(alf, bh[j], acc[i][j], 0, 0, 0);
      }
    }
    // no end barrier: next step's start barrier orders reads-before-overwrite (3-buffer ring)
  }
  #pragma unroll
  for(int i = 0; i < 4; ++i){
    #pragma unroll
    for(int j = 0; j < 4; ++j){
      int col = n0 + wn * 64 + j * 16 + lr;
      if(col >= NCK) continue;
      float bv = bias2[col];
      #pragma unroll
      for(int r2 = 0; r2 < 4; ++r2){
        int row = m0 + wm * 64 + i * 16 + lk * 4 + r2;
        if(row < NTOT) C[(size_t)row * NCK + col] = acc[i][j][r2] + bv;
      }
    }
  }
  // ---- pooled partials ----
  float* psh = (float*)lds;
  int rb = ((m0 / NPATCH) + 1) * NPATCH;
  #pragma unroll
  for(int j = 0; j < 4; ++j){
    float s0 = 0.f, s1 = 0.f;
    #pragma unroll
    for(int i = 0; i < 4; ++i)
      #pragma unroll
      for(int r2 = 0; r2 < 4; ++r2){
        int row = m0 + wm * 64 + i * 16 + lk * 4 + r2;
        float v = acc[i][j][r2];
        if(row < rb) s0 += v; else s1 += v;
      }
    s0 += __shfl_xor(s0, 16); s0 += __shfl_xor(s0, 32);
    s1 += __shfl_xor(s1, 16); s1 += __shfl_xor(s1, 32);
    if(lk == 0){
      int cslot = wn * 64 + j * 16 + lr;
      if(wm == 0){ psh[cslot] = s0; psh[256 + cslot] = s1; }
      else        { psh[512 + cslot] = s0; psh[768 + cslot] = s1; }
    }
  }
  __syncthreads();
  if(t < 256){
    float* pp = poolPart + (size_t)h * 512;
    pp[t] = psh[t] + psh[512 + t];
    pp[256 + t] = psh[256 + t] + psh[768 + t];
  }
}

// ---------------- per-class masked Sinkhorn (rank computed in-block) ----------------
__global__ __launch_bounds__(256) void k_sinkhorn(const float* __restrict__ logits,
    const int* __restrict__ pl, const int* __restrict__ counts,
    const int* __restrict__ labels, float* __restrict__ Aw, float* __restrict__ assign_out){
  int c = blockIdx.x;
  int NcI = counts[c];
  if(NcI == 0) return;
  __shared__ int imgs[BIMG];
  __shared__ int nimgS;
  __shared__ float sh[256];
  int t = threadIdx.x;
  if(t == 0){
    int ni = 0;
    for(int b = 0; b < BIMG; ++b) if(labels[b] == c) imgs[ni++] = b;
    nimgS = ni;
  }
  __syncthreads();
  float prf = (t < NCLS && t < c && counts[t] > 0) ? 1.f : 0.f;
  int rankc = (int)(red256(prf, sh) + 0.5f);
  int tot = nimgS * NPATCH;
  float Ncf = (float)NcI;
  float invNc = 1.0f / Ncf;

  float sp = 0.f;
  for(int ii = t; ii < tot; ii += 256){
    int n = imgs[ii / NPATCH] * NPATCH + (ii % NPATCH);
    if(pl[n] != c) continue;
    const float* lg = logits + (size_t)n * NCK + c * KP;
    float* aw = Aw + (size_t)n * KP;
    float l0 = expf(lg[0] / 0.05f), l1 = expf(lg[1] / 0.05f), l2 = expf(lg[2] / 0.05f),
          l3 = expf(lg[3] / 0.05f), l4 = expf(lg[4] / 0.05f);
    aw[0] = l0; aw[1] = l1; aw[2] = l2; aw[3] = l3; aw[4] = l4;
    sp += l0 + l1 + l2 + l3 + l4;
  }
  float S = red256(sp, sh);
  float sc = 1.0f / (S + 1e-16f);

  float cs0 = 0, cs1 = 0, cs2 = 0, cs3 = 0, cs4 = 0;
  for(int ii = t; ii < tot; ii += 256){
    int n = imgs[ii / NPATCH] * NPATCH + (ii % NPATCH);
    if(pl[n] != c) continue;
    float* aw = Aw + (size_t)n * KP;
    float l0 = aw[0]*sc, l1 = aw[1]*sc, l2 = aw[2]*sc, l3 = aw[3]*sc, l4 = aw[4]*sc;
    aw[0] = l0; aw[1] = l1; aw[2] = l2; aw[3] = l3; aw[4] = l4;
    cs0 += l0; cs1 += l1; cs2 += l2; cs3 += l3; cs4 += l4;
  }
  cs0 = red256(cs0, sh); cs1 = red256(cs1, sh); cs2 = red256(cs2, sh);
  cs3 = red256(cs3, sh); cs4 = red256(cs4, sh);

  for(int it = 0; it < 3; ++it){
    float m0 = 1.0f/(cs0+1e-16f), m1 = 1.0f/(cs1+1e-16f), m2 = 1.0f/(cs2+1e-16f),
          m3 = 1.0f/(cs3+1e-16f), m4 = 1.0f/(cs4+1e-16f);
    bool last = (it == 2);
    float n0 = 0, n1 = 0, n2 = 0, n3 = 0, n4 = 0;
    for(int ii = t; ii < tot; ii += 256){
      int n = imgs[ii / NPATCH] * NPATCH + (ii % NPATCH);
      if(pl[n] != c) continue;
      float* aw = Aw + (size_t)n * KP;
      float l0 = aw[0]*m0*0.2f, l1 = aw[1]*m1*0.2f, l2 = aw[2]*m2*0.2f,
            l3 = aw[3]*m3*0.2f, l4 = aw[4]*m4*0.2f;
      float rs = l0 + l1 + l2 + l3 + l4;
      float rw = 1.0f / (rs + 1e-16f);
      if(last){
        l0 *= rw; l1 *= rw; l2 *= rw; l3 *= rw; l4 *= rw;
        aw[0] = l0; aw[1] = l1; aw[2] = l2; aw[3] = l3; aw[4] = l4;
        int am = 0; float bv = l0;
        if(l1 > bv){ bv = l1; am = 1; }
        if(l2 > bv){ bv = l2; am = 2; }
        if(l3 > bv){ bv = l3; am = 3; }
        if(l4 > bv){ bv = l4; am = 4; }
        assign_out[n] = (float)(am + KP * rankc);
      } else {
        float w2 = rw * invNc;
        l0 *= w2; l1 *= w2; l2 *= w2; l3 *= w2; l4 *= w2;
        aw[0] = l0; aw[1] = l1; aw[2] = l2; aw[3] = l3; aw[4] = l4;
        n0 += l0; n1 += l1; n2 += l2; n3 += l3; n4 += l4;
      }
    }
    if(!last){
      cs0 = red256(n0, sh); cs1 = red256(n1, sh); cs2 = red256(n2, sh);
      cs3 = red256(n3, sh); cs4 = red256(n4, sh);
    }
  }
}

// ---------------- P_new partial sums (USEA: read bf16 normalized rows) ----------------
template<int USEA>
__global__ __launch_bounds__(256) void k_pnew_part(const float* __restrict__ X,
    const float* __restrict__ rinv, const unsigned short* __restrict__ Ahi,
    const float* __restrict__ Aw,
    const int* __restrict__ pl, const int* __restrict__ labels,
    float* __restrict__ part){
  int b = blockIdx.y, ch = blockIdx.x;
  int c = labels[b];
  int t = threadIdx.x;
  int j0 = ch * 86, j1 = j0 + 86; if(j1 > NPATCH) j1 = NPATCH;
  float acc[3][5] = {};
  for(int j = j0; j < j1; ++j){
    int n = b * NPATCH + j;
    if(pl[n] != c) continue;
    const float* aw = Aw + (size_t)n * KP;
    float a0 = aw[0], a1 = aw[1], a2 = aw[2], a3 = aw[3], a4 = aw[4];
    float rv = USEA ? 1.0f : rinv[n];
    #pragma unroll
    for(int dj = 0; dj < 3; ++dj){
      float x;
      if(USEA) x = bf2f(Ahi[(size_t)n * DIM + t + dj * 256]);
      else     x = X[(size_t)n * DIM + t + dj * 256] * rv;
      acc[dj][0] += a0 * x; acc[dj][1] += a1 * x; acc[dj][2] += a2 * x;
      acc[dj][3] += a3 * x; acc[dj][4] += a4 * x;
    }
  }
  float* po = part + ((size_t)(b * PCH + ch)) * KP * DIM;
  #pragma unroll
  for(int k = 0; k < 5; ++k)
    #pragma unroll
    for(int dj = 0; dj < 3; ++dj)
      po[k * DIM + t + dj * 256] = acc[dj][k];
}

// ---------------- fused tail: P_new final (blocks 0..200) + pooled gather + sa head (blocks 201..216) ----------------
__global__ __launch_bounds__(256) void k_tailm(const float* __restrict__ P,
    const float* __restrict__ part, const int* __restrict__ counts,
    const int* __restrict__ labels, float* __restrict__ out_np,
    const float* __restrict__ poolPart, const float* __restrict__ bias2,
    const float* __restrict__ sa, float* __restrict__ pooled, float* __restrict__ out){
  __shared__ float ps[1024];
  __shared__ int imgs[BIMG];
  __shared__ int nimgS;
  int t = threadIdx.x;
  if(blockIdx.x < CDIM){
    int c = blockIdx.x;
    bool pres = (c < NCLS) && (counts[c] > 0);
    const float* Pc = P + (size_t)c * KP * DIM;
    float* Oc = out_np + (size_t)c * KP * DIM;
    if(!pres){
      for(int i = t; i < KP * DIM; i += 256) Oc[i] = Pc[i];
      return;
    }
    if(t == 0){
      int ni = 0;
      for(int b = 0; b < BIMG; ++b) if(labels[b] == c) imgs[ni++] = b;
      nimgS = ni;
    }
    __syncthreads();
    int ni = nimgS;
    for(int i = t; i < KP * DIM; i += 256){
      float s = 0.f;
      for(int q = 0; q < ni; ++q){
        const float* pb = part + ((size_t)(imgs[q] * PCH)) * KP * DIM + i;
        for(int ch = 0; ch < PCH; ++ch) s += pb[(size_t)ch * KP * DIM];
      }
      Oc[i] = 0.99f * Pc[i] + 0.01f * s;
    }
  } else {
    int b = blockIdx.x - CDIM;
    int mt_lo = (b * NPATCH) >> 7;
    int mt_hi = ((b + 1) * NPATCH - 1) >> 7;
    #pragma unroll
    for(int g = 0; g < 4; ++g){
      int col = g * 256 + t;
      float s = 0.f;
      for(int mt = mt_lo; mt <= mt_hi; ++mt){
        int img0 = (mt * 128) / NPATCH;
        int buck = (img0 == b) ? 0 : 1;
        s += poolPart[((size_t)(mt * 4 + g)) * 512 + buck * 256 + t];
      }
      float pv = s / 1369.0f + ((col < NCK) ? bias2[col] : 0.f);
      if(col < NCK) pooled[(size_t)b * NCK + col] = pv;
      ps[col] = pv;
    }
    __syncthreads();
    if(t < NCLS){
      float sa0 = sa[t*5+0], sa1 = sa[t*5+1], sa2 = sa[t*5+2], sa3 = sa[t*5+3], sa4 = sa[t*5+4];
      float mx = fmaxf(fmaxf(fmaxf(sa0, sa1), fmaxf(sa2, sa3)), sa4);
      float e0 = expf(sa0 - mx), e1 = expf(sa1 - mx), e2 = expf(sa2 - mx),
            e3 = expf(sa3 - mx), e4 = expf(sa4 - mx);
      float se = e0 + e1 + e2 + e3 + e4;
      float iv = 5.0f / se;
      const float* p = ps + t * KP;
      out[b * NCLS + t] = p[0]*e0*iv + p[1]*e1*iv + p[2]*e2*iv + p[3]*e3*iv + p[4]*e4*iv;
    }
  }
}

// ---------------- P_new final (fallback) ----------------
__global__ __launch_bounds__(256) void k_pnew_fin(const float* __restrict__ P,
    const float* __restrict__ part, const int* __restrict__ counts,
    const int* __restrict__ labels, float* __restrict__ out_np){
  int c = blockIdx.x;
  int t = threadIdx.x;
  bool pres = (c < NCLS) && (counts[c] > 0);
  const float* Pc = P + (size_t)c * KP * DIM;
  float* Oc = out_np + (size_t)c * KP * DIM;
  if(!pres){
    for(int i = t; i < KP * DIM; i += 256) Oc[i] = Pc[i];
    return;
  }
  __shared__ int imgs[BIMG];
  __shared__ int nimgS;
  if(t == 0){
    int ni = 0;
    for(int b = 0; b < BIMG; ++b) if(labels[b] == c) imgs[ni++] = b;
    nimgS = ni;
  }
  __syncthreads();
  int ni = nimgS;
  for(int i = t; i < KP * DIM; i += 256){
    float s = 0.f;
    for(int q = 0; q < ni; ++q){
      const float* pb = part + ((size_t)(imgs[q] * PCH)) * KP * DIM + i;
      for(int ch = 0; ch < PCH; ++ch) s += pb[(size_t)ch * KP * DIM];
    }
    Oc[i] = 0.99f * Pc[i] + 0.01f * s;
  }
}

// ---------------- pooled stage 1 (fallback only) ----------------
__global__ __launch_bounds__(256) void k_pool1(const float* __restrict__ logits,
    float* __restrict__ poolPart){
  int b = blockIdx.y, ch = blockIdx.x;
  int t = threadIdx.x;
  int j0 = ch * 43, j1 = j0 + 43; if(j1 > NPATCH) j1 = NPATCH;
  float a0 = 0, a1 = 0, a2 = 0, a3 = 0;
  for(int j = j0; j < j1; ++j){
    const float* row = logits + ((size_t)(b * NPATCH + j)) * NCK;
    a0 += row[t]; a1 += row[t + 256]; a2 += row[t + 512];
    if(t < 237) a3 += row[t + 768];
  }
  float* po = poolPart + ((size_t)(b * QCH + ch)) * 1024;
  po[t] = a0; po[t + 256] = a1; po[t + 512] = a2;
  if(t < 237) po[t + 768] = a3;
}

// ---------------- pooled stage 2 + sa head (fallback) ----------------
__global__ __launch_bounds__(256) void k_pool2cls(const float* __restrict__ poolPart,
    const float* __restrict__ bias2, const float* __restrict__ sa,
    float* __restrict__ pooled, float* __restrict__ out){
  __shared__ float ps[1024];
  int b = blockIdx.x;
  int t = threadIdx.x;
  float s0 = 0, s1 = 0, s2 = 0, s3 = 0;
  const float* pb = poolPart + ((size_t)(b * QCH)) * 1024;
  for(int ch = 0; ch < QCH; ++ch){
    const float* p = pb + (size_t)ch * 1024;
    s0 += p[t]; s1 += p[t + 256]; s2 += p[t + 512];
    if(t < 237) s3 += p[t + 768];
  }
  float* o = pooled + (size_t)b * NCK;
  float o0 = s0 / 1369.0f, o1 = s1 / 1369.0f, o2 = s2 / 1369.0f, o3 = s3 / 1369.0f;
  o[t] = o0; o[t + 256] = o1; o[t + 512] = o2;
  if(t < 237) o[t + 768] = o3;
  ps[t] = o0; ps[t + 256] = o1; ps[t + 512] = o2;
  if(t < 237) ps[t + 768] = o3;
  __syncthreads();
  if(t < NCLS){
    float sa0 = sa[t*5+0], sa1 = sa[t*5+1], sa2 = sa[t*5+2], sa3 = sa[t*5+3], sa4 = sa[t*5+4];
    float mx = fmaxf(fmaxf(fmaxf(sa0, sa1), fmaxf(sa2, sa3)), sa4);
    float e0 = expf(sa0 - mx), e1 = expf(sa1 - mx), e2 = expf(sa2 - mx),
          e3 = expf(sa3 - mx), e4 = expf(sa4 - mx);
    float se = e0 + e1 + e2 + e3 + e4;
    float iv = 5.0f / se;
    const float* p = ps + t * KP;
    out[b * NCLS + t] = p[0]*e0*iv + p[1]*e1*iv + p[2]*e2*iv + p[3]*e3*iv + p[4]*e4*iv;
  }
}

extern "C" void kernel_launch(void* const* d_in, const int* in_sizes, int n_in,
                              void* d_out, int out_size, void* d_ws, size_t ws_size,
                              hipStream_t stream){
  const float* X      = (const float*)d_in[0];
  const int*   labels = (const int*)d_in[1];
  const float* P      = (const float*)d_in[2];
  const float* W      = (const float*)d_in[3];
  const float* bvec   = (const float*)d_in[4];
  const float* sa     = (const float*)d_in[5];

  float* out        = (float*)d_out;
  float* out_cls    = out;
  float* out_logits = out + 3200;
  float* out_pooled = out_logits + (size_t)NTOT * NCK;
  float* out_assign = out_pooled + BIMG * NCK;
  float* out_np     = out_assign + NTOT;
  float* out_pseudo = out_np + (size_t)CDIM * KP * DIM;

  const size_t AHI_F = (size_t)MPAD * DIM / 2;   // ushort array in float units
  const size_t BHI_F = (size_t)1024 * DIM / 2;
  const size_t MFMA_F = 2 * AHI_F + 2 * BHI_F;
  const size_t BASE_F = 4050000;
  bool use_mfma = ws_size >= (MFMA_F + BASE_F) * sizeof(float);

  float* ws = (float*)d_ws;
  unsigned short* Ahi = (unsigned short*)ws;
  unsigned short* Alo = (unsigned short*)(ws + AHI_F);
  unsigned short* Bhi = (unsigned short*)(ws + 2 * AHI_F);
  unsigned short* Blo = (unsigned short*)(ws + 2 * AHI_F + BHI_F);
  float* base = use_mfma ? (ws + MFMA_F) : ws;

  float* protn  = base;
  float* Bmat   = protn + (size_t)NCK * DIM;
  float* bias2  = Bmat + (size_t)NCK * DIM;
  float* rinv   = bias2 + 1024;
  float* uvec   = rinv + NTOT;
  float* Aw     = uvec + NTOT;
  float* meanv  = Aw + (size_t)NTOT * KP;
  float* wvb    = meanv + DIM;
  float* pbuf   = wvb + DIM;
  float* subuf  = pbuf + (size_t)UCH * DIM;
  float* parts  = subuf + UCH;
  float* scal   = parts + 32;
  int*   pli    = (int*)(scal + 8);
  int*   counts = pli + NTOT;
  float* pnewP  = (float*)(counts + 256);
  float* poolP  = pnewP + (size_t)BIMG * PCH * KP * DIM;
  unsigned* enc = (unsigned*)(scal + 1);

  k_colmean1<<<512, 256, 0, stream>>>(X, pbuf);
  k_meanred<<<12, 256, 0, stream>>>(pbuf, meanv, wvb, parts, counts, enc);
  for(int i = 0; i < 10; ++i){
    k_pcapass<<<UCH, 256, 0, stream>>>(X, wvb, parts, pbuf, subuf);
    k_pcared<<<12, 256, 0, stream>>>(pbuf, subuf, meanv, wvb, parts);
  }
  if(use_mfma){
    k_ufinal<1><<<UCH, 256, 0, stream>>>(X, wvb, parts, uvec, enc, rinv, Ahi, Alo);
  } else {
    k_ufinal<0><<<UCH, 256, 0, stream>>>(X, wvb, parts, uvec, enc, nullptr, nullptr, nullptr);
    k_rnorm<<<5476, 256, 0, stream>>>(X, rinv);
  }
  k_pseudo<<<86, 256, 0, stream>>>(uvec, enc, labels, pli, out_pseudo, out_assign, counts);
  k_protn<<<252, 256, 0, stream>>>(P, bvec, protn, bias2);
  if(use_mfma){
    k_gemm_nt<0, 0, 1, 1><<<dim3(12, 16), 256, 0, stream>>>(protn, W, Bmat, nullptr, nullptr,
                                                            protn, Bhi, Blo, NCK, DIM, DIM);
    k_gemm_mfma<<<688, 512, 0, stream>>>(Ahi, Alo, Bhi, Blo, bias2, out_logits, poolP);
  } else {
    k_gemm_nt<0, 0, 1, 0><<<dim3(12, 16), 256, 0, stream>>>(protn, W, Bmat, nullptr, nullptr,
                                                            protn, nullptr, nullptr, NCK, DIM, DIM);
    k_gemm_nt<1, 1, 0, 0><<<dim3(16, 343), 256, 0, stream>>>(X, Bmat, out_logits, rinv, bias2,
                                                             nullptr, nullptr, nullptr, NTOT, NCK, DIM);
  }
  k_sinkhorn<<<NCLS, 256, 0, stream>>>(out_logits, pli, counts, labels, Aw, out_assign);
  if(use_mfma){
    k_pnew_part<1><<<dim3(PCH, BIMG), 256, 0, stream>>>(nullptr, nullptr, Ahi, Aw, pli, labels, pnewP);
    k_tailm<<<CDIM + BIMG, 256, 0, stream>>>(P, pnewP, counts, labels, out_np,
                                             poolP, bias2, sa, out_pooled, out_cls);
  } else {
    k_pnew_part<0><<<dim3(PCH, BIMG), 256, 0, stream>>>(X, rinv, nullptr, Aw, pli, labels, pnewP);
    k_pnew_fin<<<CDIM, 256, 0, stream>>>(P, pnewP, counts, labels, out_np);
    k_pool1<<<dim3(QCH, BIMG), 256, 0, stream>>>(out_logits, poolP);
    k_pool2cls<<<BIMG, 256, 0, stream>>>(poolP, bias2, sa, out_pooled, out_cls);
  }
}

// Round 18
// 556.067 us; speedup vs baseline: 1.2491x; 1.0106x over previous
//
#include <hip/hip_runtime.h>

#define NTOT 21904
#define MPAD 22016
#define NPATCH 1369
#define BIMG 16
#define DIM 768
#define NCLS 200
#define CDIM 201
#define KP 5
#define NCK 1005
#define PCH 16   // pnew patch chunks per image
#define QCH 32   // pool patch chunks per image (fallback)
#define UCH 1024 // pca pass partial chunks

typedef short bf16x8 __attribute__((ext_vector_type(8)));
typedef float f32x4v __attribute__((ext_vector_type(4)));

__device__ __forceinline__ unsigned encf(float x){
  unsigned b = __float_as_uint(x);
  return (b & 0x80000000u) ? ~b : (b | 0x80000000u);
}
__device__ __forceinline__ float decf(unsigned e){
  return (e & 0x80000000u) ? __uint_as_float(e ^ 0x80000000u) : __uint_as_float(~e);
}
__device__ __forceinline__ unsigned short f2bf(float f){
  unsigned u = __float_as_uint(f);
  u += 0x7FFFu + ((u >> 16) & 1u);
  return (unsigned short)(u >> 16);
}
__device__ __forceinline__ float bf2f(unsigned short h){
  return __uint_as_float(((unsigned)h) << 16);
}
__device__ __forceinline__ void gload16(const unsigned short* g, unsigned short* l){
  __builtin_amdgcn_global_load_lds(
      (const __attribute__((address_space(1))) unsigned int*)g,
      (__attribute__((address_space(3))) unsigned int*)l, 16, 0, 0);
}

__device__ __forceinline__ float red256(float v, float* sh){
  int t = threadIdx.x;
  sh[t] = v; __syncthreads();
  for(int s = 128; s > 0; s >>= 1){ if(t < s) sh[t] += sh[t+s]; __syncthreads(); }
  float r = sh[0]; __syncthreads();
  return r;
}

// ---------------- column sums, 512 chunks x 43 rows (FROZEN ORDER) ----------------
__global__ __launch_bounds__(256) void k_colmean1(const float* __restrict__ X, float* __restrict__ pbuf){
  int b = blockIdx.x, t = threadIdx.x;
  int n0 = b * 43, n1 = n0 + 43; if(n1 > NTOT) n1 = NTOT;
  float s0 = 0.f, s1 = 0.f, s2 = 0.f;
  #pragma unroll 4
  for(int n = n0; n < n1; ++n){
    const float* row = X + (size_t)n * DIM;
    s0 += row[t]; s1 += row[t + 256]; s2 += row[t + 512];
  }
  float* pb = pbuf + (size_t)b * DIM;
  pb[t] = s0; pb[t + 256] = s1; pb[t + 512] = s2;
}

// ---------------- mean + wv init + 12-way parts; also init counts/enc (FROZEN ORDER) ----------------
__global__ __launch_bounds__(256) void k_meanred(const float* __restrict__ pbuf,
    float* __restrict__ meanv, float* __restrict__ wvb, float* __restrict__ parts,
    int* __restrict__ counts, unsigned* __restrict__ enc){
  __shared__ float sh[256];
  int cg = blockIdx.x, t = threadIdx.x;
  if(cg == 0){
    if(t < CDIM) counts[t] = 0;
    if(t == 0){ enc[0] = 0xFFFFFFFFu; enc[1] = 0u; }
  }
  int tc = t & 63, th = t >> 6;
  int col = cg * 64 + tc;
  const float v0 = 0.036084391824351615f;   // 1/sqrt(768)
  float s = 0.f;
  #pragma unroll 32
  for(int ch = th; ch < 512; ch += 4) s += pbuf[ch * DIM + col];
  sh[t] = s; __syncthreads();
  float mcontrib = 0.f;
  if(th == 0){
    float m = (sh[tc] + sh[64 + tc] + sh[128 + tc] + sh[192 + tc]) / 21904.0f;
    meanv[col] = m;
    wvb[col] = v0;
    mcontrib = m * v0;
  }
  __syncthreads();
  float md = red256(mcontrib, sh);
  if(t == 0){ parts[cg] = 64.0f * v0 * v0; parts[16 + cg] = md; }
}

// ---------------- power-iteration pass (FROZEN ORDER; 3-row batch + 2-row tail batch, bit-identical) ----------------
__global__ __launch_bounds__(256) void k_pcapass(const float* __restrict__ X,
    const float* __restrict__ wvb, const float* __restrict__ parts,
    float* __restrict__ pbuf, float* __restrict__ subuf){
  __shared__ float shacc[4][DIM];
  __shared__ float shsu[4];
  int t = threadIdx.x, w = t >> 6, l = t & 63;
  float nrm2 = 0.f, mvr = 0.f;
  #pragma unroll
  for(int i = 0; i < 12; ++i){ nrm2 += parts[i]; mvr += parts[16 + i]; }
  float invD = 1.0f / (sqrtf(nrm2) + 1e-12f);
  const float4* v4 = (const float4*)(wvb + l * 12);
  float4 v0 = v4[0], v1 = v4[1], v2 = v4[2];
  float4 a0 = {0,0,0,0}, a1 = {0,0,0,0}, a2 = {0,0,0,0};
  float su = 0.f;
  int n = blockIdx.x * 4 + w;
  while(n + 8192 < NTOT){
    const float4* xa4 = (const float4*)(X + (size_t)n * DIM + l * 12);
    const float4* xb4 = (const float4*)(X + (size_t)(n + 4096) * DIM + l * 12);
    const float4* xc4 = (const float4*)(X + (size_t)(n + 8192) * DIM + l * 12);
    float4 xa0 = xa4[0], xa1 = xa4[1], xa2 = xa4[2];
    float4 xb0 = xb4[0], xb1 = xb4[1], xb2 = xb4[2];
    float4 xc0 = xc4[0], xc1 = xc4[1], xc2 = xc4[2];
    float tpA = xa0.x*v0.x + xa0.y*v0.y + xa0.z*v0.z + xa0.w*v0.w
              + xa1.x*v1.x + xa1.y*v1.y + xa1.z*v1.z + xa1.w*v1.w
              + xa2.x*v2.x + xa2.y*v2.y + xa2.z*v2.z + xa2.w*v2.w;
    float tpB = xb0.x*v0.x + xb0.y*v0.y + xb0.z*v0.z + xb0.w*v0.w
              + xb1.x*v1.x + xb1.y*v1.y + xb1.z*v1.z + xb1.w*v1.w
              + xb2.x*v2.x + xb2.y*v2.y + xb2.z*v2.z + xb2.w*v2.w;
    float tpC = xc0.x*v0.x + xc0.y*v0.y + xc0.z*v0.z + xc0.w*v0.w
              + xc1.x*v1.x + xc1.y*v1.y + xc1.z*v1.z + xc1.w*v1.w
              + xc2.x*v2.x + xc2.y*v2.y + xc2.z*v2.z + xc2.w*v2.w;
    #pragma unroll
    for(int o = 32; o > 0; o >>= 1){
      tpA += __shfl_xor(tpA, o);
      tpB += __shfl_xor(tpB, o);
      tpC += __shfl_xor(tpC, o);
    }
    tpA = (tpA - mvr) * invD;
    tpB = (tpB - mvr) * invD;
    tpC = (tpC - mvr) * invD;
    a0.x += tpA*xa0.x; a0.y += tpA*xa0.y; a0.z += tpA*xa0.z; a0.w += tpA*xa0.w;
    a1.x += tpA*xa1.x; a1.y += tpA*xa1.y; a1.z += tpA*xa1.z; a1.w += tpA*xa1.w;
    a2.x += tpA*xa2.x; a2.y += tpA*xa2.y; a2.z += tpA*xa2.z; a2.w += tpA*xa2.w;
    a0.x += tpB*xb0.x; a0.y += tpB*xb0.y; a0.z += tpB*xb0.z; a0.w += tpB*xb0.w;
    a1.x += tpB*xb1.x; a1.y += tpB*xb1.y; a1.z += tpB*xb1.z; a1.w += tpB*xb1.w;
    a2.x += tpB*xb2.x; a2.y += tpB*xb2.y; a2.z += tpB*xb2.z; a2.w += tpB*xb2.w;
    a0.x += tpC*xc0.x; a0.y += tpC*xc0.y; a0.z += tpC*xc0.z; a0.w += tpC*xc0.w;
    a1.x += tpC*xc1.x; a1.y += tpC*xc1.y; a1.z += tpC*xc1.z; a1.w += tpC*xc1.w;
    a2.x += tpC*xc2.x; a2.y += tpC*xc2.y; a2.z += tpC*xc2.z; a2.w += tpC*xc2.w;
    if(l == 0){ su += tpA; su += tpB; su += tpC; }
    n += 12288;
  }
  if(n + 4096 < NTOT){   // 2-row tail batch (bit-identical accumulation order)
    const float4* xa4 = (const float4*)(X + (size_t)n * DIM + l * 12);
    const float4* xb4 = (const float4*)(X + (size_t)(n + 4096) * DIM + l * 12);
    float4 xa0 = xa4[0], xa1 = xa4[1], xa2 = xa4[2];
    float4 xb0 = xb4[0], xb1 = xb4[1], xb2 = xb4[2];
    float tpA = xa0.x*v0.x + xa0.y*v0.y + xa0.z*v0.z + xa0.w*v0.w
              + xa1.x*v1.x + xa1.y*v1.y + xa1.z*v1.z + xa1.w*v1.w
              + xa2.x*v2.x + xa2.y*v2.y + xa2.z*v2.z + xa2.w*v2.w;
    float tpB = xb0.x*v0.x + xb0.y*v0.y + xb0.z*v0.z + xb0.w*v0.w
              + xb1.x*v1.x + xb1.y*v1.y + xb1.z*v1.z + xb1.w*v1.w
              + xb2.x*v2.x + xb2.y*v2.y + xb2.z*v2.z + xb2.w*v2.w;
    #pragma unroll
    for(int o = 32; o > 0; o >>= 1){
      tpA += __shfl_xor(tpA, o);
      tpB += __shfl_xor(tpB, o);
    }
    tpA = (tpA - mvr) * invD;
    tpB = (tpB - mvr) * invD;
    a0.x += tpA*xa0.x; a0.y += tpA*xa0.y; a0.z += tpA*xa0.z; a0.w += tpA*xa0.w;
    a1.x += tpA*xa1.x; a1.y += tpA*xa1.y; a1.z += tpA*xa1.z; a1.w += tpA*xa1.w;
    a2.x += tpA*xa2.x; a2.y += tpA*xa2.y; a2.z += tpA*xa2.z; a2.w += tpA*xa2.w;
    a0.x += tpB*xb0.x; a0.y += tpB*xb0.y; a0.z += tpB*xb0.z; a0.w += tpB*xb0.w;
    a1.x += tpB*xb1.x; a1.y += tpB*xb1.y; a1.z += tpB*xb1.z; a1.w += tpB*xb1.w;
    a2.x += tpB*xb2.x; a2.y += tpB*xb2.y; a2.z += tpB*xb2.z; a2.w += tpB*xb2.w;
    if(l == 0){ su += tpA; su += tpB; }
    n += 8192;
  }
  while(n < NTOT){
    const float4* x4 = (const float4*)(X + (size_t)n * DIM + l * 12);
    float4 x0 = x4[0], x1 = x4[1], x2 = x4[2];
    float tp = x0.x*v0.x + x0.y*v0.y + x0.z*v0.z + x0.w*v0.w
             + x1.x*v1.x + x1.y*v1.y + x1.z*v1.z + x1.w*v1.w
             + x2.x*v2.x + x2.y*v2.y + x2.z*v2.z + x2.w*v2.w;
    #pragma unroll
    for(int o = 32; o > 0; o >>= 1) tp += __shfl_xor(tp, o);
    tp = (tp - mvr) * invD;
    a0.x += tp*x0.x; a0.y += tp*x0.y; a0.z += tp*x0.z; a0.w += tp*x0.w;
    a1.x += tp*x1.x; a1.y += tp*x1.y; a1.z += tp*x1.z; a1.w += tp*x1.w;
    a2.x += tp*x2.x; a2.y += tp*x2.y; a2.z += tp*x2.z; a2.w += tp*x2.w;
    if(l == 0) su += tp;
    n += 4096;
  }
  float4* sh4 = (float4*)&shacc[w][l * 12];
  sh4[0] = a0; sh4[1] = a1; sh4[2] = a2;
  if(l == 0) shsu[w] = su;
  __syncthreads();
  for(int c = t; c < DIM; c += 256)
    pbuf[blockIdx.x * DIM + c] = shacc[0][c] + shacc[1][c] + shacc[2][c] + shacc[3][c];
  if(t == 0) subuf[blockIdx.x] = shsu[0] + shsu[1] + shsu[2] + shsu[3];
}

// ---------------- reduce partials -> new wv + 12-way parts (FROZEN ORDER) ----------------
__global__ __launch_bounds__(256) void k_pcared(const float* __restrict__ pbuf,
    const float* __restrict__ subuf, const float* __restrict__ meanv,
    float* __restrict__ wvb, float* __restrict__ parts){
  __shared__ float sh[256];
  int cg = blockIdx.x, t = threadIdx.x;
  float sv = subuf[t] + subuf[t + 256] + subuf[t + 512] + subuf[t + 768];
  float su = red256(sv, sh);
  int tc = t & 63, th = t >> 6;
  int col = cg * 64 + tc;
  float s = 0.f;
  #pragma unroll 64
  for(int ch = th; ch < UCH; ch += 4) s += pbuf[(size_t)ch * DIM + col];
  sh[t] = s; __syncthreads();
  float csq = 0.f, cmd = 0.f;
  if(th == 0){
    float wvn = (sh[tc] + sh[64 + tc] + sh[128 + tc] + sh[192 + tc]) - meanv[col] * su;
    wvb[col] = wvn;
    csq = wvn * wvn;
    cmd = meanv[col] * wvn;
  }
  __syncthreads();
  float sq = red256(csq, sh);
  float md = red256(cmd, sh);
  if(t == 0){ parts[cg] = sq; parts[16 + cg] = md; }
}

// ---------------- final u = Xc v + min/max; PREP: fused rinv + bf16 hi/lo split (FROZEN) ----------------
template<int PREP>
__global__ __launch_bounds__(256) void k_ufinal(const float* __restrict__ X,
    const float* __restrict__ wvb, const float* __restrict__ parts,
    float* __restrict__ u, unsigned* __restrict__ enc,
    float* __restrict__ rinv, unsigned short* __restrict__ Ahi, unsigned short* __restrict__ Alo){
  __shared__ float smn[4], smx[4];
  int t = threadIdx.x, w = t >> 6, l = t & 63;
  float nrm2 = 0.f, mvr = 0.f;
  #pragma unroll
  for(int i = 0; i < 12; ++i){ nrm2 += parts[i]; mvr += parts[16 + i]; }
  float invD = 1.0f / (sqrtf(nrm2) + 1e-12f);
  const float4* v4 = (const float4*)(wvb + l * 12);
  float4 v0 = v4[0], v1 = v4[1], v2 = v4[2];
  float lmn = 3.4e38f, lmx = -3.4e38f;
  int nend = PREP ? MPAD : NTOT;
  for(int n = blockIdx.x * 4 + w; n < nend; n += 4096){
    size_t off = (size_t)n * DIM + l * 12;
    if(PREP && n >= NTOT){
      ushort4 z = make_ushort4(0, 0, 0, 0);
      #pragma unroll
      for(int j = 0; j < 3; ++j){
        *(ushort4*)(Ahi + off + j * 4) = z;
        *(ushort4*)(Alo + off + j * 4) = z;
      }
      continue;
    }
    const float4* x4 = (const float4*)(X + off);
    float4 x0 = x4[0], x1 = x4[1], x2 = x4[2];
    float tp = x0.x*v0.x + x0.y*v0.y + x0.z*v0.z + x0.w*v0.w
             + x1.x*v1.x + x1.y*v1.y + x1.z*v1.z + x1.w*v1.w
             + x2.x*v2.x + x2.y*v2.y + x2.z*v2.z + x2.w*v2.w;
    #pragma unroll
    for(int o = 32; o > 0; o >>= 1) tp += __shfl_xor(tp, o);
    tp = (tp - mvr) * invD;
    if(l == 0){ u[n] = tp; lmn = fminf(lmn, tp); lmx = fmaxf(lmx, tp); }
    if(PREP){
      float s = x0.x*x0.x + x0.y*x0.y + x0.z*x0.z + x0.w*x0.w
              + x1.x*x1.x + x1.y*x1.y + x1.z*x1.z + x1.w*x1.w
              + x2.x*x2.x + x2.y*x2.y + x2.z*x2.z + x2.w*x2.w;
      #pragma unroll
      for(int o = 32; o > 0; o >>= 1) s += __shfl_xor(s, o);
      float rv = 1.0f / (sqrtf(s) + 1e-12f);
      if(l == 0) rinv[n] = rv;
      float xs[12] = {x0.x*rv, x0.y*rv, x0.z*rv, x0.w*rv,
                      x1.x*rv, x1.y*rv, x1.z*rv, x1.w*rv,
                      x2.x*rv, x2.y*rv, x2.z*rv, x2.w*rv};
      unsigned short hi[12], lo[12];
      #pragma unroll
      for(int j = 0; j < 12; ++j){
        hi[j] = f2bf(xs[j]);
        lo[j] = f2bf(xs[j] - bf2f(hi[j]));
      }
      #pragma unroll
      for(int j = 0; j < 3; ++j){
        *(ushort4*)(Ahi + off + j * 4) = make_ushort4(hi[j*4], hi[j*4+1], hi[j*4+2], hi[j*4+3]);
        *(ushort4*)(Alo + off + j * 4) = make_ushort4(lo[j*4], lo[j*4+1], lo[j*4+2], lo[j*4+3]);
      }
    }
  }
  if(l == 0){ smn[w] = lmn; smx[w] = lmx; }
  __syncthreads();
  if(t == 0){
    float mn = fminf(fminf(smn[0], smn[1]), fminf(smn[2], smn[3]));
    float mx = fmaxf(fmaxf(smx[0], smx[1]), fmaxf(smx[2], smx[3]));
    atomicMin(&enc[0], encf(mn));
    atomicMax(&enc[1], encf(mx));
  }
}

// ---------------- pseudo labels (FROZEN threshold path; counts via LDS histogram) ----------------
__global__ __launch_bounds__(256) void k_pseudo(const float* __restrict__ u,
    const unsigned* __restrict__ enc, const int* __restrict__ labels,
    int* __restrict__ pl, float* __restrict__ pseudo_out,
    float* __restrict__ assign_out, int* __restrict__ counts){
  __shared__ int lc[CDIM];
  int t = threadIdx.x;
  for(int i = t; i < CDIM; i += 256) lc[i] = 0;
  __syncthreads();
  int n = blockIdx.x * 256 + t;
  if(n < NTOT){
    float mn = decf(enc[0]), mx = decf(enc[1]);
    float us = (u[n] - mn) / (mx - mn);
    int b = n / NPATCH;
    int p = (us <= 0.5f) ? labels[b] : NCLS;
    pl[n] = p;
    pseudo_out[n] = (float)p;
    assign_out[n] = -1.0f;
    atomicAdd(&lc[p], 1);
  }
  __syncthreads();
  for(int i = t; i < CDIM; i += 256)
    if(lc[i] > 0) atomicAdd(&counts[i], lc[i]);
}

// ---------------- row norms (fallback path) ----------------
__global__ __launch_bounds__(256) void k_rnorm(const float* __restrict__ X, float* __restrict__ rinv){
  int t = threadIdx.x, w = t >> 6, l = t & 63;
  int n = blockIdx.x * 4 + w;
  if(n >= NTOT) return;
  const float4* x4 = (const float4*)(X + (size_t)n * DIM + l * 12);
  float4 x0 = x4[0], x1 = x4[1], x2 = x4[2];
  float s = x0.x*x0.x + x0.y*x0.y + x0.z*x0.z + x0.w*x0.w
          + x1.x*x1.x + x1.y*x1.y + x1.z*x1.z + x1.w*x1.w
          + x2.x*x2.x + x2.y*x2.y + x2.z*x2.z + x2.w*x2.w;
  #pragma unroll
  for(int o = 32; o > 0; o >>= 1) s += __shfl_xor(s, o);
  if(l == 0) rinv[n] = 1.0f / (sqrtf(s) + 1e-12f);
}

// ---------------- normalized prototypes + bias2 ----------------
__global__ __launch_bounds__(256) void k_protn(const float* __restrict__ P,
    const float* __restrict__ bvec, float* __restrict__ protn, float* __restrict__ bias2){
  int t = threadIdx.x, w = t >> 6, l = t & 63;
  int r = blockIdx.x * 4 + w;
  if(r >= NCK) return;
  const float4* x4 = (const float4*)(P + (size_t)r * DIM + l * 12);
  float4 x0 = x4[0], x1 = x4[1], x2 = x4[2];
  float s = x0.x*x0.x + x0.y*x0.y + x0.z*x0.z + x0.w*x0.w
          + x1.x*x1.x + x1.y*x1.y + x1.z*x1.z + x1.w*x1.w
          + x2.x*x2.x + x2.y*x2.y + x2.z*x2.z + x2.w*x2.w;
  #pragma unroll
  for(int o = 32; o > 0; o >>= 1) s += __shfl_xor(s, o);
  float rv = 1.0f / (sqrtf(s) + 1e-12f);
  x0.x *= rv; x0.y *= rv; x0.z *= rv; x0.w *= rv;
  x1.x *= rv; x1.y *= rv; x1.z *= rv; x1.w *= rv;
  x2.x *= rv; x2.y *= rv; x2.z *= rv; x2.w *= rv;
  float4* o4 = (float4*)(protn + (size_t)r * DIM + l * 12);
  o4[0] = x0; o4[1] = x1; o4[2] = x2;
  const float4* b4 = (const float4*)(bvec + l * 12);
  float4 b0 = b4[0], b1 = b4[1], b2 = b4[2];
  float bb = b0.x*x0.x + b0.y*x0.y + b0.z*x0.z + b0.w*x0.w
           + b1.x*x1.x + b1.y*x1.y + b1.z*x1.z + b1.w*x1.w
           + b2.x*x2.x + b2.y*x2.y + b2.z*x2.z + b2.w*x2.w;
  #pragma unroll
  for(int o = 32; o > 0; o >>= 1) bb += __shfl_xor(bb, o);
  if(l == 0) bias2[r] = bb;
}

// ---------------- f32 NT GEMM; BF16OUT also emits hi/lo split (rows padded to 1024) ----------------
template<int HAS_SCALE, int HAS_BIAS, int HAS_ADD, int BF16OUT>
__global__ __launch_bounds__(256) void k_gemm_nt(const float* __restrict__ A,
    const float* __restrict__ B, float* __restrict__ C,
    const float* __restrict__ rowScale, const float* __restrict__ colBias,
    const float* __restrict__ addMat, unsigned short* __restrict__ Bh,
    unsigned short* __restrict__ Bl, int M, int N, int K){
  __shared__ float As[32][72];
  __shared__ float Bs[32][72];
  int t = threadIdx.x;
  int m0 = blockIdx.y * 64, n0 = blockIdx.x * 64;
  int srow = t >> 2, skq = (t & 3) * 8;
  int ty = t >> 4, tx = t & 15;
  int i0 = ty * 4, j0 = tx * 4;
  float acc[4][4] = {};
  int gra = m0 + srow; bool va = gra < M;
  int grb = n0 + srow; bool vb = grb < N;
  float scale = 1.0f;
  if(HAS_SCALE && va) scale = rowScale[gra];
  const float* Aptr = A + (size_t)gra * K + skq;
  const float* Bptr = B + (size_t)grb * K + skq;
  for(int k0 = 0; k0 < K; k0 += 32){
    float4 a0 = {0,0,0,0}, a1 = {0,0,0,0}, b0 = {0,0,0,0}, b1 = {0,0,0,0};
    if(va){ a0 = *(const float4*)(Aptr + k0); a1 = *(const float4*)(Aptr + k0 + 4); }
    if(vb){ b0 = *(const float4*)(Bptr + k0); b1 = *(const float4*)(Bptr + k0 + 4); }
    if(HAS_SCALE){
      a0.x *= scale; a0.y *= scale; a0.z *= scale; a0.w *= scale;
      a1.x *= scale; a1.y *= scale; a1.z *= scale; a1.w *= scale;
    }
    __syncthreads();
    As[skq+0][srow] = a0.x; As[skq+1][srow] = a0.y; As[skq+2][srow] = a0.z; As[skq+3][srow] = a0.w;
    As[skq+4][srow] = a1.x; As[skq+5][srow] = a1.y; As[skq+6][srow] = a1.z; As[skq+7][srow] = a1.w;
    Bs[skq+0][srow] = b0.x; Bs[skq+1][srow] = b0.y; Bs[skq+2][srow] = b0.z; Bs[skq+3][srow] = b0.w;
    Bs[skq+4][srow] = b1.x; Bs[skq+5][srow] = b1.y; Bs[skq+6][srow] = b1.z; Bs[skq+7][srow] = b1.w;
    __syncthreads();
    #pragma unroll
    for(int kk = 0; kk < 32; ++kk){
      float4 avv = *(const float4*)&As[kk][i0];
      float4 bvv = *(const float4*)&Bs[kk][j0];
      float a_[4] = {avv.x, avv.y, avv.z, avv.w};
      float b_[4] = {bvv.x, bvv.y, bvv.z, bvv.w};
      #pragma unroll
      for(int i = 0; i < 4; ++i)
        #pragma unroll
        for(int j = 0; j < 4; ++j)
          acc[i][j] += a_[i] * b_[j];
    }
  }
  #pragma unroll
  for(int i = 0; i < 4; ++i){
    int gr = m0 + i0 + i;
    #pragma unroll
    for(int j = 0; j < 4; ++j){
      int gc = n0 + j0 + j;
      if(gc >= N) continue;
      float v2 = 0.f;
      if(gr < M){
        v2 = acc[i][j];
        if(HAS_BIAS) v2 += colBias[gc];
        if(HAS_ADD) v2 += addMat[(size_t)gr * N + gc];
        C[(size_t)gr * N + gc] = v2;
      }
      if(BF16OUT && gr < 1024){
        unsigned short h = f2bf(v2);
        Bh[(size_t)gr * N + gc] = h;
        Bl[(size_t)gr * N + gc] = f2bf(v2 - bf2f(h));
      }
    }
  }
}

// ---------------- MFMA split-bf16 main GEMM: 128x256, 3-buffer ring, single barrier, T5 setprio ----------------
__global__ __launch_bounds__(512, 1) void k_gemm_mfma(
    const unsigned short* __restrict__ Ahi, const unsigned short* __restrict__ Alo,
    const unsigned short* __restrict__ Bhi, const unsigned short* __restrict__ Blo,
    const float* __restrict__ bias2, float* __restrict__ C, float* __restrict__ poolPart){
  __shared__ __align__(16) unsigned short lds[73728];   // 144 KB = 3 buffers
  int h0 = blockIdx.x;
  int h = (h0 & 7) * 86 + (h0 >> 3);   // bijective XCD swizzle: 688 = 8 * 86 (T1)
  int nt = h & 3, mt = h >> 2;
  int m0 = mt * 128, n0 = nt * 256;
  int t = threadIdx.x;
  int w = t >> 6, l = t & 63;
  int wm = w >> 2, wn = w & 3;
  int lr = l & 15, lk = l >> 4;

  const unsigned short* gptr[6];
  int dofs[6];
  #pragma unroll
  for(int s = 0; s < 6; ++s){
    int cc = w * 6 + s;
    int r = (cc < 8) ? 0 : (cc < 16) ? 1 : (cc < 32) ? 2 : 3;
    int cc0 = (r == 0) ? 0 : (r == 1) ? 8 : (r == 2) ? 16 : 32;
    int regofs = (r == 0) ? 0 : (r == 1) ? 4096 : (r == 2) ? 8192 : 16384;
    int cloc = cc - cc0;
    int rloc = cloc * 16 + (l >> 2);
    int q = (l & 3) ^ ((rloc >> 1) & 3);
    const unsigned short* gs = (r == 0) ? Ahi : (r == 1) ? Alo : (r == 2) ? Bhi : Blo;
    int rbase = (r < 2) ? m0 : n0;
    gptr[s] = gs + (size_t)(rbase + rloc) * DIM + q * 8;
    dofs[s] = regofs + cloc * 512;
  }

  f32x4v acc[4][4];
  #pragma unroll
  for(int i = 0; i < 4; ++i)
    #pragma unroll
    for(int j = 0; j < 4; ++j) acc[i][j] = (f32x4v){0.f, 0.f, 0.f, 0.f};

  int aofs[4], bofs[4];
  #pragma unroll
  for(int f = 0; f < 4; ++f){
    int ar = wm * 64 + f * 16 + lr;
    aofs[f] = ar * 32 + (lk ^ ((ar >> 1) & 3)) * 8;
    int bc = wn * 64 + f * 16 + lr;
    bofs[f] = bc * 32 + (lk ^ ((bc >> 1) & 3)) * 8;
  }

  #pragma unroll
  for(int s = 0; s < 6; ++s) gload16(gptr[s], lds + dofs[s]);
  #pragma unroll
  for(int s = 0; s < 6; ++s) gload16(gptr[s] + 32, lds + 24576 + dofs[s]);

  const int NT = DIM / 32;  // 24
  for(int k = 0; k < NT; ++k){
    int k0 = k * 32;
    if(k + 1 < NT){
      asm volatile("s_waitcnt vmcnt(6)" ::: "memory");   // tile k's 6 (oldest) complete
    } else {
      asm volatile("s_waitcnt vmcnt(0)" ::: "memory");
    }
    asm volatile("s_barrier" ::: "memory");              // tile k visible; prior reads of buf[(k+2)%3] done
    if(k + 2 < NT){
      unsigned short* dst = lds + ((k + 2) % 3) * 24576;
      #pragma unroll
      for(int s = 0; s < 6; ++s)
        gload16(gptr[s] + k0 + 64, dst + dofs[s]);
    }
    const unsigned short* Lb = lds + (k % 3) * 24576;
    bf16x8 bh[4], bl[4];
    #pragma unroll
    for(int f = 0; f < 4; ++f){
      bh[f] = *(const bf16x8*)&Lb[8192 + bofs[f]];
      bl[f] = *(const bf16x8*)&Lb[16384 + bofs[f]];
    }
    __builtin_amdgcn_s_setprio(1);                       // T5: favor MFMA-issuing wave
    #pragma unroll
    for(int i = 0; i < 4; ++i){
      bf16x8 ahf = *(const bf16x8*)&Lb[aofs[i]];
      bf16x8 alf = *(const bf16x8*)&Lb[4096 + aofs[i]];
      #pragma unroll
      for(int j = 0; j < 4; ++j){
        acc[i][j] = __builtin_amdgcn_mfma_f32_16x16x32_bf16(ahf, bh[j], acc[i][j], 0, 0, 0);
        acc[i][j] = __builtin_amdgcn_mfma_f32_16x16x32_bf16(ahf, bl[j], acc[i][j], 0, 0, 0);
        acc[i][j] = __builtin_amdgcn_mfma_f32_16x16x32_bf16(alf, bh[j], acc[i][j], 0, 0, 0);
      }
    }
    __builtin_amdgcn_s_setprio(0);
    // no end barrier: next step's start barrier orders reads-before-overwrite (3-buffer ring)
  }
  #pragma unroll
  for(int i = 0; i < 4; ++i){
    #pragma unroll
    for(int j = 0; j < 4; ++j){
      int col = n0 + wn * 64 + j * 16 + lr;
      if(col >= NCK) continue;
      float bv = bias2[col];
      #pragma unroll
      for(int r2 = 0; r2 < 4; ++r2){
        int row = m0 + wm * 64 + i * 16 + lk * 4 + r2;
        if(row < NTOT) C[(size_t)row * NCK + col] = acc[i][j][r2] + bv;
      }
    }
  }
  // ---- pooled partials ----
  float* psh = (float*)lds;
  int rb = ((m0 / NPATCH) + 1) * NPATCH;
  #pragma unroll
  for(int j = 0; j < 4; ++j){
    float s0 = 0.f, s1 = 0.f;
    #pragma unroll
    for(int i = 0; i < 4; ++i)
      #pragma unroll
      for(int r2 = 0; r2 < 4; ++r2){
        int row = m0 + wm * 64 + i * 16 + lk * 4 + r2;
        float v = acc[i][j][r2];
        if(row < rb) s0 += v; else s1 += v;
      }
    s0 += __shfl_xor(s0, 16); s0 += __shfl_xor(s0, 32);
    s1 += __shfl_xor(s1, 16); s1 += __shfl_xor(s1, 32);
    if(lk == 0){
      int cslot = wn * 64 + j * 16 + lr;
      if(wm == 0){ psh[cslot] = s0; psh[256 + cslot] = s1; }
      else        { psh[512 + cslot] = s0; psh[768 + cslot] = s1; }
    }
  }
  __syncthreads();
  if(t < 256){
    float* pp = poolPart + (size_t)h * 512;
    pp[t] = psh[t] + psh[512 + t];
    pp[256 + t] = psh[256 + t] + psh[768 + t];
  }
}

// ---------------- per-class masked Sinkhorn (rank computed in-block) ----------------
__global__ __launch_bounds__(256) void k_sinkhorn(const float* __restrict__ logits,
    const int* __restrict__ pl, const int* __restrict__ counts,
    const int* __restrict__ labels, float* __restrict__ Aw, float* __restrict__ assign_out){
  int c = blockIdx.x;
  int NcI = counts[c];
  if(NcI == 0) return;
  __shared__ int imgs[BIMG];
  __shared__ int nimgS;
  __shared__ float sh[256];
  int t = threadIdx.x;
  if(t == 0){
    int ni = 0;
    for(int b = 0; b < BIMG; ++b) if(labels[b] == c) imgs[ni++] = b;
    nimgS = ni;
  }
  __syncthreads();
  float prf = (t < NCLS && t < c && counts[t] > 0) ? 1.f : 0.f;
  int rankc = (int)(red256(prf, sh) + 0.5f);
  int tot = nimgS * NPATCH;
  float Ncf = (float)NcI;
  float invNc = 1.0f / Ncf;

  float sp = 0.f;
  for(int ii = t; ii < tot; ii += 256){
    int n = imgs[ii / NPATCH] * NPATCH + (ii % NPATCH);
    if(pl[n] != c) continue;
    const float* lg = logits + (size_t)n * NCK + c * KP;
    float* aw = Aw + (size_t)n * KP;
    float l0 = expf(lg[0] / 0.05f), l1 = expf(lg[1] / 0.05f), l2 = expf(lg[2] / 0.05f),
          l3 = expf(lg[3] / 0.05f), l4 = expf(lg[4] / 0.05f);
    aw[0] = l0; aw[1] = l1; aw[2] = l2; aw[3] = l3; aw[4] = l4;
    sp += l0 + l1 + l2 + l3 + l4;
  }
  float S = red256(sp, sh);
  float sc = 1.0f / (S + 1e-16f);

  float cs0 = 0, cs1 = 0, cs2 = 0, cs3 = 0, cs4 = 0;
  for(int ii = t; ii < tot; ii += 256){
    int n = imgs[ii / NPATCH] * NPATCH + (ii % NPATCH);
    if(pl[n] != c) continue;
    float* aw = Aw + (size_t)n * KP;
    float l0 = aw[0]*sc, l1 = aw[1]*sc, l2 = aw[2]*sc, l3 = aw[3]*sc, l4 = aw[4]*sc;
    aw[0] = l0; aw[1] = l1; aw[2] = l2; aw[3] = l3; aw[4] = l4;
    cs0 += l0; cs1 += l1; cs2 += l2; cs3 += l3; cs4 += l4;
  }
  cs0 = red256(cs0, sh); cs1 = red256(cs1, sh); cs2 = red256(cs2, sh);
  cs3 = red256(cs3, sh); cs4 = red256(cs4, sh);

  for(int it = 0; it < 3; ++it){
    float m0 = 1.0f/(cs0+1e-16f), m1 = 1.0f/(cs1+1e-16f), m2 = 1.0f/(cs2+1e-16f),
          m3 = 1.0f/(cs3+1e-16f), m4 = 1.0f/(cs4+1e-16f);
    bool last = (it == 2);
    float n0 = 0, n1 = 0, n2 = 0, n3 = 0, n4 = 0;
    for(int ii = t; ii < tot; ii += 256){
      int n = imgs[ii / NPATCH] * NPATCH + (ii % NPATCH);
      if(pl[n] != c) continue;
      float* aw = Aw + (size_t)n * KP;
      float l0 = aw[0]*m0*0.2f, l1 = aw[1]*m1*0.2f, l2 = aw[2]*m2*0.2f,
            l3 = aw[3]*m3*0.2f, l4 = aw[4]*m4*0.2f;
      float rs = l0 + l1 + l2 + l3 + l4;
      float rw = 1.0f / (rs + 1e-16f);
      if(last){
        l0 *= rw; l1 *= rw; l2 *= rw; l3 *= rw; l4 *= rw;
        aw[0] = l0; aw[1] = l1; aw[2] = l2; aw[3] = l3; aw[4] = l4;
        int am = 0; float bv = l0;
        if(l1 > bv){ bv = l1; am = 1; }
        if(l2 > bv){ bv = l2; am = 2; }
        if(l3 > bv){ bv = l3; am = 3; }
        if(l4 > bv){ bv = l4; am = 4; }
        assign_out[n] = (float)(am + KP * rankc);
      } else {
        float w2 = rw * invNc;
        l0 *= w2; l1 *= w2; l2 *= w2; l3 *= w2; l4 *= w2;
        aw[0] = l0; aw[1] = l1; aw[2] = l2; aw[3] = l3; aw[4] = l4;
        n0 += l0; n1 += l1; n2 += l2; n3 += l3; n4 += l4;
      }
    }
    if(!last){
      cs0 = red256(n0, sh); cs1 = red256(n1, sh); cs2 = red256(n2, sh);
      cs3 = red256(n3, sh); cs4 = red256(n4, sh);
    }
  }
}

// ---------------- P_new partial sums (USEA: read bf16 normalized rows) ----------------
template<int USEA>
__global__ __launch_bounds__(256) void k_pnew_part(const float* __restrict__ X,
    const float* __restrict__ rinv, const unsigned short* __restrict__ Ahi,
    const float* __restrict__ Aw,
    const int* __restrict__ pl, const int* __restrict__ labels,
    float* __restrict__ part){
  int b = blockIdx.y, ch = blockIdx.x;
  int c = labels[b];
  int t = threadIdx.x;
  int j0 = ch * 86, j1 = j0 + 86; if(j1 > NPATCH) j1 = NPATCH;
  float acc[3][5] = {};
  for(int j = j0; j < j1; ++j){
    int n = b * NPATCH + j;
    if(pl[n] != c) continue;
    const float* aw = Aw + (size_t)n * KP;
    float a0 = aw[0], a1 = aw[1], a2 = aw[2], a3 = aw[3], a4 = aw[4];
    float rv = USEA ? 1.0f : rinv[n];
    #pragma unroll
    for(int dj = 0; dj < 3; ++dj){
      float x;
      if(USEA) x = bf2f(Ahi[(size_t)n * DIM + t + dj * 256]);
      else     x = X[(size_t)n * DIM + t + dj * 256] * rv;
      acc[dj][0] += a0 * x; acc[dj][1] += a1 * x; acc[dj][2] += a2 * x;
      acc[dj][3] += a3 * x; acc[dj][4] += a4 * x;
    }
  }
  float* po = part + ((size_t)(b * PCH + ch)) * KP * DIM;
  #pragma unroll
  for(int k = 0; k < 5; ++k)
    #pragma unroll
    for(int dj = 0; dj < 3; ++dj)
      po[k * DIM + t + dj * 256] = acc[dj][k];
}

// ---------------- fused tail: P_new final (blocks 0..200) + pooled gather + sa head (blocks 201..216) ----------------
__global__ __launch_bounds__(256) void k_tailm(const float* __restrict__ P,
    const float* __restrict__ part, const int* __restrict__ counts,
    const int* __restrict__ labels, float* __restrict__ out_np,
    const float* __restrict__ poolPart, const float* __restrict__ bias2,
    const float* __restrict__ sa, float* __restrict__ pooled, float* __restrict__ out){
  __shared__ float ps[1024];
  __shared__ int imgs[BIMG];
  __shared__ int nimgS;
  int t = threadIdx.x;
  if(blockIdx.x < CDIM){
    int c = blockIdx.x;
    bool pres = (c < NCLS) && (counts[c] > 0);
    const float* Pc = P + (size_t)c * KP * DIM;
    float* Oc = out_np + (size_t)c * KP * DIM;
    if(!pres){
      for(int i = t; i < KP * DIM; i += 256) Oc[i] = Pc[i];
      return;
    }
    if(t == 0){
      int ni = 0;
      for(int b = 0; b < BIMG; ++b) if(labels[b] == c) imgs[ni++] = b;
      nimgS = ni;
    }
    __syncthreads();
    int ni = nimgS;
    for(int i = t; i < KP * DIM; i += 256){
      float s = 0.f;
      for(int q = 0; q < ni; ++q){
        const float* pb = part + ((size_t)(imgs[q] * PCH)) * KP * DIM + i;
        for(int ch = 0; ch < PCH; ++ch) s += pb[(size_t)ch * KP * DIM];
      }
      Oc[i] = 0.99f * Pc[i] + 0.01f * s;
    }
  } else {
    int b = blockIdx.x - CDIM;
    int mt_lo = (b * NPATCH) >> 7;
    int mt_hi = ((b + 1) * NPATCH - 1) >> 7;
    #pragma unroll
    for(int g = 0; g < 4; ++g){
      int col = g * 256 + t;
      float s = 0.f;
      for(int mt = mt_lo; mt <= mt_hi; ++mt){
        int img0 = (mt * 128) / NPATCH;
        int buck = (img0 == b) ? 0 : 1;
        s += poolPart[((size_t)(mt * 4 + g)) * 512 + buck * 256 + t];
      }
      float pv = s / 1369.0f + ((col < NCK) ? bias2[col] : 0.f);
      if(col < NCK) pooled[(size_t)b * NCK + col] = pv;
      ps[col] = pv;
    }
    __syncthreads();
    if(t < NCLS){
      float sa0 = sa[t*5+0], sa1 = sa[t*5+1], sa2 = sa[t*5+2], sa3 = sa[t*5+3], sa4 = sa[t*5+4];
      float mx = fmaxf(fmaxf(fmaxf(sa0, sa1), fmaxf(sa2, sa3)), sa4);
      float e0 = expf(sa0 - mx), e1 = expf(sa1 - mx), e2 = expf(sa2 - mx),
            e3 = expf(sa3 - mx), e4 = expf(sa4 - mx);
      float se = e0 + e1 + e2 + e3 + e4;
      float iv = 5.0f / se;
      const float* p = ps + t * KP;
      out[b * NCLS + t] = p[0]*e0*iv + p[1]*e1*iv + p[2]*e2*iv + p[3]*e3*iv + p[4]*e4*iv;
    }
  }
}

// ---------------- P_new final (fallback) ----------------
__global__ __launch_bounds__(256) void k_pnew_fin(const float* __restrict__ P,
    const float* __restrict__ part, const int* __restrict__ counts,
    const int* __restrict__ labels, float* __restrict__ out_np){
  int c = blockIdx.x;
  int t = threadIdx.x;
  bool pres = (c < NCLS) && (counts[c] > 0);
  const float* Pc = P + (size_t)c * KP * DIM;
  float* Oc = out_np + (size_t)c * KP * DIM;
  if(!pres){
    for(int i = t; i < KP * DIM; i += 256) Oc[i] = Pc[i];
    return;
  }
  __shared__ int imgs[BIMG];
  __shared__ int nimgS;
  if(t == 0){
    int ni = 0;
    for(int b = 0; b < BIMG; ++b) if(labels[b] == c) imgs[ni++] = b;
    nimgS = ni;
  }
  __syncthreads();
  int ni = nimgS;
  for(int i = t; i < KP * DIM; i += 256){
    float s = 0.f;
    for(int q = 0; q < ni; ++q){
      const float* pb = part + ((size_t)(imgs[q] * PCH)) * KP * DIM + i;
      for(int ch = 0; ch < PCH; ++ch) s += pb[(size_t)ch * KP * DIM];
    }
    Oc[i] = 0.99f * Pc[i] + 0.01f * s;
  }
}

// ---------------- pooled stage 1 (fallback only) ----------------
__global__ __launch_bounds__(256) void k_pool1(const float* __restrict__ logits,
    float* __restrict__ poolPart){
  int b = blockIdx.y, ch = blockIdx.x;
  int t = threadIdx.x;
  int j0 = ch * 43, j1 = j0 + 43; if(j1 > NPATCH) j1 = NPATCH;
  float a0 = 0, a1 = 0, a2 = 0, a3 = 0;
  for(int j = j0; j < j1; ++j){
    const float* row = logits + ((size_t)(b * NPATCH + j)) * NCK;
    a0 += row[t]; a1 += row[t + 256]; a2 += row[t + 512];
    if(t < 237) a3 += row[t + 768];
  }
  float* po = poolPart + ((size_t)(b * QCH + ch)) * 1024;
  po[t] = a0; po[t + 256] = a1; po[t + 512] = a2;
  if(t < 237) po[t + 768] = a3;
}

// ---------------- pooled stage 2 + sa head (fallback) ----------------
__global__ __launch_bounds__(256) void k_pool2cls(const float* __restrict__ poolPart,
    const float* __restrict__ bias2, const float* __restrict__ sa,
    float* __restrict__ pooled, float* __restrict__ out){
  __shared__ float ps[1024];
  int b = blockIdx.x;
  int t = threadIdx.x;
  float s0 = 0, s1 = 0, s2 = 0, s3 = 0;
  const float* pb = poolPart + ((size_t)(b * QCH)) * 1024;
  for(int ch = 0; ch < QCH; ++ch){
    const float* p = pb + (size_t)ch * 1024;
    s0 += p[t]; s1 += p[t + 256]; s2 += p[t + 512];
    if(t < 237) s3 += p[t + 768];
  }
  float* o = pooled + (size_t)b * NCK;
  float o0 = s0 / 1369.0f, o1 = s1 / 1369.0f, o2 = s2 / 1369.0f, o3 = s3 / 1369.0f;
  o[t] = o0; o[t + 256] = o1; o[t + 512] = o2;
  if(t < 237) o[t + 768] = o3;
  ps[t] = o0; ps[t + 256] = o1; ps[t + 512] = o2;
  if(t < 237) ps[t + 768] = o3;
  __syncthreads();
  if(t < NCLS){
    float sa0 = sa[t*5+0], sa1 = sa[t*5+1], sa2 = sa[t*5+2], sa3 = sa[t*5+3], sa4 = sa[t*5+4];
    float mx = fmaxf(fmaxf(fmaxf(sa0, sa1), fmaxf(sa2, sa3)), sa4);
    float e0 = expf(sa0 - mx), e1 = expf(sa1 - mx), e2 = expf(sa2 - mx),
          e3 = expf(sa3 - mx), e4 = expf(sa4 - mx);
    float se = e0 + e1 + e2 + e3 + e4;
    float iv = 5.0f / se;
    const float* p = ps + t * KP;
    out[b * NCLS + t] = p[0]*e0*iv + p[1]*e1*iv + p[2]*e2*iv + p[3]*e3*iv + p[4]*e4*iv;
  }
}

extern "C" void kernel_launch(void* const* d_in, const int* in_sizes, int n_in,
                              void* d_out, int out_size, void* d_ws, size_t ws_size,
                              hipStream_t stream){
  const float* X      = (const float*)d_in[0];
  const int*   labels = (const int*)d_in[1];
  const float* P      = (const float*)d_in[2];
  const float* W      = (const float*)d_in[3];
  const float* bvec   = (const float*)d_in[4];
  const float* sa     = (const float*)d_in[5];

  float* out        = (float*)d_out;
  float* out_cls    = out;
  float* out_logits = out + 3200;
  float* out_pooled = out_logits + (size_t)NTOT * NCK;
  float* out_assign = out_pooled + BIMG * NCK;
  float* out_np     = out_assign + NTOT;
  float* out_pseudo = out_np + (size_t)CDIM * KP * DIM;

  const size_t AHI_F = (size_t)MPAD * DIM / 2;   // ushort array in float units
  const size_t BHI_F = (size_t)1024 * DIM / 2;
  const size_t MFMA_F = 2 * AHI_F + 2 * BHI_F;
  const size_t BASE_F = 4050000;
  bool use_mfma = ws_size >= (MFMA_F + BASE_F) * sizeof(float);

  float* ws = (float*)d_ws;
  unsigned short* Ahi = (unsigned short*)ws;
  unsigned short* Alo = (unsigned short*)(ws + AHI_F);
  unsigned short* Bhi = (unsigned short*)(ws + 2 * AHI_F);
  unsigned short* Blo = (unsigned short*)(ws + 2 * AHI_F + BHI_F);
  float* base = use_mfma ? (ws + MFMA_F) : ws;

  float* protn  = base;
  float* Bmat   = protn + (size_t)NCK * DIM;
  float* bias2  = Bmat + (size_t)NCK * DIM;
  float* rinv   = bias2 + 1024;
  float* uvec   = rinv + NTOT;
  float* Aw     = uvec + NTOT;
  float* meanv  = Aw + (size_t)NTOT * KP;
  float* wvb    = meanv + DIM;
  float* pbuf   = wvb + DIM;
  float* subuf  = pbuf + (size_t)UCH * DIM;
  float* parts  = subuf + UCH;
  float* scal   = parts + 32;
  int*   pli    = (int*)(scal + 8);
  int*   counts = pli + NTOT;
  float* pnewP  = (float*)(counts + 256);
  float* poolP  = pnewP + (size_t)BIMG * PCH * KP * DIM;
  unsigned* enc = (unsigned*)(scal + 1);

  k_colmean1<<<512, 256, 0, stream>>>(X, pbuf);
  k_meanred<<<12, 256, 0, stream>>>(pbuf, meanv, wvb, parts, counts, enc);
  for(int i = 0; i < 10; ++i){
    k_pcapass<<<UCH, 256, 0, stream>>>(X, wvb, parts, pbuf, subuf);
    k_pcared<<<12, 256, 0, stream>>>(pbuf, subuf, meanv, wvb, parts);
  }
  if(use_mfma){
    k_ufinal<1><<<UCH, 256, 0, stream>>>(X, wvb, parts, uvec, enc, rinv, Ahi, Alo);
  } else {
    k_ufinal<0><<<UCH, 256, 0, stream>>>(X, wvb, parts, uvec, enc, nullptr, nullptr, nullptr);
    k_rnorm<<<5476, 256, 0, stream>>>(X, rinv);
  }
  k_pseudo<<<86, 256, 0, stream>>>(uvec, enc, labels, pli, out_pseudo, out_assign, counts);
  k_protn<<<252, 256, 0, stream>>>(P, bvec, protn, bias2);
  if(use_mfma){
    k_gemm_nt<0, 0, 1, 1><<<dim3(12, 16), 256, 0, stream>>>(protn, W, Bmat, nullptr, nullptr,
                                                            protn, Bhi, Blo, NCK, DIM, DIM);
    k_gemm_mfma<<<688, 512, 0, stream>>>(Ahi, Alo, Bhi, Blo, bias2, out_logits, poolP);
  } else {
    k_gemm_nt<0, 0, 1, 0><<<dim3(12, 16), 256, 0, stream>>>(protn, W, Bmat, nullptr, nullptr,
                                                            protn, nullptr, nullptr, NCK, DIM, DIM);
    k_gemm_nt<1, 1, 0, 0><<<dim3(16, 343), 256, 0, stream>>>(X, Bmat, out_logits, rinv, bias2,
                                                             nullptr, nullptr, nullptr, NTOT, NCK, DIM);
  }
  k_sinkhorn<<<NCLS, 256, 0, stream>>>(out_logits, pli, counts, labels, Aw, out_assign);
  if(use_mfma){
    k_pnew_part<1><<<dim3(PCH, BIMG), 256, 0, stream>>>(nullptr, nullptr, Ahi, Aw, pli, labels, pnewP);
    k_tailm<<<CDIM + BIMG, 256, 0, stream>>>(P, pnewP, counts, labels, out_np,
                                             poolP, bias2, sa, out_pooled, out_cls);
  } else {
    k_pnew_part<0><<<dim3(PCH, BIMG), 256, 0, stream>>>(X, rinv, nullptr, Aw, pli, labels, pnewP);
    k_pnew_fin<<<CDIM, 256, 0, stream>>>(P, pnewP, counts, labels, out_np);
    k_pool1<<<dim3(QCH, BIMG), 256, 0, stream>>>(out_logits, poolP);
    k_pool2cls<<<BIMG, 256, 0, stream>>>(poolP, bias2, sa, out_pooled, out_cls);
  }
}